// Round 3
// baseline (1657.352 us; speedup 1.0000x reference)
//
#include <hip/hip_runtime.h>
#include <math.h>

typedef unsigned short bf16_t;

#define B_ 4
#define C_ 128
#define H_ 128
#define W_ 128
#define L_ (H_*W_)               // 16384
#define NS  ((size_t)B_*L_*C_)   // 8388608 elems
#define NH  ((size_t)B_*L_*64)
#define NSP ((size_t)L_*C_)
#define PI_F 3.14159265358979323846f
#define BN_INV 0.9999950000374997f   // (1+1e-5)^-0.5
#define THETA_SC 0.8304820237218406f // log2(10000)/16
#define TOTW 157148

__device__ __forceinline__ float ldf(bf16_t v){ return __uint_as_float(((unsigned)v)<<16); }
__device__ __forceinline__ bf16_t f2b(float f){
  unsigned u = __float_as_uint(f);
  u += 0x7fffu + ((u>>16)&1u);     // RNE
  return (bf16_t)(u>>16);
}

// workspace: 6 full seq buffers + 3 half + WG + ACC + converted weights + flag
#define WGSZ ((size_t)B_*8*L_)       // 524288
#define ACCSZ 2304
#define CWSZ 157184
#define WSF (6*NS + 3*NH + WGSZ + ACCSZ + CWSZ + 16)
__device__ float g_ws[WSF];

// ---------------------------------------------------------------- dtype probe + weight convert
__global__ void k_probe(const bf16_t* __restrict__ xb, int* __restrict__ flag){
  __shared__ int vote;
  if (threadIdx.x == 0) vote = 0;
  __syncthreads();
  int bad = 0;
  for (int i = threadIdx.x; i < 2048; i += 256) {
    float v = ldf(xb[2*i]);            // even bf16 index = fp32 mantissa half if storage is fp32
    if (!(fabsf(v) < 1e6f)) bad = 1;   // catches huge / inf / nan
  }
  if (bad) atomicOr(&vote, 1);
  __syncthreads();
  if (threadIdx.x == 0) *flag = vote;  // 1 = fp32 storage, 0 = bf16 storage
}

struct P47 { const void* p[47]; };
__device__ __constant__ int c_wsz[47] = {
  16384,128,128,128,1152,128,1024,8,8,8,1024,128,128,128,128,128,
  16384,128,1152,16384,128,3200,16384,128,4096,64,576,64,8192,128,
  576,64,16384,128,1152,128,128,128,512,4,512,128,16384,32768,128,128,128};

__global__ __launch_bounds__(256) void k_cvt(P47 ps, const int* __restrict__ flagp,
                                             float* __restrict__ dst){
  int g = blockIdx.x*256 + threadIdx.x;
  if (g >= TOTW) return;
  int fl = *flagp;
  int idx = 0, off = g;
  while (off >= c_wsz[idx]) { off -= c_wsz[idx]; idx++; }
  const void* s = ps.p[idx];
  dst[g] = fl ? ((const float*)s)[off] : ldf(((const bf16_t*)s)[off]);
}

__global__ void k_zero(float* p, int n){
  int i = blockIdx.x*256 + threadIdx.x;
  if (i < n) p[i] = 0.f;
}

// ---------------------------------------------------------------- FFT core
// 128-pt FFT across 64 lanes: lane l holds x[l] (lo) and x[l+64] (hi).
// Forward = DIF (natural in, bit-reversed out); inverse = DIT (bit-reversed in,
// natural out), conjugate twiddles. Mid-FFT ops are pointwise per pixel so the
// bit-reversal permutation cancels.
__device__ __forceinline__ void fft128_fwd(float& lor, float& loi, float& hir, float& hii, int lane) {
  {
    float s, c; sincosf(-PI_F * (float)lane * (1.f/64.f), &s, &c);
    float ar = lor, ai = loi;
    float dr = ar - hir, di = ai - hii;
    lor = ar + hir; loi = ai + hii;
    hir = dr*c - di*s; hii = dr*s + di*c;
  }
  #pragma unroll
  for (int m = 32; m >= 1; m >>= 1) {
    int k = lane & (m-1);
    float s, c; sincosf(-PI_F * (float)k / (float)m, &s, &c);
    bool up = (lane & m) != 0;
    {
      float orr = __shfl_xor(lor, m), oii = __shfl_xor(loi, m);
      float sr = lor + orr, si = loi + oii;
      float dr = orr - lor, di = oii - loi;
      float tr = dr*c - di*s, ti = dr*s + di*c;
      lor = up ? tr : sr; loi = up ? ti : si;
    }
    {
      float orr = __shfl_xor(hir, m), oii = __shfl_xor(hii, m);
      float sr = hir + orr, si = hii + oii;
      float dr = orr - hir, di = oii - hii;
      float tr = dr*c - di*s, ti = dr*s + di*c;
      hir = up ? tr : sr; hii = up ? ti : si;
    }
  }
}

__device__ __forceinline__ void fft128_inv(float& lor, float& loi, float& hir, float& hii, int lane) {
  #pragma unroll
  for (int m = 1; m <= 32; m <<= 1) {
    int k = lane & (m-1);
    float s, c; sincosf(PI_F * (float)k / (float)m, &s, &c);
    bool up = (lane & m) != 0;
    {
      float orr = __shfl_xor(lor, m), oii = __shfl_xor(loi, m);
      float qr = orr*c - oii*s, qi = orr*s + oii*c;
      float lo_r = lor + qr, lo_i = loi + qi;
      float mr = lor*c - loi*s, mi = lor*s + loi*c;
      float up_r = orr - mr, up_i = oii - mi;
      lor = up ? up_r : lo_r; loi = up ? up_i : lo_i;
    }
    {
      float orr = __shfl_xor(hir, m), oii = __shfl_xor(hii, m);
      float qr = orr*c - oii*s, qi = orr*s + oii*c;
      float lo_r = hir + qr, lo_i = hii + qi;
      float mr = hir*c - hii*s, mi = hir*s + hii*c;
      float up_r = orr - mr, up_i = oii - mi;
      hir = up ? up_r : lo_r; hii = up ? up_i : lo_i;
    }
  }
  {
    float s, c; sincosf(PI_F * (float)lane * (1.f/64.f), &s, &c);
    float qr = hir*c - hii*s, qi = hir*s + hii*c;
    float pr = lor, pi = loi;
    lor = pr + qr; loi = pi + qi;
    hir = pr - qr; hii = pi - qi;
  }
}

__global__ __launch_bounds__(256) void k_fft_row_fwd(const float* __restrict__ in,
    float* __restrict__ re, float* __restrict__ im) {
  int lane = threadIdx.x & 63;
  size_t row = (size_t)blockIdx.x*4 + (threadIdx.x >> 6);
  size_t base = row * 128;
  float lor = in[base + lane], loi = 0.f;
  float hir = in[base + lane + 64], hii = 0.f;
  fft128_fwd(lor, loi, hir, hii, lane);
  re[base+lane] = lor; im[base+lane] = loi;
  re[base+lane+64] = hir; im[base+lane+64] = hii;
}

__global__ __launch_bounds__(256) void k_fft_row_inv_abs(
    float* __restrict__ re, float* __restrict__ im,
    const float* __restrict__ ng, const float* __restrict__ nbe) {
  int lane = threadIdx.x & 63;
  size_t row = (size_t)blockIdx.x*4 + (threadIdx.x >> 6);
  size_t base = row * 128;
  float lor = re[base+lane], loi = im[base+lane];
  float hir = re[base+lane+64], hii = im[base+lane+64];
  fft128_inv(lor, loi, hir, hii, lane);
  int c = (int)((row >> 7) & 127);
  float sg = ng[c] * BN_INV, sb = nbe[c];
  float v0 = sqrtf(lor*lor + loi*loi) * (1.f/128.f);
  float v1 = sqrtf(hir*hir + hii*hii) * (1.f/128.f);
  re[base+lane]    = fmaxf(v0*sg + sb, 0.f);
  re[base+lane+64] = fmaxf(v1*sg + sb, 0.f);
}

template<bool FWD>
__global__ __launch_bounds__(256) void k_fft_col(float* __restrict__ re, float* __restrict__ im) {
  __shared__ float Lre[128][33];
  __shared__ float Lim[128][33];
  int tid = threadIdx.x;
  size_t img = blockIdx.x >> 2;
  int w0 = (blockIdx.x & 3) * 32;
  float* rp = re + img * (size_t)L_ + w0;
  float* ip = im + img * (size_t)L_ + w0;
  for (int i = tid; i < 4096; i += 256) {
    int h = i >> 5, wl = i & 31;
    Lre[h][wl] = rp[(size_t)h*W_ + wl];
    Lim[h][wl] = ip[(size_t)h*W_ + wl];
  }
  __syncthreads();
  int lane = tid & 63, wv = tid >> 6;
  for (int i = 0; i < 8; i++) {
    int col = wv*8 + i;
    float lor = Lre[lane][col], loi = Lim[lane][col];
    float hir = Lre[lane+64][col], hii = Lim[lane+64][col];
    if (FWD) {
      fft128_fwd(lor, loi, hir, hii, lane);
    } else {
      fft128_inv(lor, loi, hir, hii, lane);
      lor *= (1.f/128.f); loi *= (1.f/128.f); hir *= (1.f/128.f); hii *= (1.f/128.f);
    }
    Lre[lane][col]=lor; Lim[lane][col]=loi;
    Lre[lane+64][col]=hir; Lim[lane+64][col]=hii;
  }
  __syncthreads();
  for (int i = tid; i < 4096; i += 256) {
    int h = i >> 5, wl = i & 31;
    rp[(size_t)h*W_ + wl] = Lre[h][wl];
    ip[(size_t)h*W_ + wl] = Lim[h][wl];
  }
}

// ---------------------------------------------------------------- freq-domain convs
__global__ __launch_bounds__(256) void k_freq1(const float* __restrict__ tre,
    const float* __restrict__ fw1, const float* __restrict__ fb1,
    const float* __restrict__ fg, const float* __restrict__ fbe,
    float* __restrict__ wg1) {
  __shared__ float w1s[1024];
  int tid = threadIdx.x;
  for (int i = tid; i < 1024; i += 256) w1s[i] = fw1[i];
  __syncthreads();
  size_t g = (size_t)blockIdx.x*256 + tid;   // (b,o,p)
  int p = (int)(g & (L_-1));
  int o = (int)((g >> 14) & 7);
  int b = (int)(g >> 17);
  const float* tp = tre + (size_t)b*128*L_ + p;
  const float* wrow = w1s + o*128;
  float acc = 0.f;
  for (int c = 0; c < 128; c++) acc += wrow[c] * tp[(size_t)c*L_];
  float v = (acc + fb1[o]) * (fg[o]*BN_INV) + fbe[o];
  wg1[g] = fmaxf(v, 0.f);
}

__global__ __launch_bounds__(256) void k_freq2(const float* __restrict__ wg1,
    const float* __restrict__ fw2, const float* __restrict__ fb2,
    float* __restrict__ re, float* __restrict__ im) {
  __shared__ float w2s[1024];
  __shared__ float b2s[128];
  int tid = threadIdx.x;
  for (int i = tid; i < 1024; i += 256) w2s[i] = fw2[i];
  if (tid < 128) b2s[tid] = fb2[tid];
  __syncthreads();
  size_t g = (size_t)blockIdx.x*256 + tid;   // (b,c,p)
  int p = (int)(g & (L_-1));
  int c = (int)((g >> 14) & 127);
  int b = (int)(g >> 21);
  const float* wp = wg1 + (size_t)b*8*L_ + p;
  float acc = b2s[c];
  #pragma unroll
  for (int o = 0; o < 8; o++) acc += w2s[c*8+o] * wp[(size_t)o*L_];
  float wgt = 1.f/(1.f+expf(-acc));
  re[g] *= wgt; im[g] *= wgt;
}

// ---------------------------------------------------------------- transposes
template<bool DUAL>
__global__ void k_p2s(const void* __restrict__ src, float* __restrict__ dst,
                      const float* __restrict__ add1, const float* __restrict__ add2,
                      const int* __restrict__ flagp) {
  __shared__ float tile[32][33];
  int fl = DUAL ? *flagp : 1;
  int b = blockIdx.z;
  int p0 = blockIdx.x*32, c0 = blockIdx.y*32;
  int tx = threadIdx.x, ty = threadIdx.y;
  size_t base_in = (size_t)b*NSP;
  #pragma unroll
  for (int k = 0; k < 4; k++) {
    size_t off = base_in + (size_t)(c0+ty+8*k)*L_ + p0 + tx;
    float v;
    if (DUAL && !fl) v = ldf(((const bf16_t*)src)[off]);
    else             v = ((const float*)src)[off];
    tile[ty+8*k][tx] = v;
  }
  __syncthreads();
  size_t base = (size_t)b*NSP;
  #pragma unroll
  for (int k = 0; k < 4; k++) {
    size_t idx = base + (size_t)(p0+ty+8*k)*C_ + c0 + tx;
    float v = tile[tx][ty+8*k];
    if (add1) v += add1[idx];
    if (add2) v += add2[idx];
    dst[idx] = v;
  }
}

__global__ void k_s2p(const float* __restrict__ src, float* __restrict__ dst) {
  __shared__ float tile[32][33];
  int b = blockIdx.z;
  int p0 = blockIdx.x*32, c0 = blockIdx.y*32;
  int tx = threadIdx.x, ty = threadIdx.y;
  const float* sp = src + (size_t)b*NSP;
  #pragma unroll
  for (int k = 0; k < 4; k++)
    tile[ty+8*k][tx] = sp[(size_t)(p0+ty+8*k)*C_ + c0 + tx];
  __syncthreads();
  float* dp = dst + (size_t)b*NSP;
  #pragma unroll
  for (int k = 0; k < 4; k++)
    dp[(size_t)(c0+ty+8*k)*L_ + p0 + tx] = tile[tx][ty+8*k];
}

// ---------------------------------------------------------------- depthwise convs (NHWC)
template<int CC, int MODE>  // MODE 0: out = in + dw + b ; MODE 1: out = silu(dw + b)
__global__ __launch_bounds__(256) void k_dw3(const float* __restrict__ in,
    const float* __restrict__ w, const float* __restrict__ bias,
    float* __restrict__ out) {
  __shared__ float wl[CC*9];
  int tid = threadIdx.x;
  for (int i = tid; i < CC*9; i += 256) wl[i] = w[i];
  __syncthreads();
  size_t g = (size_t)blockIdx.x*256 + tid;
  int c = (int)(g % CC);
  size_t t = g / CC;
  int wp_ = (int)(t % W_);
  int hp = (int)((t / W_) % H_);
  int b = (int)(t / (size_t)L_);
  const float* ip = in + (size_t)b * L_ * CC + c;
  float acc = bias[c];
  #pragma unroll
  for (int dh = -1; dh <= 1; dh++) {
    int h2 = hp + dh;
    if ((unsigned)h2 >= (unsigned)H_) continue;
    #pragma unroll
    for (int dw = -1; dw <= 1; dw++) {
      int w2 = wp_ + dw;
      if ((unsigned)w2 >= (unsigned)W_) continue;
      acc += wl[c*9 + (dh+1)*3 + (dw+1)] * ip[((size_t)h2*W_ + w2)*CC];
    }
  }
  if (MODE == 0) out[g] = in[g] + acc;
  else           out[g] = acc / (1.f + expf(-acc));
}

template<int K>
__global__ __launch_bounds__(256) void k_gconv(const float* __restrict__ in,
    const float* __restrict__ w, float* __restrict__ out) {
  __shared__ float wl[64*2*K*K];
  int tid = threadIdx.x;
  for (int i = tid; i < 64*2*K*K; i += 256) wl[i] = w[i];
  __syncthreads();
  size_t g = (size_t)blockIdx.x*256 + tid;
  int oc = (int)(g & 63);
  size_t t = g >> 6;
  int wp_ = (int)(t & (W_-1));
  int hp = (int)((t >> 7) & (H_-1));
  int b = (int)(t >> 14);
  const float* ip = in + (size_t)b*L_*128 + 2*oc;
  const int P = K/2;
  float acc = 0.f;
  #pragma unroll
  for (int kh = 0; kh < K; kh++) {
    int h2 = hp + kh - P;
    if ((unsigned)h2 >= (unsigned)H_) continue;
    #pragma unroll
    for (int kw = 0; kw < K; kw++) {
      int w2 = wp_ + kw - P;
      if ((unsigned)w2 >= (unsigned)W_) continue;
      const float* px = ip + ((size_t)h2*W_ + w2)*128;
      acc += wl[(oc*2+0)*(K*K) + kh*K + kw]*px[0]
           + wl[(oc*2+1)*(K*K) + kh*K + kw]*px[1];
    }
  }
  out[g] = acc;
}

// ---------------------------------------------------------------- token GEMM (seq 1x1 conv)
// In-place (out==in) safe: all global reads of a block's 64 tokens finish
// before its epilogue writes; blocks own disjoint token ranges.
template<int CIN, int COUT, int EPI, bool MUL>   // EPI 0:none 1:bias 2:bias+silu
__global__ __launch_bounds__(256) void k_gemm_tok(
    const float* __restrict__ in, const float* __restrict__ mulp,
    const float* __restrict__ Wm, const float* __restrict__ bias,
    float* __restrict__ out) {
  __shared__ __align__(16) float As[16][68];
  __shared__ __align__(16) float Bs[16][COUT+4];
  constexpr int RN = COUT/16;
  int tid = threadIdx.x;
  size_t t0 = (size_t)blockIdx.x * 64;
  int to = tid & 15, og = tid >> 4;
  float acc[4][RN];
  #pragma unroll
  for (int j = 0; j < 4; j++)
    #pragma unroll
    for (int i = 0; i < RN; i++) acc[j][i] = 0.f;
  for (int kc = 0; kc < CIN; kc += 16) {
    {
      int tt = tid >> 2, kq = (tid & 3) * 4;
      size_t base = (t0 + tt) * CIN + kc + kq;
      float4 v = *(const float4*)(in + base);
      if (MUL) {
        float4 m = *(const float4*)(mulp + base);
        v.x *= m.x; v.y *= m.y; v.z *= m.z; v.w *= m.w;
      }
      As[kq+0][tt]=v.x; As[kq+1][tt]=v.y; As[kq+2][tt]=v.z; As[kq+3][tt]=v.w;
    }
    if (tid < 2*COUT) {
      int o = tid >> 1, k8 = (tid & 1) * 8;
      const float* wp = Wm + (size_t)o * CIN + kc + k8;
      float4 v0 = *(const float4*)wp;
      float4 v1 = *(const float4*)(wp + 4);
      Bs[k8+0][o]=v0.x; Bs[k8+1][o]=v0.y; Bs[k8+2][o]=v0.z; Bs[k8+3][o]=v0.w;
      Bs[k8+4][o]=v1.x; Bs[k8+5][o]=v1.y; Bs[k8+6][o]=v1.z; Bs[k8+7][o]=v1.w;
    }
    __syncthreads();
    #pragma unroll
    for (int kk = 0; kk < 16; kk++) {
      float4 a = *(const float4*)&As[kk][to*4];
      float bv[RN];
      #pragma unroll
      for (int i = 0; i < RN; i++) bv[i] = Bs[kk][og*RN+i];
      #pragma unroll
      for (int i = 0; i < RN; i++) {
        acc[0][i] += a.x*bv[i];
        acc[1][i] += a.y*bv[i];
        acc[2][i] += a.z*bv[i];
        acc[3][i] += a.w*bv[i];
      }
    }
    __syncthreads();
  }
  #pragma unroll
  for (int j = 0; j < 4; j++) {
    size_t t = t0 + to*4 + j;
    #pragma unroll
    for (int i = 0; i < RN; i++) {
      int o = og*RN + i;
      float v = acc[j][i];
      if (EPI >= 1) v += bias[o];
      if (EPI == 2) v = v / (1.f + expf(-v));
      out[t*COUT + o] = v;
    }
  }
}

// ---------------------------------------------------------------- planar GEMM (c1 / red)
// DUALIN: in1 dtype selected by flag (x input). DUALOUT: out dtype by flag.
template<int CIN, bool DUALIN, bool DUALOUT, bool ADDX>
__global__ __launch_bounds__(256) void k_gemm_planar(
    const void* __restrict__ in1, const float* __restrict__ in2f,
    const float* __restrict__ Wm, const float* __restrict__ bias,
    const float* __restrict__ gam, const float* __restrict__ bet,
    const float* __restrict__ addp, void* __restrict__ out,
    const int* __restrict__ flagp) {
  constexpr int COUT = 128;
  __shared__ __align__(16) float As[16][68];
  __shared__ __align__(16) float Bs[16][COUT+4];
  int fl = (DUALIN || DUALOUT) ? *flagp : 1;
  int tid = threadIdx.x;
  int b = blockIdx.y;
  size_t p0 = (size_t)blockIdx.x * 64;
  int to = tid & 15, og = tid >> 4;
  float acc[4][8];
  #pragma unroll
  for (int j = 0; j < 4; j++)
    #pragma unroll
    for (int i = 0; i < 8; i++) acc[j][i] = 0.f;
  for (int kc = 0; kc < CIN; kc += 16) {
    {
      int kk = tid >> 4, pq = (tid & 15) * 4;
      int k = kc + kk;
      if (CIN == 128 || k < 128) {
        size_t eoff = ((size_t)b*128 + k)*L_ + p0 + pq;
        if (DUALIN && !fl) {
          ushort4 v = *(const ushort4*)((const bf16_t*)in1 + eoff);
          As[kk][pq+0]=ldf((bf16_t)v.x); As[kk][pq+1]=ldf((bf16_t)v.y);
          As[kk][pq+2]=ldf((bf16_t)v.z); As[kk][pq+3]=ldf((bf16_t)v.w);
        } else {
          *(float4*)&As[kk][pq] = *(const float4*)((const float*)in1 + eoff);
        }
      } else {
        size_t eoff = ((size_t)b*128 + (k-128))*L_ + p0 + pq;
        *(float4*)&As[kk][pq] = *(const float4*)(in2f + eoff);
      }
    }
    {
      int o = tid >> 1, k8 = (tid & 1) * 8;
      const float* wp = Wm + (size_t)o * CIN + kc + k8;
      float4 v0 = *(const float4*)wp;
      float4 v1 = *(const float4*)(wp + 4);
      Bs[k8+0][o]=v0.x; Bs[k8+1][o]=v0.y; Bs[k8+2][o]=v0.z; Bs[k8+3][o]=v0.w;
      Bs[k8+4][o]=v1.x; Bs[k8+5][o]=v1.y; Bs[k8+6][o]=v1.z; Bs[k8+7][o]=v1.w;
    }
    __syncthreads();
    #pragma unroll
    for (int kk = 0; kk < 16; kk++) {
      float4 a = *(const float4*)&As[kk][to*4];
      float bv[8];
      #pragma unroll
      for (int i = 0; i < 8; i++) bv[i] = Bs[kk][og*8+i];
      #pragma unroll
      for (int i = 0; i < 8; i++) {
        acc[0][i] += a.x*bv[i];
        acc[1][i] += a.y*bv[i];
        acc[2][i] += a.z*bv[i];
        acc[3][i] += a.w*bv[i];
      }
    }
    __syncthreads();
  }
  #pragma unroll
  for (int j = 0; j < 4; j++) {
    #pragma unroll
    for (int i = 0; i < 8; i++) {
      int o = og*8 + i;
      float v = acc[j][i] + bias[o];
      v = v * (gam[o]*BN_INV) + bet[o];
      v = fmaxf(v, 0.f);
      size_t idx = ((size_t)b*128 + o)*L_ + p0 + to*4 + j;
      if (ADDX) v += addp[idx];
      if (DUALOUT && !fl) ((bf16_t*)out)[idx] = f2b(v);
      else                ((float*)out)[idx]  = v;
    }
  }
}

// ---------------------------------------------------------------- LN / LN+FFN
__global__ __launch_bounds__(256) void k_ln(const float* __restrict__ in,
    const float* __restrict__ g, const float* __restrict__ be, float* __restrict__ out) {
  int tid = threadIdx.x, lane = tid & 63;
  size_t t = (size_t)blockIdx.x*4 + (tid >> 6);
  const float* row = in + t*128;
  float2 v = *(const float2*)(row + lane*2);
  float s = v.x + v.y, ss = v.x*v.x + v.y*v.y;
  #pragma unroll
  for (int m = 1; m < 64; m <<= 1) { s += __shfl_xor(s, m); ss += __shfl_xor(ss, m); }
  float mean = s*(1.f/128.f);
  float inv = rsqrtf(ss*(1.f/128.f) - mean*mean + 1e-5f);
  float2 o;
  o.x = (v.x-mean)*inv*g[lane*2]   + be[lane*2];
  o.y = (v.y-mean)*inv*g[lane*2+1] + be[lane*2+1];
  *(float2*)(out + t*128 + lane*2) = o;
}

__global__ __launch_bounds__(256) void k_ln_ffn(const float* __restrict__ in,
    const float* __restrict__ g, const float* __restrict__ be,
    const float* __restrict__ w1, const float* __restrict__ b1,
    const float* __restrict__ w2, const float* __restrict__ b2,
    float* __restrict__ out) {
  int tid = threadIdx.x, lane = tid & 63;
  size_t t = (size_t)blockIdx.x*4 + (tid >> 6);
  const float* row = in + t*128;
  float2 v = *(const float2*)(row + lane*2);
  float s = v.x + v.y, ss = v.x*v.x + v.y*v.y;
  #pragma unroll
  for (int m = 1; m < 64; m <<= 1) { s += __shfl_xor(s, m); ss += __shfl_xor(ss, m); }
  float mean = s*(1.f/128.f);
  float inv = rsqrtf(ss*(1.f/128.f) - mean*mean + 1e-5f);
  float hx = (v.x-mean)*inv*g[lane*2]   + be[lane*2];
  float hy = (v.y-mean)*inv*g[lane*2+1] + be[lane*2+1];
  float hp0 = hx*w1[0*128+lane*2] + hy*w1[0*128+lane*2+1];
  float hp1 = hx*w1[1*128+lane*2] + hy*w1[1*128+lane*2+1];
  float hp2 = hx*w1[2*128+lane*2] + hy*w1[2*128+lane*2+1];
  float hp3 = hx*w1[3*128+lane*2] + hy*w1[3*128+lane*2+1];
  #pragma unroll
  for (int m = 1; m < 64; m <<= 1) {
    hp0 += __shfl_xor(hp0, m); hp1 += __shfl_xor(hp1, m);
    hp2 += __shfl_xor(hp2, m); hp3 += __shfl_xor(hp3, m);
  }
  float hv0, hv1, hv2, hv3;
  { float a = hp0 + b1[0]; hv0 = 0.5f*a*(1.f+erff(a*0.7071067811865476f)); }
  { float a = hp1 + b1[1]; hv1 = 0.5f*a*(1.f+erff(a*0.7071067811865476f)); }
  { float a = hp2 + b1[2]; hv2 = 0.5f*a*(1.f+erff(a*0.7071067811865476f)); }
  { float a = hp3 + b1[3]; hv3 = 0.5f*a*(1.f+erff(a*0.7071067811865476f)); }
  int cx = lane*2, cy = lane*2+1;
  float2 o;
  o.x = hv0*w2[cx*4+0] + hv1*w2[cx*4+1] + hv2*w2[cx*4+2] + hv3*w2[cx*4+3] + b2[cx];
  o.y = hv0*w2[cy*4+0] + hv1*w2[cy*4+1] + hv2*w2[cy*4+2] + hv3*w2[cy*4+3] + b2[cy];
  *(float2*)(out + t*128 + lane*2) = o;
}

// ---------------------------------------------------------------- linear attention
__global__ __launch_bounds__(256) void k_attn1(
    const float* __restrict__ x, const float* __restrict__ qkw,
    const float* __restrict__ qkb, float* __restrict__ qbuf,
    float* __restrict__ akv_g, float* __restrict__ aks_g) {
  __shared__ float WT[64][130];
  __shared__ float kvred[512];
  __shared__ float ksred[64];
  int tid = threadIdx.x;
  for (int i = tid; i < 8192; i += 256) { int o = i >> 6, c = i & 63; WT[c][o] = qkw[i]; }
  for (int i = tid; i < 512; i += 256) kvred[i] = 0.f;
  if (tid < 64) ksred[tid] = 0.f;
  __syncthreads();
  int lane = tid & 63, wv = tid >> 6;
  size_t t0 = (size_t)blockIdx.x * 128;
  int b = (int)(t0 >> 14);
  int pr = lane >> 1;
  float theta = exp2f(-(float)(pr & 15) * THETA_SC);
  bool use_i = pr < 16;
  float qb_q = qkb[lane], qb_k = qkb[lane+64];
  float akv[8];
  #pragma unroll
  for (int d = 0; d < 8; d++) akv[d] = 0.f;
  float aks = 0.f;
  int hbase = lane & 56;
  for (int it = 0; it < 32; it++) {
    size_t t = t0 + (size_t)wv*32 + it;
    float xv = x[t*64 + lane];
    float qa = qb_q, ka = qb_k;
    #pragma unroll
    for (int c2 = 0; c2 < 64; c2++) {
      float xc = __shfl(xv, c2);
      qa += xc * WT[c2][lane];
      ka += xc * WT[c2][lane+64];
    }
    float q = qa > 0.f ? qa + 1.f : expf(qa);
    float k = ka > 0.f ? ka + 1.f : expf(ka);
    int l = (int)(t & (L_-1));
    float pos = use_i ? (float)(l >> 7) : (float)(l & 127);
    float sn, cs; sincosf(pos*theta, &sn, &cs);
    float kp = __shfl_xor(k, 1);
    float kr = (lane & 1) ? (sn*kp + cs*k) : (cs*k - sn*kp);
    #pragma unroll
    for (int d = 0; d < 8; d++) {
      float krd = __shfl(kr, hbase + d);
      akv[d] += krd * xv;
    }
    aks += k;
    qbuf[t*64+lane] = q;
  }
  int h8 = lane >> 3, e = lane & 7;
  #pragma unroll
  for (int d = 0; d < 8; d++)
    atomicAdd(&kvred[h8*64 + d*8 + e], akv[d]);
  atomicAdd(&ksred[lane], aks);
  __syncthreads();
  for (int i = tid; i < 512; i += 256) atomicAdd(&akv_g[b*512 + i], kvred[i]);
  if (tid < 64) atomicAdd(&aks_g[b*64 + tid], ksred[tid]);
}

__global__ __launch_bounds__(256) void k_attn2(
    const float* __restrict__ qbuf, const float* __restrict__ x,
    const float* __restrict__ akv_g, const float* __restrict__ aks_g,
    const float* __restrict__ lw, const float* __restrict__ lb,
    float* __restrict__ out, int coff) {
  __shared__ float kv[512];
  __shared__ float km[64];
  __shared__ float lwl[576];
  int tid = threadIdx.x;
  size_t t0 = (size_t)blockIdx.x * 128;
  int b = (int)(t0 >> 14);
  const float invn = 1.f/16384.f;
  for (int i = tid; i < 512; i += 256) kv[i] = akv_g[b*512 + i]*invn;
  if (tid < 64) km[tid] = aks_g[b*64 + tid]*invn;
  for (int i = tid; i < 576; i += 256) lwl[i] = lw[i];
  __syncthreads();
  int lane = tid & 63, wv = tid >> 6;
  int pr = lane >> 1;
  float theta = exp2f(-(float)(pr & 15) * THETA_SC);
  bool use_i = pr < 16;
  int hbase = lane & 56, e = lane & 7;
  float lbv = lb[lane];
  const float* xb = x + ((size_t)b << 14) * 64;
  for (int it = 0; it < 32; it++) {
    size_t t = t0 + (size_t)wv*32 + it;
    int l = (int)(t & (L_-1));
    int ipos = l >> 7, jpos = l & 127;
    float q = qbuf[t*64 + lane];
    float p = q * km[lane];
    p += __shfl_xor(p, 1); p += __shfl_xor(p, 2); p += __shfl_xor(p, 4);
    float z = 1.f/(p + 1e-6f);
    float pos = use_i ? (float)ipos : (float)jpos;
    float sn, cs; sincosf(pos*theta, &sn, &cs);
    float qp = __shfl_xor(q, 1);
    float qr = (lane & 1) ? (sn*qp + cs*q) : (cs*q - sn*qp);
    float acc = 0.f;
    #pragma unroll
    for (int d = 0; d < 8; d++) {
      float qrd = __shfl(qr, hbase + d);
      acc += qrd * kv[hbase*8 + d*8 + e];
    }
    acc *= z;
    float lp = lbv;
    #pragma unroll
    for (int dh = -1; dh <= 1; dh++) {
      int h2 = ipos + dh; if ((unsigned)h2 >= 128u) continue;
      #pragma unroll
      for (int dw = -1; dw <= 1; dw++) {
        int w2 = jpos + dw; if ((unsigned)w2 >= 128u) continue;
        lp += lwl[lane*9 + (dh+1)*3 + (dw+1)] * xb[((size_t)(h2 << 7) + w2)*64 + lane];
      }
    }
    out[t*128 + coff + lane] = acc + lp;
  }
}

// ---------------------------------------------------------------- launcher
extern "C" void kernel_launch(void* const* d_in, const int* in_sizes, int n_in,
                              void* d_out, int out_size, void* d_ws, size_t ws_size,
                              hipStream_t stream) {
  (void)in_sizes; (void)n_in; (void)out_size;

  // workspace: prefer d_ws, fall back to static global
  float* base;
  if (ws_size >= WSF * sizeof(float)) {
    base = (float*)d_ws;
  } else {
    void* p = nullptr;
    hipGetSymbolAddress(&p, HIP_SYMBOL(g_ws));
    base = (float*)p;
  }
  float* P0 = base;          // x0 (planar, persists)
  float* PA = base + 1*NS;   // xseq / x_s / ACT
  float* PB = base + 2*NS;   // XT shortcut / XT2 / fmt2 planar
  float* PC = base + 3*NS;   // fmt1 planar / XT3 / XT4
  float* PD = base + 4*NS;   // fft im / gemm scratch / xo seq
  float* PF = base + 5*NS;   // CAT / XSS / FFN / xo planar
  float* H0 = base + 6*NS;
  float* H1 = H0 + NH;
  float* H2 = H1 + NH;
  float* WG = H2 + NH;                 // B*8*L
  float* ACC = WG + WGSZ;              // 2304
  float* CW  = ACC + ACCSZ;            // converted weights
  int*   FLG = (int*)(CW + CWSZ);

  // converted-weight offsets (inputs 1..47)
  static const int wsz[47] = {
    16384,128,128,128,1152,128,1024,8,8,8,1024,128,128,128,128,128,
    16384,128,1152,16384,128,3200,16384,128,4096,64,576,64,8192,128,
    576,64,16384,128,1152,128,128,128,512,4,512,128,16384,32768,128,128,128};
  int woff[47]; { int a = 0; for (int i = 0; i < 47; i++){ woff[i] = a; a += wsz[i]; } }
  const float* Wf[47]; for (int i = 0; i < 47; i++) Wf[i] = CW + woff[i];
  const float *c1_w=Wf[0], *c1_b=Wf[1], *c1_g=Wf[2], *c1_be=Wf[3], *cpe1_w=Wf[4],
    *cpe1_b=Wf[5], *fw1=Wf[6], *fb1=Wf[7], *f_g=Wf[8], *f_be=Wf[9], *fw2=Wf[10],
    *fb2=Wf[11], *nbn_g=Wf[12], *nbn_be=Wf[13], *ln1_g=Wf[14], *ln1_b=Wf[15],
    *d3w1=Wf[16], *d3b1=Wf[17], *d3w2=Wf[18], *d5w1=Wf[19], *d5b1=Wf[20],
    *d5w2=Wf[21], *ap_w=Wf[22], *ap_b=Wf[23], *ip2_w=Wf[24], *ip2_b=Wf[25],
    *dwc2_w=Wf[26], *dwc2_b=Wf[27], *qk_w=Wf[28], *qk_b=Wf[29], *lepe_w=Wf[30],
    *lepe_b=Wf[31], *op_w=Wf[32], *op_b=Wf[33], *cpe2_w=Wf[34], *cpe2_b=Wf[35],
    *ln2_g=Wf[36], *ln2_b=Wf[37], *ffn_w1=Wf[38], *ffn_b1=Wf[39], *ffn_w2=Wf[40],
    *ffn_b2=Wf[41], *po_w=Wf[42], *red_w=Wf[43], *red_b=Wf[44], *red_g=Wf[45],
    *red_be=Wf[46];

  const void* x = d_in[0];

  // 0. dtype probe + weight conversion
  k_probe<<<1, 256, 0, stream>>>((const bf16_t*)x, FLG);
  P47 ps; for (int i = 0; i < 47; i++) ps.p[i] = d_in[i+1];
  k_cvt<<<(TOTW+255)/256, 256, 0, stream>>>(ps, FLG, CW);

  dim3 tgrid(512, 4, 4), tblk(32, 8);

  auto fmt = [&](float* tp, float* im) {
    k_fft_row_fwd<<<16384, 256, 0, stream>>>(tp, tp, im);        // in-place re
    k_fft_col<true><<<2048, 256, 0, stream>>>(tp, im);
    k_freq1<<<2048, 256, 0, stream>>>(tp, fw1, fb1, f_g, f_be, WG);
    k_freq2<<<32768, 256, 0, stream>>>(WG, fw2, fb2, tp, im);
    k_fft_col<false><<<2048, 256, 0, stream>>>(tp, im);
    k_fft_row_inv_abs<<<16384, 256, 0, stream>>>(tp, im, nbn_g, nbn_be);
  };

  // 1. x_0 = relu(bn(conv1x1(x)))                         -> P0 (planar)
  k_gemm_planar<128,true,false,false><<<dim3(256,4), 256, 0, stream>>>(
      x, nullptr, c1_w, c1_b, c1_g, c1_be, nullptr, P0, FLG);
  // 2. x -> seq                                           -> PA
  k_p2s<true><<<tgrid, tblk, 0, stream>>>(x, PA, nullptr, nullptr, FLG);
  // 3. xt = x + dw3(x,cpe1)+b                             -> PB (shortcut)
  k_dw3<128,0><<<32768, 256, 0, stream>>>(PA, cpe1_w, cpe1_b, PB);
  // 4. fmt1 -> PC (planar)
  k_s2p<<<tgrid, tblk, 0, stream>>>(PB, PC);
  fmt(PC, PD);
  // 5. x_s = ln(xt)                                       -> PA
  k_ln<<<16384, 256, 0, stream>>>(PB, ln1_g, ln1_b, PA);
  // 6. multi-scale convs
  k_gemm_tok<128,128,1,false><<<1024, 256, 0, stream>>>(PA, nullptr, d3w1, d3b1, PD);
  k_gconv<3><<<16384, 256, 0, stream>>>(PD, d3w2, H0);
  k_gemm_tok<128,128,1,false><<<1024, 256, 0, stream>>>(PA, nullptr, d5w1, d5b1, PD);
  k_gconv<5><<<16384, 256, 0, stream>>>(PD, d5w2, H1);
  k_gemm_tok<128,128,2,false><<<1024, 256, 0, stream>>>(PA, nullptr, ap_w, ap_b, PA); // in-place: ACT
  // 7. branch3 -> attention -> CAT[:, :, 0:64] in PF
  k_gemm_tok<64,64,1,false><<<1024, 256, 0, stream>>>(H0, nullptr, ip2_w, ip2_b, H2);
  k_dw3<64,1><<<16384, 256, 0, stream>>>(H2, dwc2_w, dwc2_b, H0);
  k_zero<<<9, 256, 0, stream>>>(ACC, 2304);
  k_attn1<<<512, 256, 0, stream>>>(H0, qk_w, qk_b, H2, ACC, ACC + B_*512);
  k_attn2<<<512, 256, 0, stream>>>(H2, H0, ACC, ACC + B_*512, lepe_w, lepe_b, PF, 0);
  //    branch5 -> attention -> CAT[:, :, 64:128]
  k_gemm_tok<64,64,1,false><<<1024, 256, 0, stream>>>(H1, nullptr, ip2_w, ip2_b, H2);
  k_dw3<64,1><<<16384, 256, 0, stream>>>(H2, dwc2_w, dwc2_b, H0);
  k_zero<<<9, 256, 0, stream>>>(ACC, 2304);
  k_attn1<<<512, 256, 0, stream>>>(H0, qk_w, qk_b, H2, ACC, ACC + B_*512);
  k_attn2<<<512, 256, 0, stream>>>(H2, H0, ACC, ACC + B_*512, lepe_w, lepe_b, PF, 64);
  // 8. xss = conv1x1(CAT * ACT, op_w)+op_b                -> PF (in-place)
  k_gemm_tok<128,128,1,true><<<1024, 256, 0, stream>>>(PF, PA, op_w, op_b, PF);
  // 9. xt2 = shortcut + xss + fmt1                        -> PB (in-place add1)
  k_p2s<false><<<tgrid, tblk, 0, stream>>>(PC, PB, PB, PF, nullptr);
  // 10. xt3 = xt2 + dw3(xt2,cpe2)+b                       -> PC
  k_dw3<128,0><<<32768, 256, 0, stream>>>(PB, cpe2_w, cpe2_b, PC);
  // 11. fmt2 -> PB (planar)
  k_s2p<<<tgrid, tblk, 0, stream>>>(PC, PB);
  fmt(PB, PD);
  // 12. ffn(ln2(xt3))                                     -> PF
  k_ln_ffn<<<16384, 256, 0, stream>>>(PC, ln2_g, ln2_b, ffn_w1, ffn_b1, ffn_w2, ffn_b2, PF);
  // 13. xt4 = xt3 + ffn + fmt2                            -> PC (in-place add1)
  k_p2s<false><<<tgrid, tblk, 0, stream>>>(PB, PC, PC, PF, nullptr);
  // 14. xo = conv1x1(xt4, po_w)                           -> PD (seq)
  k_gemm_tok<128,128,0,false><<<1024, 256, 0, stream>>>(PC, nullptr, po_w, nullptr, PD);
  // 15. xo -> planar                                      -> PF
  k_s2p<<<tgrid, tblk, 0, stream>>>(PD, PF);
  // 16. out = relu(bn(conv1x1([x0;xo], red))) + x0        -> d_out (dtype per flag)
  k_gemm_planar<256,false,true,true><<<dim3(256,4), 256, 0, stream>>>(
      P0, PF, red_w, red_b, red_g, red_be, P0, d_out, FLG);
}

// Round 4
// 1440.034 us; speedup vs baseline: 1.1509x; 1.1509x over previous
//
#include <hip/hip_runtime.h>
#include <math.h>

typedef unsigned short bf16_t;

#define B_ 4
#define C_ 128
#define H_ 128
#define W_ 128
#define L_ (H_*W_)               // 16384
#define NS  ((size_t)B_*L_*C_)   // 8388608 elems
#define NH  ((size_t)B_*L_*64)
#define NSP ((size_t)L_*C_)
#define PI_F 3.14159265358979323846f
#define BN_INV 0.9999950000374997f   // (1+1e-5)^-0.5
#define THETA_SC 0.8304820237218406f // log2(10000)/16
#define TOTW 157148

__device__ __forceinline__ float ldf(bf16_t v){ return __uint_as_float(((unsigned)v)<<16); }
__device__ __forceinline__ bf16_t f2b(float f){
  unsigned u = __float_as_uint(f);
  u += 0x7fffu + ((u>>16)&1u);     // RNE
  return (bf16_t)(u>>16);
}

// workspace: 6 full seq buffers + 3 half + WG + ACC + converted weights + flag
#define WGSZ ((size_t)B_*8*L_)       // 524288
#define ACCSZ 2304
#define CWSZ 157184
#define WSF (6*NS + 3*NH + WGSZ + ACCSZ + CWSZ + 16)
__device__ float g_ws[WSF];

// ---------------------------------------------------------------- dtype probe + weight convert
__global__ void k_probe(const bf16_t* __restrict__ xb, int* __restrict__ flag){
  __shared__ int vote;
  if (threadIdx.x == 0) vote = 0;
  __syncthreads();
  int bad = 0;
  for (int i = threadIdx.x; i < 2048; i += 256) {
    float v = ldf(xb[2*i]);            // even bf16 index = fp32 mantissa half if storage is fp32
    if (!(fabsf(v) < 1e6f)) bad = 1;   // catches huge / inf / nan
  }
  if (bad) atomicOr(&vote, 1);
  __syncthreads();
  if (threadIdx.x == 0) *flag = vote;  // 1 = fp32 storage, 0 = bf16 storage
}

struct P47 { const void* p[47]; };
__device__ __constant__ int c_wsz[47] = {
  16384,128,128,128,1152,128,1024,8,8,8,1024,128,128,128,128,128,
  16384,128,1152,16384,128,3200,16384,128,4096,64,576,64,8192,128,
  576,64,16384,128,1152,128,128,128,512,4,512,128,16384,32768,128,128,128};

__global__ __launch_bounds__(256) void k_cvt(P47 ps, const int* __restrict__ flagp,
                                             float* __restrict__ dst){
  int g = blockIdx.x*256 + threadIdx.x;
  if (g >= TOTW) return;
  int fl = *flagp;
  int idx = 0, off = g;
  while (off >= c_wsz[idx]) { off -= c_wsz[idx]; idx++; }
  const void* s = ps.p[idx];
  dst[g] = fl ? ((const float*)s)[off] : ldf(((const bf16_t*)s)[off]);
}

__global__ void k_zero(float* p, int n){
  int i = blockIdx.x*256 + threadIdx.x;
  if (i < n) p[i] = 0.f;
}

// ---------------------------------------------------------------- FFT core
__device__ __forceinline__ void fft128_fwd(float& lor, float& loi, float& hir, float& hii, int lane) {
  {
    float s, c; sincosf(-PI_F * (float)lane * (1.f/64.f), &s, &c);
    float ar = lor, ai = loi;
    float dr = ar - hir, di = ai - hii;
    lor = ar + hir; loi = ai + hii;
    hir = dr*c - di*s; hii = dr*s + di*c;
  }
  #pragma unroll
  for (int m = 32; m >= 1; m >>= 1) {
    int k = lane & (m-1);
    float s, c; sincosf(-PI_F * (float)k / (float)m, &s, &c);
    bool up = (lane & m) != 0;
    {
      float orr = __shfl_xor(lor, m), oii = __shfl_xor(loi, m);
      float sr = lor + orr, si = loi + oii;
      float dr = orr - lor, di = oii - loi;
      float tr = dr*c - di*s, ti = dr*s + di*c;
      lor = up ? tr : sr; loi = up ? ti : si;
    }
    {
      float orr = __shfl_xor(hir, m), oii = __shfl_xor(hii, m);
      float sr = hir + orr, si = hii + oii;
      float dr = orr - hir, di = oii - hii;
      float tr = dr*c - di*s, ti = dr*s + di*c;
      hir = up ? tr : sr; hii = up ? ti : si;
    }
  }
}

__device__ __forceinline__ void fft128_inv(float& lor, float& loi, float& hir, float& hii, int lane) {
  #pragma unroll
  for (int m = 1; m <= 32; m <<= 1) {
    int k = lane & (m-1);
    float s, c; sincosf(PI_F * (float)k / (float)m, &s, &c);
    bool up = (lane & m) != 0;
    {
      float orr = __shfl_xor(lor, m), oii = __shfl_xor(loi, m);
      float qr = orr*c - oii*s, qi = orr*s + oii*c;
      float lo_r = lor + qr, lo_i = loi + qi;
      float mr = lor*c - loi*s, mi = lor*s + loi*c;
      float up_r = orr - mr, up_i = oii - mi;
      lor = up ? up_r : lo_r; loi = up ? up_i : lo_i;
    }
    {
      float orr = __shfl_xor(hir, m), oii = __shfl_xor(hii, m);
      float qr = orr*c - oii*s, qi = orr*s + oii*c;
      float lo_r = hir + qr, lo_i = hii + qi;
      float mr = hir*c - hii*s, mi = hir*s + hii*c;
      float up_r = orr - mr, up_i = oii - mi;
      hir = up ? up_r : lo_r; hii = up ? up_i : lo_i;
    }
  }
  {
    float s, c; sincosf(PI_F * (float)lane * (1.f/64.f), &s, &c);
    float qr = hir*c - hii*s, qi = hir*s + hii*c;
    float pr = lor, pi = loi;
    lor = pr + qr; loi = pi + qi;
    hir = pr - qr; hii = pi - qi;
  }
}

__global__ __launch_bounds__(256) void k_fft_row_fwd(const float* __restrict__ in,
    float* __restrict__ re, float* __restrict__ im) {
  int lane = threadIdx.x & 63;
  size_t row = (size_t)blockIdx.x*4 + (threadIdx.x >> 6);
  size_t base = row * 128;
  float lor = in[base + lane], loi = 0.f;
  float hir = in[base + lane + 64], hii = 0.f;
  fft128_fwd(lor, loi, hir, hii, lane);
  re[base+lane] = lor; im[base+lane] = loi;
  re[base+lane+64] = hir; im[base+lane+64] = hii;
}

__global__ __launch_bounds__(256) void k_fft_row_inv_abs(
    float* __restrict__ re, float* __restrict__ im,
    const float* __restrict__ ng, const float* __restrict__ nbe) {
  int lane = threadIdx.x & 63;
  size_t row = (size_t)blockIdx.x*4 + (threadIdx.x >> 6);
  size_t base = row * 128;
  float lor = re[base+lane], loi = im[base+lane];
  float hir = re[base+lane+64], hii = im[base+lane+64];
  fft128_inv(lor, loi, hir, hii, lane);
  int c = (int)((row >> 7) & 127);
  float sg = ng[c] * BN_INV, sb = nbe[c];
  float v0 = sqrtf(lor*lor + loi*loi) * (1.f/128.f);
  float v1 = sqrtf(hir*hir + hii*hii) * (1.f/128.f);
  re[base+lane]    = fmaxf(v0*sg + sb, 0.f);
  re[base+lane+64] = fmaxf(v1*sg + sb, 0.f);
}

template<bool FWD>
__global__ __launch_bounds__(256) void k_fft_col(float* __restrict__ re, float* __restrict__ im) {
  __shared__ float Lre[128][33];
  __shared__ float Lim[128][33];
  int tid = threadIdx.x;
  size_t img = blockIdx.x >> 2;
  int w0 = (blockIdx.x & 3) * 32;
  float* rp = re + img * (size_t)L_ + w0;
  float* ip = im + img * (size_t)L_ + w0;
  for (int i = tid; i < 4096; i += 256) {
    int h = i >> 5, wl = i & 31;
    Lre[h][wl] = rp[(size_t)h*W_ + wl];
    Lim[h][wl] = ip[(size_t)h*W_ + wl];
  }
  __syncthreads();
  int lane = tid & 63, wv = tid >> 6;
  for (int i = 0; i < 8; i++) {
    int col = wv*8 + i;
    float lor = Lre[lane][col], loi = Lim[lane][col];
    float hir = Lre[lane+64][col], hii = Lim[lane+64][col];
    if (FWD) {
      fft128_fwd(lor, loi, hir, hii, lane);
    } else {
      fft128_inv(lor, loi, hir, hii, lane);
      lor *= (1.f/128.f); loi *= (1.f/128.f); hir *= (1.f/128.f); hii *= (1.f/128.f);
    }
    Lre[lane][col]=lor; Lim[lane][col]=loi;
    Lre[lane+64][col]=hir; Lim[lane+64][col]=hii;
  }
  __syncthreads();
  for (int i = tid; i < 4096; i += 256) {
    int h = i >> 5, wl = i & 31;
    rp[(size_t)h*W_ + wl] = Lre[h][wl];
    ip[(size_t)h*W_ + wl] = Lim[h][wl];
  }
}

// ---------------------------------------------------------------- freq-domain convs
__global__ __launch_bounds__(256) void k_freq1(const float* __restrict__ tre,
    const float* __restrict__ fw1, const float* __restrict__ fb1,
    const float* __restrict__ fg, const float* __restrict__ fbe,
    float* __restrict__ wg1) {
  __shared__ float w1s[1024];
  int tid = threadIdx.x;
  for (int i = tid; i < 1024; i += 256) w1s[i] = fw1[i];
  __syncthreads();
  size_t g = (size_t)blockIdx.x*256 + tid;   // (b,o,p)
  int p = (int)(g & (L_-1));
  int o = (int)((g >> 14) & 7);
  int b = (int)(g >> 17);
  const float* tp = tre + (size_t)b*128*L_ + p;
  const float* wrow = w1s + o*128;
  float acc = 0.f;
  for (int c = 0; c < 128; c++) acc += wrow[c] * tp[(size_t)c*L_];
  float v = (acc + fb1[o]) * (fg[o]*BN_INV) + fbe[o];
  wg1[g] = fmaxf(v, 0.f);
}

__global__ __launch_bounds__(256) void k_freq2(const float* __restrict__ wg1,
    const float* __restrict__ fw2, const float* __restrict__ fb2,
    float* __restrict__ re, float* __restrict__ im) {
  __shared__ float w2s[1024];
  __shared__ float b2s[128];
  int tid = threadIdx.x;
  for (int i = tid; i < 1024; i += 256) w2s[i] = fw2[i];
  if (tid < 128) b2s[tid] = fb2[tid];
  __syncthreads();
  size_t g = (size_t)blockIdx.x*256 + tid;   // (b,c,p)
  int p = (int)(g & (L_-1));
  int c = (int)((g >> 14) & 127);
  int b = (int)(g >> 21);
  const float* wp = wg1 + (size_t)b*8*L_ + p;
  float acc = b2s[c];
  #pragma unroll
  for (int o = 0; o < 8; o++) acc += w2s[c*8+o] * wp[(size_t)o*L_];
  float wgt = 1.f/(1.f+expf(-acc));
  re[g] *= wgt; im[g] *= wgt;
}

// ---------------------------------------------------------------- transposes
template<bool DUAL>
__global__ void k_p2s(const void* __restrict__ src, float* __restrict__ dst,
                      const float* __restrict__ add1, const float* __restrict__ add2,
                      const int* __restrict__ flagp) {
  __shared__ float tile[32][33];
  int fl = DUAL ? *flagp : 1;
  int b = blockIdx.z;
  int p0 = blockIdx.x*32, c0 = blockIdx.y*32;
  int tx = threadIdx.x, ty = threadIdx.y;
  size_t base_in = (size_t)b*NSP;
  #pragma unroll
  for (int k = 0; k < 4; k++) {
    size_t off = base_in + (size_t)(c0+ty+8*k)*L_ + p0 + tx;
    float v;
    if (DUAL && !fl) v = ldf(((const bf16_t*)src)[off]);
    else             v = ((const float*)src)[off];
    tile[ty+8*k][tx] = v;
  }
  __syncthreads();
  size_t base = (size_t)b*NSP;
  #pragma unroll
  for (int k = 0; k < 4; k++) {
    size_t idx = base + (size_t)(p0+ty+8*k)*C_ + c0 + tx;
    float v = tile[tx][ty+8*k];
    if (add1) v += add1[idx];
    if (add2) v += add2[idx];
    dst[idx] = v;
  }
}

__global__ void k_s2p(const float* __restrict__ src, float* __restrict__ dst) {
  __shared__ float tile[32][33];
  int b = blockIdx.z;
  int p0 = blockIdx.x*32, c0 = blockIdx.y*32;
  int tx = threadIdx.x, ty = threadIdx.y;
  const float* sp = src + (size_t)b*NSP;
  #pragma unroll
  for (int k = 0; k < 4; k++)
    tile[ty+8*k][tx] = sp[(size_t)(p0+ty+8*k)*C_ + c0 + tx];
  __syncthreads();
  float* dp = dst + (size_t)b*NSP;
  #pragma unroll
  for (int k = 0; k < 4; k++)
    dp[(size_t)(c0+ty+8*k)*L_ + p0 + tx] = tile[tx][ty+8*k];
}

// ---------------------------------------------------------------- depthwise convs (NHWC)
template<int CC, int MODE>  // MODE 0: out = in + dw + b ; MODE 1: out = silu(dw + b)
__global__ __launch_bounds__(256) void k_dw3(const float* __restrict__ in,
    const float* __restrict__ w, const float* __restrict__ bias,
    float* __restrict__ out) {
  __shared__ float wl[CC*9];
  int tid = threadIdx.x;
  for (int i = tid; i < CC*9; i += 256) wl[i] = w[i];
  __syncthreads();
  size_t g = (size_t)blockIdx.x*256 + tid;
  int c = (int)(g % CC);
  size_t t = g / CC;
  int wp_ = (int)(t % W_);
  int hp = (int)((t / W_) % H_);
  int b = (int)(t / (size_t)L_);
  const float* ip = in + (size_t)b * L_ * CC + c;
  float acc = bias[c];
  #pragma unroll
  for (int dh = -1; dh <= 1; dh++) {
    int h2 = hp + dh;
    if ((unsigned)h2 >= (unsigned)H_) continue;
    #pragma unroll
    for (int dw = -1; dw <= 1; dw++) {
      int w2 = wp_ + dw;
      if ((unsigned)w2 >= (unsigned)W_) continue;
      acc += wl[c*9 + (dh+1)*3 + (dw+1)] * ip[((size_t)h2*W_ + w2)*CC];
    }
  }
  if (MODE == 0) out[g] = in[g] + acc;
  else           out[g] = acc / (1.f + expf(-acc));
}

template<int K>
__global__ __launch_bounds__(256) void k_gconv(const float* __restrict__ in,
    const float* __restrict__ w, float* __restrict__ out) {
  __shared__ float wl[64*2*K*K];
  int tid = threadIdx.x;
  for (int i = tid; i < 64*2*K*K; i += 256) wl[i] = w[i];
  __syncthreads();
  size_t g = (size_t)blockIdx.x*256 + tid;
  int oc = (int)(g & 63);
  size_t t = g >> 6;
  int wp_ = (int)(t & (W_-1));
  int hp = (int)((t >> 7) & (H_-1));
  int b = (int)(t >> 14);
  const float* ip = in + (size_t)b*L_*128 + 2*oc;
  const int P = K/2;
  float acc = 0.f;
  #pragma unroll
  for (int kh = 0; kh < K; kh++) {
    int h2 = hp + kh - P;
    if ((unsigned)h2 >= (unsigned)H_) continue;
    #pragma unroll
    for (int kw = 0; kw < K; kw++) {
      int w2 = wp_ + kw - P;
      if ((unsigned)w2 >= (unsigned)W_) continue;
      const float* px = ip + ((size_t)h2*W_ + w2)*128;
      acc += wl[(oc*2+0)*(K*K) + kh*K + kw]*px[0]
           + wl[(oc*2+1)*(K*K) + kh*K + kw]*px[1];
    }
  }
  out[g] = acc;
}

// ---------------------------------------------------------------- token GEMM (seq 1x1 conv)
// In-place (out==in) safe. EPI 0:none 1:bias 2:bias+silu 3:bias+elu+1
template<int CIN, int COUT, int EPI, bool MUL>
__global__ __launch_bounds__(256) void k_gemm_tok(
    const float* __restrict__ in, const float* __restrict__ mulp,
    const float* __restrict__ Wm, const float* __restrict__ bias,
    float* __restrict__ out) {
  __shared__ __align__(16) float As[16][68];
  __shared__ __align__(16) float Bs[16][COUT+4];
  constexpr int RN = COUT/16;
  int tid = threadIdx.x;
  size_t t0 = (size_t)blockIdx.x * 64;
  int to = tid & 15, og = tid >> 4;
  float acc[4][RN];
  #pragma unroll
  for (int j = 0; j < 4; j++)
    #pragma unroll
    for (int i = 0; i < RN; i++) acc[j][i] = 0.f;
  for (int kc = 0; kc < CIN; kc += 16) {
    {
      int tt = tid >> 2, kq = (tid & 3) * 4;
      size_t base = (t0 + tt) * CIN + kc + kq;
      float4 v = *(const float4*)(in + base);
      if (MUL) {
        float4 m = *(const float4*)(mulp + base);
        v.x *= m.x; v.y *= m.y; v.z *= m.z; v.w *= m.w;
      }
      As[kq+0][tt]=v.x; As[kq+1][tt]=v.y; As[kq+2][tt]=v.z; As[kq+3][tt]=v.w;
    }
    if (tid < 2*COUT) {
      int o = tid >> 1, k8 = (tid & 1) * 8;
      const float* wp = Wm + (size_t)o * CIN + kc + k8;
      float4 v0 = *(const float4*)wp;
      float4 v1 = *(const float4*)(wp + 4);
      Bs[k8+0][o]=v0.x; Bs[k8+1][o]=v0.y; Bs[k8+2][o]=v0.z; Bs[k8+3][o]=v0.w;
      Bs[k8+4][o]=v1.x; Bs[k8+5][o]=v1.y; Bs[k8+6][o]=v1.z; Bs[k8+7][o]=v1.w;
    }
    __syncthreads();
    #pragma unroll
    for (int kk = 0; kk < 16; kk++) {
      float4 a = *(const float4*)&As[kk][to*4];
      float bv[RN];
      #pragma unroll
      for (int i = 0; i < RN; i++) bv[i] = Bs[kk][og*RN+i];
      #pragma unroll
      for (int i = 0; i < RN; i++) {
        acc[0][i] += a.x*bv[i];
        acc[1][i] += a.y*bv[i];
        acc[2][i] += a.z*bv[i];
        acc[3][i] += a.w*bv[i];
      }
    }
    __syncthreads();
  }
  #pragma unroll
  for (int j = 0; j < 4; j++) {
    size_t t = t0 + to*4 + j;
    #pragma unroll
    for (int i = 0; i < RN; i++) {
      int o = og*RN + i;
      float v = acc[j][i];
      if (EPI >= 1) v += bias[o];
      if (EPI == 2) v = v / (1.f + expf(-v));
      if (EPI == 3) v = v > 0.f ? v + 1.f : expf(v);   // elu(v)+1
      out[t*COUT + o] = v;
    }
  }
}

// ---------------------------------------------------------------- planar GEMM (c1 / red)
template<int CIN, bool DUALIN, bool DUALOUT, bool ADDX>
__global__ __launch_bounds__(256) void k_gemm_planar(
    const void* __restrict__ in1, const float* __restrict__ in2f,
    const float* __restrict__ Wm, const float* __restrict__ bias,
    const float* __restrict__ gam, const float* __restrict__ bet,
    const float* __restrict__ addp, void* __restrict__ out,
    const int* __restrict__ flagp) {
  constexpr int COUT = 128;
  __shared__ __align__(16) float As[16][68];
  __shared__ __align__(16) float Bs[16][COUT+4];
  int fl = (DUALIN || DUALOUT) ? *flagp : 1;
  int tid = threadIdx.x;
  int b = blockIdx.y;
  size_t p0 = (size_t)blockIdx.x * 64;
  int to = tid & 15, og = tid >> 4;
  float acc[4][8];
  #pragma unroll
  for (int j = 0; j < 4; j++)
    #pragma unroll
    for (int i = 0; i < 8; i++) acc[j][i] = 0.f;
  for (int kc = 0; kc < CIN; kc += 16) {
    {
      int kk = tid >> 4, pq = (tid & 15) * 4;
      int k = kc + kk;
      if (CIN == 128 || k < 128) {
        size_t eoff = ((size_t)b*128 + k)*L_ + p0 + pq;
        if (DUALIN && !fl) {
          ushort4 v = *(const ushort4*)((const bf16_t*)in1 + eoff);
          As[kk][pq+0]=ldf((bf16_t)v.x); As[kk][pq+1]=ldf((bf16_t)v.y);
          As[kk][pq+2]=ldf((bf16_t)v.z); As[kk][pq+3]=ldf((bf16_t)v.w);
        } else {
          *(float4*)&As[kk][pq] = *(const float4*)((const float*)in1 + eoff);
        }
      } else {
        size_t eoff = ((size_t)b*128 + (k-128))*L_ + p0 + pq;
        *(float4*)&As[kk][pq] = *(const float4*)(in2f + eoff);
      }
    }
    {
      int o = tid >> 1, k8 = (tid & 1) * 8;
      const float* wp = Wm + (size_t)o * CIN + kc + k8;
      float4 v0 = *(const float4*)wp;
      float4 v1 = *(const float4*)(wp + 4);
      Bs[k8+0][o]=v0.x; Bs[k8+1][o]=v0.y; Bs[k8+2][o]=v0.z; Bs[k8+3][o]=v0.w;
      Bs[k8+4][o]=v1.x; Bs[k8+5][o]=v1.y; Bs[k8+6][o]=v1.z; Bs[k8+7][o]=v1.w;
    }
    __syncthreads();
    #pragma unroll
    for (int kk = 0; kk < 16; kk++) {
      float4 a = *(const float4*)&As[kk][to*4];
      float bv[8];
      #pragma unroll
      for (int i = 0; i < 8; i++) bv[i] = Bs[kk][og*8+i];
      #pragma unroll
      for (int i = 0; i < 8; i++) {
        acc[0][i] += a.x*bv[i];
        acc[1][i] += a.y*bv[i];
        acc[2][i] += a.z*bv[i];
        acc[3][i] += a.w*bv[i];
      }
    }
    __syncthreads();
  }
  #pragma unroll
  for (int j = 0; j < 4; j++) {
    #pragma unroll
    for (int i = 0; i < 8; i++) {
      int o = og*8 + i;
      float v = acc[j][i] + bias[o];
      v = v * (gam[o]*BN_INV) + bet[o];
      v = fmaxf(v, 0.f);
      size_t idx = ((size_t)b*128 + o)*L_ + p0 + to*4 + j;
      if (ADDX) v += addp[idx];
      if (DUALOUT && !fl) ((bf16_t*)out)[idx] = f2b(v);
      else                ((float*)out)[idx]  = v;
    }
  }
}

// ---------------------------------------------------------------- LN / LN+FFN
__global__ __launch_bounds__(256) void k_ln(const float* __restrict__ in,
    const float* __restrict__ g, const float* __restrict__ be, float* __restrict__ out) {
  int tid = threadIdx.x, lane = tid & 63;
  size_t t = (size_t)blockIdx.x*4 + (tid >> 6);
  const float* row = in + t*128;
  float2 v = *(const float2*)(row + lane*2);
  float s = v.x + v.y, ss = v.x*v.x + v.y*v.y;
  #pragma unroll
  for (int m = 1; m < 64; m <<= 1) { s += __shfl_xor(s, m); ss += __shfl_xor(ss, m); }
  float mean = s*(1.f/128.f);
  float inv = rsqrtf(ss*(1.f/128.f) - mean*mean + 1e-5f);
  float2 o;
  o.x = (v.x-mean)*inv*g[lane*2]   + be[lane*2];
  o.y = (v.y-mean)*inv*g[lane*2+1] + be[lane*2+1];
  *(float2*)(out + t*128 + lane*2) = o;
}

__global__ __launch_bounds__(256) void k_ln_ffn(const float* __restrict__ in,
    const float* __restrict__ g, const float* __restrict__ be,
    const float* __restrict__ w1, const float* __restrict__ b1,
    const float* __restrict__ w2, const float* __restrict__ b2,
    float* __restrict__ out) {
  int tid = threadIdx.x, lane = tid & 63;
  size_t t = (size_t)blockIdx.x*4 + (tid >> 6);
  const float* row = in + t*128;
  float2 v = *(const float2*)(row + lane*2);
  float s = v.x + v.y, ss = v.x*v.x + v.y*v.y;
  #pragma unroll
  for (int m = 1; m < 64; m <<= 1) { s += __shfl_xor(s, m); ss += __shfl_xor(ss, m); }
  float mean = s*(1.f/128.f);
  float inv = rsqrtf(ss*(1.f/128.f) - mean*mean + 1e-5f);
  float hx = (v.x-mean)*inv*g[lane*2]   + be[lane*2];
  float hy = (v.y-mean)*inv*g[lane*2+1] + be[lane*2+1];
  float hp0 = hx*w1[0*128+lane*2] + hy*w1[0*128+lane*2+1];
  float hp1 = hx*w1[1*128+lane*2] + hy*w1[1*128+lane*2+1];
  float hp2 = hx*w1[2*128+lane*2] + hy*w1[2*128+lane*2+1];
  float hp3 = hx*w1[3*128+lane*2] + hy*w1[3*128+lane*2+1];
  #pragma unroll
  for (int m = 1; m < 64; m <<= 1) {
    hp0 += __shfl_xor(hp0, m); hp1 += __shfl_xor(hp1, m);
    hp2 += __shfl_xor(hp2, m); hp3 += __shfl_xor(hp3, m);
  }
  float hv0, hv1, hv2, hv3;
  { float a = hp0 + b1[0]; hv0 = 0.5f*a*(1.f+erff(a*0.7071067811865476f)); }
  { float a = hp1 + b1[1]; hv1 = 0.5f*a*(1.f+erff(a*0.7071067811865476f)); }
  { float a = hp2 + b1[2]; hv2 = 0.5f*a*(1.f+erff(a*0.7071067811865476f)); }
  { float a = hp3 + b1[3]; hv3 = 0.5f*a*(1.f+erff(a*0.7071067811865476f)); }
  int cx = lane*2, cy = lane*2+1;
  float2 o;
  o.x = hv0*w2[cx*4+0] + hv1*w2[cx*4+1] + hv2*w2[cx*4+2] + hv3*w2[cx*4+3] + b2[cx];
  o.y = hv0*w2[cy*4+0] + hv1*w2[cy*4+1] + hv2*w2[cy*4+2] + hv3*w2[cy*4+3] + b2[cy];
  *(float2*)(out + t*128 + lane*2) = o;
}

// ---------------------------------------------------------------- linear attention
// k_kv: rank-8 KV + k_mean accumulation. qk: (B,L,128) with elu+1 applied
// (q = [...,:64], k = [...,64:]). v: (B,L,64). 1024 blocks x 64 tokens.
__global__ __launch_bounds__(256) void k_kv(
    const float* __restrict__ qk, const float* __restrict__ v,
    float* __restrict__ akv_g, float* __restrict__ aks_g) {
  __shared__ float kvred[512];
  __shared__ float ksred[64];
  int tid = threadIdx.x;
  for (int i = tid; i < 512; i += 256) kvred[i] = 0.f;
  if (tid < 64) ksred[tid] = 0.f;
  __syncthreads();
  int lane = tid & 63, wv = tid >> 6;
  size_t t0 = (size_t)blockIdx.x * 64;
  int b = (int)(t0 >> 14);
  int pr = lane >> 1;
  float theta = exp2f(-(float)(pr & 15) * THETA_SC);
  bool use_i = pr < 16;
  int hbase = lane & 56;
  float akv[8];
  #pragma unroll
  for (int d = 0; d < 8; d++) akv[d] = 0.f;
  float aks = 0.f;
  for (int it = 0; it < 16; it++) {
    size_t t = t0 + (size_t)wv*16 + it;
    float k = qk[t*128 + 64 + lane];
    float xv = v[t*64 + lane];
    int l = (int)(t & (L_-1));
    float pos = use_i ? (float)(l >> 7) : (float)(l & 127);
    float sn, cs; sincosf(pos*theta, &sn, &cs);
    float kp = __shfl_xor(k, 1);
    float kr = (lane & 1) ? (sn*kp + cs*k) : (cs*k - sn*kp);
    #pragma unroll
    for (int d = 0; d < 8; d++) {
      float krd = __shfl(kr, hbase + d);
      akv[d] += krd * xv;
    }
    aks += k;
  }
  int h8 = lane >> 3, e = lane & 7;
  #pragma unroll
  for (int d = 0; d < 8; d++)
    atomicAdd(&kvred[h8*64 + d*8 + e], akv[d]);
  atomicAdd(&ksred[lane], aks);
  __syncthreads();
  for (int i = tid; i < 512; i += 256) atomicAdd(&akv_g[b*512 + i], kvred[i]);
  if (tid < 64) atomicAdd(&aks_g[b*64 + tid], ksred[tid]);
}

// k_attn2: out[t, coff+lane] = rope(q)·kv * z + lepe(v). 2048 blocks x 32 tokens.
__global__ __launch_bounds__(256) void k_attn2(
    const float* __restrict__ qk, const float* __restrict__ x,
    const float* __restrict__ akv_g, const float* __restrict__ aks_g,
    const float* __restrict__ lw, const float* __restrict__ lb,
    float* __restrict__ out, int coff) {
  __shared__ float kv[512];
  __shared__ float km[64];
  __shared__ float lwl[576];
  int tid = threadIdx.x;
  size_t t0 = (size_t)blockIdx.x * 32;
  int b = (int)(t0 >> 14);
  const float invn = 1.f/16384.f;
  for (int i = tid; i < 512; i += 256) kv[i] = akv_g[b*512 + i]*invn;
  if (tid < 64) km[tid] = aks_g[b*64 + tid]*invn;
  for (int i = tid; i < 576; i += 256) lwl[i] = lw[i];
  __syncthreads();
  int lane = tid & 63, wv = tid >> 6;
  int pr = lane >> 1;
  float theta = exp2f(-(float)(pr & 15) * THETA_SC);
  bool use_i = pr < 16;
  int hbase = lane & 56, e = lane & 7;
  float lbv = lb[lane];
  const float* xb = x + ((size_t)b << 14) * 64;
  for (int it = 0; it < 8; it++) {
    size_t t = t0 + (size_t)wv*8 + it;
    int l = (int)(t & (L_-1));
    int ipos = l >> 7, jpos = l & 127;
    float q = qk[t*128 + lane];
    float p = q * km[lane];
    p += __shfl_xor(p, 1); p += __shfl_xor(p, 2); p += __shfl_xor(p, 4);
    float z = 1.f/(p + 1e-6f);
    float pos = use_i ? (float)ipos : (float)jpos;
    float sn, cs; sincosf(pos*theta, &sn, &cs);
    float qp = __shfl_xor(q, 1);
    float qr = (lane & 1) ? (sn*qp + cs*q) : (cs*q - sn*qp);
    float acc = 0.f;
    #pragma unroll
    for (int d = 0; d < 8; d++) {
      float qrd = __shfl(qr, hbase + d);
      acc += qrd * kv[hbase*8 + d*8 + e];
    }
    acc *= z;
    float lp = lbv;
    #pragma unroll
    for (int dh = -1; dh <= 1; dh++) {
      int h2 = ipos + dh; if ((unsigned)h2 >= 128u) continue;
      #pragma unroll
      for (int dw = -1; dw <= 1; dw++) {
        int w2 = jpos + dw; if ((unsigned)w2 >= 128u) continue;
        lp += lwl[lane*9 + (dh+1)*3 + (dw+1)] * xb[((size_t)(h2 << 7) + w2)*64 + lane];
      }
    }
    out[t*128 + coff + lane] = acc + lp;
  }
}

// ---------------------------------------------------------------- launcher
extern "C" void kernel_launch(void* const* d_in, const int* in_sizes, int n_in,
                              void* d_out, int out_size, void* d_ws, size_t ws_size,
                              hipStream_t stream) {
  (void)in_sizes; (void)n_in; (void)out_size;

  float* base;
  if (ws_size >= WSF * sizeof(float)) {
    base = (float*)d_ws;
  } else {
    void* p = nullptr;
    hipGetSymbolAddress(&p, HIP_SYMBOL(g_ws));
    base = (float*)p;
  }
  float* P0 = base;          // x0 (planar, persists)
  float* PA = base + 1*NS;   // xseq / x_s / ACT
  float* PB = base + 2*NS;   // XT shortcut / XT2 / fmt2 planar
  float* PC = base + 3*NS;   // fmt1 planar / XT3 / XT4
  float* PD = base + 4*NS;   // gemm scratch / QK / xo seq
  float* PF = base + 5*NS;   // fft im / CAT / XSS / FFN / xo planar
  float* H0 = base + 6*NS;
  float* H1 = H0 + NH;
  float* H2 = H1 + NH;
  float* WG = H2 + NH;                 // B*8*L
  float* ACC = WG + WGSZ;              // 2304
  float* CW  = ACC + ACCSZ;            // converted weights
  int*   FLG = (int*)(CW + CWSZ);

  static const int wsz[47] = {
    16384,128,128,128,1152,128,1024,8,8,8,1024,128,128,128,128,128,
    16384,128,1152,16384,128,3200,16384,128,4096,64,576,64,8192,128,
    576,64,16384,128,1152,128,128,128,512,4,512,128,16384,32768,128,128,128};
  int woff[47]; { int a = 0; for (int i = 0; i < 47; i++){ woff[i] = a; a += wsz[i]; } }
  const float* Wf[47]; for (int i = 0; i < 47; i++) Wf[i] = CW + woff[i];
  const float *c1_w=Wf[0], *c1_b=Wf[1], *c1_g=Wf[2], *c1_be=Wf[3], *cpe1_w=Wf[4],
    *cpe1_b=Wf[5], *fw1=Wf[6], *fb1=Wf[7], *f_g=Wf[8], *f_be=Wf[9], *fw2=Wf[10],
    *fb2=Wf[11], *nbn_g=Wf[12], *nbn_be=Wf[13], *ln1_g=Wf[14], *ln1_b=Wf[15],
    *d3w1=Wf[16], *d3b1=Wf[17], *d3w2=Wf[18], *d5w1=Wf[19], *d5b1=Wf[20],
    *d5w2=Wf[21], *ap_w=Wf[22], *ap_b=Wf[23], *ip2_w=Wf[24], *ip2_b=Wf[25],
    *dwc2_w=Wf[26], *dwc2_b=Wf[27], *qk_w=Wf[28], *qk_b=Wf[29], *lepe_w=Wf[30],
    *lepe_b=Wf[31], *op_w=Wf[32], *op_b=Wf[33], *cpe2_w=Wf[34], *cpe2_b=Wf[35],
    *ln2_g=Wf[36], *ln2_b=Wf[37], *ffn_w1=Wf[38], *ffn_b1=Wf[39], *ffn_w2=Wf[40],
    *ffn_b2=Wf[41], *po_w=Wf[42], *red_w=Wf[43], *red_b=Wf[44], *red_g=Wf[45],
    *red_be=Wf[46];

  const void* x = d_in[0];

  // 0. dtype probe + weight conversion
  k_probe<<<1, 256, 0, stream>>>((const bf16_t*)x, FLG);
  P47 ps; for (int i = 0; i < 47; i++) ps.p[i] = d_in[i+1];
  k_cvt<<<(TOTW+255)/256, 256, 0, stream>>>(ps, FLG, CW);

  dim3 tgrid(512, 4, 4), tblk(32, 8);

  auto fmt = [&](float* tp, float* im) {
    k_fft_row_fwd<<<16384, 256, 0, stream>>>(tp, tp, im);        // in-place re
    k_fft_col<true><<<2048, 256, 0, stream>>>(tp, im);
    k_freq1<<<2048, 256, 0, stream>>>(tp, fw1, fb1, f_g, f_be, WG);
    k_freq2<<<32768, 256, 0, stream>>>(WG, fw2, fb2, tp, im);
    k_fft_col<false><<<2048, 256, 0, stream>>>(tp, im);
    k_fft_row_inv_abs<<<16384, 256, 0, stream>>>(tp, im, nbn_g, nbn_be);
  };

  // attention branch: BR (NHWC 64ch) in brin; writes CAT column coff of PF
  auto attn = [&](const float* brin, float* qkbuf, int coff) {
    k_zero<<<9, 256, 0, stream>>>(ACC, 2304);
    k_gemm_tok<64,128,3,false><<<1024, 256, 0, stream>>>(brin, nullptr, qk_w, qk_b, qkbuf);
    k_kv<<<1024, 256, 0, stream>>>(qkbuf, brin, ACC, ACC + B_*512);
    k_attn2<<<2048, 256, 0, stream>>>(qkbuf, brin, ACC, ACC + B_*512, lepe_w, lepe_b, PF, coff);
  };

  // 1. x_0 = relu(bn(conv1x1(x)))                         -> P0 (planar)
  k_gemm_planar<128,true,false,false><<<dim3(256,4), 256, 0, stream>>>(
      x, nullptr, c1_w, c1_b, c1_g, c1_be, nullptr, P0, FLG);
  // 2. x -> seq                                           -> PA
  k_p2s<true><<<tgrid, tblk, 0, stream>>>(x, PA, nullptr, nullptr, FLG);
  // 3. xt = x + dw3(x,cpe1)+b                             -> PB (shortcut)
  k_dw3<128,0><<<32768, 256, 0, stream>>>(PA, cpe1_w, cpe1_b, PB);
  // 4. fmt1 -> PC (planar)
  k_s2p<<<tgrid, tblk, 0, stream>>>(PB, PC);
  fmt(PC, PF);
  // 5. x_s = ln(xt)                                       -> PA
  k_ln<<<16384, 256, 0, stream>>>(PB, ln1_g, ln1_b, PA);
  // 6. multi-scale convs
  k_gemm_tok<128,128,1,false><<<1024, 256, 0, stream>>>(PA, nullptr, d3w1, d3b1, PD);
  k_gconv<3><<<16384, 256, 0, stream>>>(PD, d3w2, H0);
  k_gemm_tok<128,128,1,false><<<1024, 256, 0, stream>>>(PA, nullptr, d5w1, d5b1, PD);
  k_gconv<5><<<16384, 256, 0, stream>>>(PD, d5w2, H1);
  k_gemm_tok<128,128,2,false><<<1024, 256, 0, stream>>>(PA, nullptr, ap_w, ap_b, PA); // in-place: ACT
  // 7. branch3 -> attention -> CAT[:, :, 0:64] in PF
  k_gemm_tok<64,64,1,false><<<1024, 256, 0, stream>>>(H0, nullptr, ip2_w, ip2_b, H2);
  k_dw3<64,1><<<16384, 256, 0, stream>>>(H2, dwc2_w, dwc2_b, H0);
  attn(H0, PD, 0);
  //    branch5 -> attention -> CAT[:, :, 64:128]
  k_gemm_tok<64,64,1,false><<<1024, 256, 0, stream>>>(H1, nullptr, ip2_w, ip2_b, H2);
  k_dw3<64,1><<<16384, 256, 0, stream>>>(H2, dwc2_w, dwc2_b, H1);
  attn(H1, PD, 64);
  // 8. xss = conv1x1(CAT * ACT, op_w)+op_b                -> PF (in-place)
  k_gemm_tok<128,128,1,true><<<1024, 256, 0, stream>>>(PF, PA, op_w, op_b, PF);
  // 9. xt2 = shortcut + xss + fmt1                        -> PB (in-place add1)
  k_p2s<false><<<tgrid, tblk, 0, stream>>>(PC, PB, PB, PF, nullptr);
  // 10. xt3 = xt2 + dw3(xt2,cpe2)+b                       -> PC
  k_dw3<128,0><<<32768, 256, 0, stream>>>(PB, cpe2_w, cpe2_b, PC);
  // 11. fmt2 -> PB (planar)
  k_s2p<<<tgrid, tblk, 0, stream>>>(PC, PB);
  fmt(PB, PD);
  // 12. ffn(ln2(xt3))                                     -> PF
  k_ln_ffn<<<16384, 256, 0, stream>>>(PC, ln2_g, ln2_b, ffn_w1, ffn_b1, ffn_w2, ffn_b2, PF);
  // 13. xt4 = xt3 + ffn + fmt2                            -> PC (in-place add1)
  k_p2s<false><<<tgrid, tblk, 0, stream>>>(PB, PC, PC, PF, nullptr);
  // 14. xo = conv1x1(xt4, po_w)                           -> PD (seq)
  k_gemm_tok<128,128,0,false><<<1024, 256, 0, stream>>>(PC, nullptr, po_w, nullptr, PD);
  // 15. xo -> planar                                      -> PF
  k_s2p<<<tgrid, tblk, 0, stream>>>(PD, PF);
  // 16. out = relu(bn(conv1x1([x0;xo], red))) + x0        -> d_out (dtype per flag)
  k_gemm_planar<256,false,true,true><<<dim3(256,4), 256, 0, stream>>>(
      P0, PF, red_w, red_b, red_g, red_be, P0, d_out, FLG);
}

// Round 5
// 1372.226 us; speedup vs baseline: 1.2078x; 1.0494x over previous
//
#include <hip/hip_runtime.h>
#include <math.h>

typedef unsigned short bf16_t;
typedef __attribute__((ext_vector_type(8))) short short8;
typedef __attribute__((ext_vector_type(4))) float f32x4;

#define B_ 4
#define C_ 128
#define H_ 128
#define W_ 128
#define L_ (H_*W_)               // 16384
#define NS  ((size_t)B_*L_*C_)   // 8388608 elems
#define NH  ((size_t)B_*L_*64)
#define NSP ((size_t)L_*C_)
#define PI_F 3.14159265358979323846f
#define BN_INV 0.9999950000374997f   // (1+1e-5)^-0.5
#define THETA_SC 0.8304820237218406f // log2(10000)/16
#define TOTW 157148

__device__ __forceinline__ float ldf(bf16_t v){ return __uint_as_float(((unsigned)v)<<16); }
__device__ __forceinline__ bf16_t f2b(float f){
  unsigned u = __float_as_uint(f);
  u += 0x7fffu + ((u>>16)&1u);     // RNE
  return (bf16_t)(u>>16);
}

// workspace: 6 full seq buffers + 3 half + WG + ACC + converted weights + flag
#define WGSZ ((size_t)B_*8*L_)       // 524288
#define ACCSZ 2304
#define CWSZ 157184
#define WSF (6*NS + 3*NH + WGSZ + ACCSZ + CWSZ + 16)
__device__ float g_ws[WSF];

// ---------------------------------------------------------------- dtype probe + weight convert
__global__ void k_probe(const bf16_t* __restrict__ xb, int* __restrict__ flag){
  __shared__ int vote;
  if (threadIdx.x == 0) vote = 0;
  __syncthreads();
  int bad = 0;
  for (int i = threadIdx.x; i < 2048; i += 256) {
    float v = ldf(xb[2*i]);
    if (!(fabsf(v) < 1e6f)) bad = 1;
  }
  if (bad) atomicOr(&vote, 1);
  __syncthreads();
  if (threadIdx.x == 0) *flag = vote;  // 1 = fp32 storage, 0 = bf16 storage
}

struct P47 { const void* p[47]; };
__device__ __constant__ int c_wsz[47] = {
  16384,128,128,128,1152,128,1024,8,8,8,1024,128,128,128,128,128,
  16384,128,1152,16384,128,3200,16384,128,4096,64,576,64,8192,128,
  576,64,16384,128,1152,128,128,128,512,4,512,128,16384,32768,128,128,128};

__global__ __launch_bounds__(256) void k_cvt(P47 ps, const int* __restrict__ flagp,
                                             float* __restrict__ dst){
  int g = blockIdx.x*256 + threadIdx.x;
  if (g >= TOTW) return;
  int fl = *flagp;
  int idx = 0, off = g;
  while (off >= c_wsz[idx]) { off -= c_wsz[idx]; idx++; }
  const void* s = ps.p[idx];
  dst[g] = fl ? ((const float*)s)[off] : ldf(((const bf16_t*)s)[off]);
}

__global__ void k_zero(float* p, int n){
  int i = blockIdx.x*256 + threadIdx.x;
  if (i < n) p[i] = 0.f;
}

// ---------------------------------------------------------------- FFT core
__device__ __forceinline__ void fft128_fwd(float& lor, float& loi, float& hir, float& hii, int lane) {
  {
    float s, c; sincosf(-PI_F * (float)lane * (1.f/64.f), &s, &c);
    float ar = lor, ai = loi;
    float dr = ar - hir, di = ai - hii;
    lor = ar + hir; loi = ai + hii;
    hir = dr*c - di*s; hii = dr*s + di*c;
  }
  #pragma unroll
  for (int m = 32; m >= 1; m >>= 1) {
    int k = lane & (m-1);
    float s, c; sincosf(-PI_F * (float)k / (float)m, &s, &c);
    bool up = (lane & m) != 0;
    {
      float orr = __shfl_xor(lor, m), oii = __shfl_xor(loi, m);
      float sr = lor + orr, si = loi + oii;
      float dr = orr - lor, di = oii - loi;
      float tr = dr*c - di*s, ti = dr*s + di*c;
      lor = up ? tr : sr; loi = up ? ti : si;
    }
    {
      float orr = __shfl_xor(hir, m), oii = __shfl_xor(hii, m);
      float sr = hir + orr, si = hii + oii;
      float dr = orr - hir, di = oii - hii;
      float tr = dr*c - di*s, ti = dr*s + di*c;
      hir = up ? tr : sr; hii = up ? ti : si;
    }
  }
}

__device__ __forceinline__ void fft128_inv(float& lor, float& loi, float& hir, float& hii, int lane) {
  #pragma unroll
  for (int m = 1; m <= 32; m <<= 1) {
    int k = lane & (m-1);
    float s, c; sincosf(PI_F * (float)k / (float)m, &s, &c);
    bool up = (lane & m) != 0;
    {
      float orr = __shfl_xor(lor, m), oii = __shfl_xor(loi, m);
      float qr = orr*c - oii*s, qi = orr*s + oii*c;
      float lo_r = lor + qr, lo_i = loi + qi;
      float mr = lor*c - loi*s, mi = lor*s + loi*c;
      float up_r = orr - mr, up_i = oii - mi;
      lor = up ? up_r : lo_r; loi = up ? up_i : lo_i;
    }
    {
      float orr = __shfl_xor(hir, m), oii = __shfl_xor(hii, m);
      float qr = orr*c - oii*s, qi = orr*s + oii*c;
      float lo_r = hir + qr, lo_i = hii + qi;
      float mr = hir*c - hii*s, mi = hir*s + hii*c;
      float up_r = orr - mr, up_i = oii - mi;
      hir = up ? up_r : lo_r; hii = up ? up_i : lo_i;
    }
  }
  {
    float s, c; sincosf(PI_F * (float)lane * (1.f/64.f), &s, &c);
    float qr = hir*c - hii*s, qi = hir*s + hii*c;
    float pr = lor, pi = loi;
    lor = pr + qr; loi = pi + qi;
    hir = pr - qr; hii = pi - qi;
  }
}

__global__ __launch_bounds__(256) void k_fft_row_fwd(const float* __restrict__ in,
    float* __restrict__ re, float* __restrict__ im) {
  int lane = threadIdx.x & 63;
  size_t row = (size_t)blockIdx.x*4 + (threadIdx.x >> 6);
  size_t base = row * 128;
  float lor = in[base + lane], loi = 0.f;
  float hir = in[base + lane + 64], hii = 0.f;
  fft128_fwd(lor, loi, hir, hii, lane);
  re[base+lane] = lor; im[base+lane] = loi;
  re[base+lane+64] = hir; im[base+lane+64] = hii;
}

__global__ __launch_bounds__(256) void k_fft_row_inv_abs(
    float* __restrict__ re, float* __restrict__ im,
    const float* __restrict__ ng, const float* __restrict__ nbe) {
  int lane = threadIdx.x & 63;
  size_t row = (size_t)blockIdx.x*4 + (threadIdx.x >> 6);
  size_t base = row * 128;
  float lor = re[base+lane], loi = im[base+lane];
  float hir = re[base+lane+64], hii = im[base+lane+64];
  fft128_inv(lor, loi, hir, hii, lane);
  int c = (int)((row >> 7) & 127);
  float sg = ng[c] * BN_INV, sb = nbe[c];
  float v0 = sqrtf(lor*lor + loi*loi) * (1.f/128.f);
  float v1 = sqrtf(hir*hir + hii*hii) * (1.f/128.f);
  re[base+lane]    = fmaxf(v0*sg + sb, 0.f);
  re[base+lane+64] = fmaxf(v1*sg + sb, 0.f);
}

template<bool FWD>
__global__ __launch_bounds__(256) void k_fft_col(float* __restrict__ re, float* __restrict__ im) {
  __shared__ float Lre[128][33];
  __shared__ float Lim[128][33];
  int tid = threadIdx.x;
  size_t img = blockIdx.x >> 2;
  int w0 = (blockIdx.x & 3) * 32;
  float* rp = re + img * (size_t)L_ + w0;
  float* ip = im + img * (size_t)L_ + w0;
  for (int i = tid; i < 4096; i += 256) {
    int h = i >> 5, wl = i & 31;
    Lre[h][wl] = rp[(size_t)h*W_ + wl];
    Lim[h][wl] = ip[(size_t)h*W_ + wl];
  }
  __syncthreads();
  int lane = tid & 63, wv = tid >> 6;
  for (int i = 0; i < 8; i++) {
    int col = wv*8 + i;
    float lor = Lre[lane][col], loi = Lim[lane][col];
    float hir = Lre[lane+64][col], hii = Lim[lane+64][col];
    if (FWD) {
      fft128_fwd(lor, loi, hir, hii, lane);
    } else {
      fft128_inv(lor, loi, hir, hii, lane);
      lor *= (1.f/128.f); loi *= (1.f/128.f); hir *= (1.f/128.f); hii *= (1.f/128.f);
    }
    Lre[lane][col]=lor; Lim[lane][col]=loi;
    Lre[lane+64][col]=hir; Lim[lane+64][col]=hii;
  }
  __syncthreads();
  for (int i = tid; i < 4096; i += 256) {
    int h = i >> 5, wl = i & 31;
    rp[(size_t)h*W_ + wl] = Lre[h][wl];
    ip[(size_t)h*W_ + wl] = Lim[h][wl];
  }
}

// ---------------------------------------------------------------- freq-domain convs
// one thread per (b,p); computes all 8 outputs (reads each input column once)
__global__ __launch_bounds__(256) void k_freq1(const float* __restrict__ tre,
    const float* __restrict__ fw1, const float* __restrict__ fb1,
    const float* __restrict__ fg, const float* __restrict__ fbe,
    float* __restrict__ wg1) {
  __shared__ float w1s[1024];
  int tid = threadIdx.x;
  for (int i = tid; i < 1024; i += 256) w1s[i] = fw1[i];
  __syncthreads();
  size_t g = (size_t)blockIdx.x*256 + tid;   // (b,p): 65536 threads
  int p = (int)(g & (L_-1));
  int b = (int)(g >> 14);
  const float* tp = tre + (size_t)b*128*L_ + p;
  float acc[8];
  #pragma unroll
  for (int o = 0; o < 8; o++) acc[o] = 0.f;
  for (int c = 0; c < 128; c++) {
    float v = tp[(size_t)c*L_];
    #pragma unroll
    for (int o = 0; o < 8; o++) acc[o] += w1s[o*128+c]*v;
  }
  size_t ob = (size_t)b*8*L_ + p;
  #pragma unroll
  for (int o = 0; o < 8; o++) {
    float v = (acc[o] + fb1[o]) * (fg[o]*BN_INV) + fbe[o];
    wg1[ob + (size_t)o*L_] = fmaxf(v, 0.f);
  }
}

__global__ __launch_bounds__(256) void k_freq2(const float* __restrict__ wg1,
    const float* __restrict__ fw2, const float* __restrict__ fb2,
    float* __restrict__ re, float* __restrict__ im) {
  __shared__ float w2s[1024];
  __shared__ float b2s[128];
  int tid = threadIdx.x;
  for (int i = tid; i < 1024; i += 256) w2s[i] = fw2[i];
  if (tid < 128) b2s[tid] = fb2[tid];
  __syncthreads();
  size_t g = (size_t)blockIdx.x*256 + tid;   // (b,c,p)
  int p = (int)(g & (L_-1));
  int c = (int)((g >> 14) & 127);
  int b = (int)(g >> 21);
  const float* wp = wg1 + (size_t)b*8*L_ + p;
  float acc = b2s[c];
  #pragma unroll
  for (int o = 0; o < 8; o++) acc += w2s[c*8+o] * wp[(size_t)o*L_];
  float wgt = 1.f/(1.f+expf(-acc));
  re[g] *= wgt; im[g] *= wgt;
}

// ---------------------------------------------------------------- transposes
template<bool DUAL>
__global__ void k_p2s(const void* __restrict__ src, float* __restrict__ dst,
                      const float* __restrict__ add1, const float* __restrict__ add2,
                      const int* __restrict__ flagp) {
  __shared__ float tile[32][33];
  int fl = DUAL ? *flagp : 1;
  int b = blockIdx.z;
  int p0 = blockIdx.x*32, c0 = blockIdx.y*32;
  int tx = threadIdx.x, ty = threadIdx.y;
  size_t base_in = (size_t)b*NSP;
  #pragma unroll
  for (int k = 0; k < 4; k++) {
    size_t off = base_in + (size_t)(c0+ty+8*k)*L_ + p0 + tx;
    float v;
    if (DUAL && !fl) v = ldf(((const bf16_t*)src)[off]);
    else             v = ((const float*)src)[off];
    tile[ty+8*k][tx] = v;
  }
  __syncthreads();
  size_t base = (size_t)b*NSP;
  #pragma unroll
  for (int k = 0; k < 4; k++) {
    size_t idx = base + (size_t)(p0+ty+8*k)*C_ + c0 + tx;
    float v = tile[tx][ty+8*k];
    if (add1) v += add1[idx];
    if (add2) v += add2[idx];
    dst[idx] = v;
  }
}

__global__ void k_s2p(const float* __restrict__ src, float* __restrict__ dst) {
  __shared__ float tile[32][33];
  int b = blockIdx.z;
  int p0 = blockIdx.x*32, c0 = blockIdx.y*32;
  int tx = threadIdx.x, ty = threadIdx.y;
  const float* sp = src + (size_t)b*NSP;
  #pragma unroll
  for (int k = 0; k < 4; k++)
    tile[ty+8*k][tx] = sp[(size_t)(p0+ty+8*k)*C_ + c0 + tx];
  __syncthreads();
  float* dp = dst + (size_t)b*NSP;
  #pragma unroll
  for (int k = 0; k < 4; k++)
    dp[(size_t)(c0+ty+8*k)*L_ + p0 + tx] = tile[tx][ty+8*k];
}

// ---------------------------------------------------------------- depthwise convs (NHWC)
template<int CC, int MODE>  // MODE 0: out = in + dw + b ; MODE 1: out = silu(dw + b)
__global__ __launch_bounds__(256) void k_dw3(const float* __restrict__ in,
    const float* __restrict__ w, const float* __restrict__ bias,
    float* __restrict__ out) {
  __shared__ float wl[CC*9];
  int tid = threadIdx.x;
  for (int i = tid; i < CC*9; i += 256) wl[i] = w[i];
  __syncthreads();
  size_t g = (size_t)blockIdx.x*256 + tid;
  int c = (int)(g % CC);
  size_t t = g / CC;
  int wp_ = (int)(t % W_);
  int hp = (int)((t / W_) % H_);
  int b = (int)(t / (size_t)L_);
  const float* ip = in + (size_t)b * L_ * CC + c;
  float acc = bias[c];
  #pragma unroll
  for (int dh = -1; dh <= 1; dh++) {
    int h2 = hp + dh;
    if ((unsigned)h2 >= (unsigned)H_) continue;
    #pragma unroll
    for (int dw = -1; dw <= 1; dw++) {
      int w2 = wp_ + dw;
      if ((unsigned)w2 >= (unsigned)W_) continue;
      acc += wl[c*9 + (dh+1)*3 + (dw+1)] * ip[((size_t)h2*W_ + w2)*CC];
    }
  }
  if (MODE == 0) out[g] = in[g] + acc;
  else           out[g] = acc / (1.f + expf(-acc));
}

// grouped conv, 2 in-ch per out-ch; LDS weights transposed to [tap][128] so
// lane reads are consecutive float2 (2-way aliasing = free); input as float2.
template<int K>
__global__ __launch_bounds__(256) void k_gconv(const float* __restrict__ in,
    const float* __restrict__ w, float* __restrict__ out) {
  __shared__ float wl[K*K*128];
  int tid = threadIdx.x;
  for (int i = tid; i < 128*K*K; i += 256) {
    int ch = i / (K*K), tap = i % (K*K);
    wl[tap*128 + ch] = w[ch*K*K + tap];
  }
  __syncthreads();
  size_t g = (size_t)blockIdx.x*256 + tid;
  int oc = (int)(g & 63);
  size_t t = g >> 6;
  int wp_ = (int)(t & (W_-1));
  int hp = (int)((t >> 7) & (H_-1));
  int b = (int)(t >> 14);
  const float* ip = in + (size_t)b*L_*128 + 2*oc;
  const int P = K/2;
  float acc = 0.f;
  #pragma unroll
  for (int kh = 0; kh < K; kh++) {
    int h2 = hp + kh - P;
    if ((unsigned)h2 >= (unsigned)H_) continue;
    #pragma unroll
    for (int kw = 0; kw < K; kw++) {
      int w2 = wp_ + kw - P;
      if ((unsigned)w2 >= (unsigned)W_) continue;
      float2 px = *(const float2*)(ip + ((size_t)h2*W_ + w2)*128);
      float2 ww = *(const float2*)&wl[(kh*K + kw)*128 + 2*oc];
      acc += ww.x*px.x + ww.y*px.y;
    }
  }
  out[g] = acc;
}

// ---------------------------------------------------------------- MFMA token GEMM (seq 1x1 conv)
// out[t,o] = epi(sum_c in[t,c]*W[o,c]). Both operands K-contiguous.
// Wave = 16 tokens x COUT; block = 4 waves = 64 tokens. W staged bf16 in LDS
// (pitch CIN+8 shorts -> row stride = 4 banks -> only free 2-way aliasing).
// In-place safe per-wave (wave reads its own tokens fully before storing).
// EPI 0:none 1:bias 2:bias+silu 3:bias+elu+1
template<int CIN, int COUT, int EPI, bool MUL>
__global__ __launch_bounds__(256) void k_mfma_tok(
    const float* __restrict__ in, const float* __restrict__ mulp,
    const float* __restrict__ Wm, const float* __restrict__ bias,
    float* __restrict__ out) {
  constexpr int PITCH = CIN + 8;
  constexpr int NO = COUT/16;
  __shared__ __align__(16) short Wl[COUT*PITCH];
  __shared__ float bl[COUT];
  int tid = threadIdx.x;
  for (int i = tid; i < COUT*(CIN/4); i += 256) {
    int o = i / (CIN/4), kq = (i % (CIN/4))*4;
    float4 w = *(const float4*)(Wm + (size_t)o*CIN + kq);
    short* d = &Wl[o*PITCH + kq];
    d[0]=(short)f2b(w.x); d[1]=(short)f2b(w.y); d[2]=(short)f2b(w.z); d[3]=(short)f2b(w.w);
  }
  if (tid < COUT) bl[tid] = (EPI >= 1) ? bias[tid] : 0.f;
  __syncthreads();
  int lane = tid & 63, wv = tid >> 6;
  int m = lane & 15, q = lane >> 4;
  size_t t0 = (size_t)blockIdx.x*64 + (size_t)wv*16;
  f32x4 acc[NO];
  #pragma unroll
  for (int i = 0; i < NO; i++) acc[i] = (f32x4){0.f,0.f,0.f,0.f};
  for (int k0 = 0; k0 < CIN; k0 += 32) {
    const float* ap = in + (t0 + m)*CIN + k0 + q*8;
    float4 a0 = *(const float4*)ap;
    float4 a1 = *(const float4*)(ap + 4);
    if (MUL) {
      const float* mp = mulp + (t0 + m)*CIN + k0 + q*8;
      float4 m0 = *(const float4*)mp;
      float4 m1 = *(const float4*)(mp + 4);
      a0.x*=m0.x; a0.y*=m0.y; a0.z*=m0.z; a0.w*=m0.w;
      a1.x*=m1.x; a1.y*=m1.y; a1.z*=m1.z; a1.w*=m1.w;
    }
    union { short s[8]; short8 v; } af;
    af.s[0]=(short)f2b(a0.x); af.s[1]=(short)f2b(a0.y);
    af.s[2]=(short)f2b(a0.z); af.s[3]=(short)f2b(a0.w);
    af.s[4]=(short)f2b(a1.x); af.s[5]=(short)f2b(a1.y);
    af.s[6]=(short)f2b(a1.z); af.s[7]=(short)f2b(a1.w);
    #pragma unroll
    for (int o = 0; o < NO; o++) {
      short8 bf = *(const short8*)&Wl[(o*16 + m)*PITCH + k0 + q*8];
      acc[o] = __builtin_amdgcn_mfma_f32_16x16x32_bf16(af.v, bf, acc[o], 0, 0, 0);
    }
  }
  // C/D: col = lane&15 (N/o), row = (lane>>4)*4 + reg (M/token)
  #pragma unroll
  for (int o = 0; o < NO; o++) {
    #pragma unroll
    for (int r = 0; r < 4; r++) {
      int row = q*4 + r;
      float v = acc[o][r];
      if (EPI >= 1) v += bl[o*16 + m];
      if (EPI == 2) v = v / (1.f + expf(-v));
      if (EPI == 3) v = v > 0.f ? v + 1.f : expf(v);
      out[(t0 + row)*COUT + o*16 + m] = v;
    }
  }
}

// ---------------------------------------------------------------- planar GEMM (c1 / red)
template<int CIN, bool DUALIN, bool DUALOUT, bool ADDX>
__global__ __launch_bounds__(256) void k_gemm_planar(
    const void* __restrict__ in1, const float* __restrict__ in2f,
    const float* __restrict__ Wm, const float* __restrict__ bias,
    const float* __restrict__ gam, const float* __restrict__ bet,
    const float* __restrict__ addp, void* __restrict__ out,
    const int* __restrict__ flagp) {
  constexpr int COUT = 128;
  __shared__ __align__(16) float As[16][68];
  __shared__ __align__(16) float Bs[16][COUT+4];
  int fl = (DUALIN || DUALOUT) ? *flagp : 1;
  int tid = threadIdx.x;
  int b = blockIdx.y;
  size_t p0 = (size_t)blockIdx.x * 64;
  int to = tid & 15, og = tid >> 4;
  float acc[4][8];
  #pragma unroll
  for (int j = 0; j < 4; j++)
    #pragma unroll
    for (int i = 0; i < 8; i++) acc[j][i] = 0.f;
  for (int kc = 0; kc < CIN; kc += 16) {
    {
      int kk = tid >> 4, pq = (tid & 15) * 4;
      int k = kc + kk;
      if (CIN == 128 || k < 128) {
        size_t eoff = ((size_t)b*128 + k)*L_ + p0 + pq;
        if (DUALIN && !fl) {
          ushort4 v = *(const ushort4*)((const bf16_t*)in1 + eoff);
          As[kk][pq+0]=ldf((bf16_t)v.x); As[kk][pq+1]=ldf((bf16_t)v.y);
          As[kk][pq+2]=ldf((bf16_t)v.z); As[kk][pq+3]=ldf((bf16_t)v.w);
        } else {
          *(float4*)&As[kk][pq] = *(const float4*)((const float*)in1 + eoff);
        }
      } else {
        size_t eoff = ((size_t)b*128 + (k-128))*L_ + p0 + pq;
        *(float4*)&As[kk][pq] = *(const float4*)(in2f + eoff);
      }
    }
    {
      int o = tid >> 1, k8 = (tid & 1) * 8;
      const float* wp = Wm + (size_t)o * CIN + kc + k8;
      float4 v0 = *(const float4*)wp;
      float4 v1 = *(const float4*)(wp + 4);
      Bs[k8+0][o]=v0.x; Bs[k8+1][o]=v0.y; Bs[k8+2][o]=v0.z; Bs[k8+3][o]=v0.w;
      Bs[k8+4][o]=v1.x; Bs[k8+5][o]=v1.y; Bs[k8+6][o]=v1.z; Bs[k8+7][o]=v1.w;
    }
    __syncthreads();
    #pragma unroll
    for (int kk = 0; kk < 16; kk++) {
      float4 a = *(const float4*)&As[kk][to*4];
      float bv[8];
      #pragma unroll
      for (int i = 0; i < 8; i++) bv[i] = Bs[kk][og*8+i];
      #pragma unroll
      for (int i = 0; i < 8; i++) {
        acc[0][i] += a.x*bv[i];
        acc[1][i] += a.y*bv[i];
        acc[2][i] += a.z*bv[i];
        acc[3][i] += a.w*bv[i];
      }
    }
    __syncthreads();
  }
  #pragma unroll
  for (int j = 0; j < 4; j++) {
    #pragma unroll
    for (int i = 0; i < 8; i++) {
      int o = og*8 + i;
      float v = acc[j][i] + bias[o];
      v = v * (gam[o]*BN_INV) + bet[o];
      v = fmaxf(v, 0.f);
      size_t idx = ((size_t)b*128 + o)*L_ + p0 + to*4 + j;
      if (ADDX) v += addp[idx];
      if (DUALOUT && !fl) ((bf16_t*)out)[idx] = f2b(v);
      else                ((float*)out)[idx]  = v;
    }
  }
}

// ---------------------------------------------------------------- LN / LN+FFN
__global__ __launch_bounds__(256) void k_ln(const float* __restrict__ in,
    const float* __restrict__ g, const float* __restrict__ be, float* __restrict__ out) {
  int tid = threadIdx.x, lane = tid & 63;
  size_t t = (size_t)blockIdx.x*4 + (tid >> 6);
  const float* row = in + t*128;
  float2 v = *(const float2*)(row + lane*2);
  float s = v.x + v.y, ss = v.x*v.x + v.y*v.y;
  #pragma unroll
  for (int m = 1; m < 64; m <<= 1) { s += __shfl_xor(s, m); ss += __shfl_xor(ss, m); }
  float mean = s*(1.f/128.f);
  float inv = rsqrtf(ss*(1.f/128.f) - mean*mean + 1e-5f);
  float2 o;
  o.x = (v.x-mean)*inv*g[lane*2]   + be[lane*2];
  o.y = (v.y-mean)*inv*g[lane*2+1] + be[lane*2+1];
  *(float2*)(out + t*128 + lane*2) = o;
}

__global__ __launch_bounds__(256) void k_ln_ffn(const float* __restrict__ in,
    const float* __restrict__ g, const float* __restrict__ be,
    const float* __restrict__ w1, const float* __restrict__ b1,
    const float* __restrict__ w2, const float* __restrict__ b2,
    float* __restrict__ out) {
  int tid = threadIdx.x, lane = tid & 63;
  size_t t = (size_t)blockIdx.x*4 + (tid >> 6);
  const float* row = in + t*128;
  float2 v = *(const float2*)(row + lane*2);
  float s = v.x + v.y, ss = v.x*v.x + v.y*v.y;
  #pragma unroll
  for (int m = 1; m < 64; m <<= 1) { s += __shfl_xor(s, m); ss += __shfl_xor(ss, m); }
  float mean = s*(1.f/128.f);
  float inv = rsqrtf(ss*(1.f/128.f) - mean*mean + 1e-5f);
  float hx = (v.x-mean)*inv*g[lane*2]   + be[lane*2];
  float hy = (v.y-mean)*inv*g[lane*2+1] + be[lane*2+1];
  float hp0 = hx*w1[0*128+lane*2] + hy*w1[0*128+lane*2+1];
  float hp1 = hx*w1[1*128+lane*2] + hy*w1[1*128+lane*2+1];
  float hp2 = hx*w1[2*128+lane*2] + hy*w1[2*128+lane*2+1];
  float hp3 = hx*w1[3*128+lane*2] + hy*w1[3*128+lane*2+1];
  #pragma unroll
  for (int m = 1; m < 64; m <<= 1) {
    hp0 += __shfl_xor(hp0, m); hp1 += __shfl_xor(hp1, m);
    hp2 += __shfl_xor(hp2, m); hp3 += __shfl_xor(hp3, m);
  }
  float hv0, hv1, hv2, hv3;
  { float a = hp0 + b1[0]; hv0 = 0.5f*a*(1.f+erff(a*0.7071067811865476f)); }
  { float a = hp1 + b1[1]; hv1 = 0.5f*a*(1.f+erff(a*0.7071067811865476f)); }
  { float a = hp2 + b1[2]; hv2 = 0.5f*a*(1.f+erff(a*0.7071067811865476f)); }
  { float a = hp3 + b1[3]; hv3 = 0.5f*a*(1.f+erff(a*0.7071067811865476f)); }
  int cx = lane*2, cy = lane*2+1;
  float2 o;
  o.x = hv0*w2[cx*4+0] + hv1*w2[cx*4+1] + hv2*w2[cx*4+2] + hv3*w2[cx*4+3] + b2[cx];
  o.y = hv0*w2[cy*4+0] + hv1*w2[cy*4+1] + hv2*w2[cy*4+2] + hv3*w2[cy*4+3] + b2[cy];
  *(float2*)(out + t*128 + lane*2) = o;
}

// ---------------------------------------------------------------- linear attention
__global__ __launch_bounds__(256) void k_kv(
    const float* __restrict__ qk, const float* __restrict__ v,
    float* __restrict__ akv_g, float* __restrict__ aks_g) {
  __shared__ float kvred[512];
  __shared__ float ksred[64];
  int tid = threadIdx.x;
  for (int i = tid; i < 512; i += 256) kvred[i] = 0.f;
  if (tid < 64) ksred[tid] = 0.f;
  __syncthreads();
  int lane = tid & 63, wv = tid >> 6;
  size_t t0 = (size_t)blockIdx.x * 64;
  int b = (int)(t0 >> 14);
  int pr = lane >> 1;
  float theta = exp2f(-(float)(pr & 15) * THETA_SC);
  bool use_i = pr < 16;
  int hbase = lane & 56;
  float akv[8];
  #pragma unroll
  for (int d = 0; d < 8; d++) akv[d] = 0.f;
  float aks = 0.f;
  for (int it = 0; it < 16; it++) {
    size_t t = t0 + (size_t)wv*16 + it;
    float k = qk[t*128 + 64 + lane];
    float xv = v[t*64 + lane];
    int l = (int)(t & (L_-1));
    float pos = use_i ? (float)(l >> 7) : (float)(l & 127);
    float sn, cs; sincosf(pos*theta, &sn, &cs);
    float kp = __shfl_xor(k, 1);
    float kr = (lane & 1) ? (sn*kp + cs*k) : (cs*k - sn*kp);
    #pragma unroll
    for (int d = 0; d < 8; d++) {
      float krd = __shfl(kr, hbase + d);
      akv[d] += krd * xv;
    }
    aks += k;
  }
  int h8 = lane >> 3, e = lane & 7;
  #pragma unroll
  for (int d = 0; d < 8; d++)
    atomicAdd(&kvred[h8*64 + d*8 + e], akv[d]);
  atomicAdd(&ksred[lane], aks);
  __syncthreads();
  for (int i = tid; i < 512; i += 256) atomicAdd(&akv_g[b*512 + i], kvred[i]);
  if (tid < 64) atomicAdd(&aks_g[b*64 + tid], ksred[tid]);
}

__global__ __launch_bounds__(256) void k_attn2(
    const float* __restrict__ qk, const float* __restrict__ x,
    const float* __restrict__ akv_g, const float* __restrict__ aks_g,
    const float* __restrict__ lw, const float* __restrict__ lb,
    float* __restrict__ out, int coff) {
  __shared__ float kv[512];
  __shared__ float km[64];
  __shared__ float lwl[576];
  int tid = threadIdx.x;
  size_t t0 = (size_t)blockIdx.x * 32;
  int b = (int)(t0 >> 14);
  const float invn = 1.f/16384.f;
  for (int i = tid; i < 512; i += 256) kv[i] = akv_g[b*512 + i]*invn;
  if (tid < 64) km[tid] = aks_g[b*64 + tid]*invn;
  for (int i = tid; i < 576; i += 256) lwl[i] = lw[i];
  __syncthreads();
  int lane = tid & 63, wv = tid >> 6;
  int pr = lane >> 1;
  float theta = exp2f(-(float)(pr & 15) * THETA_SC);
  bool use_i = pr < 16;
  int hbase = lane & 56, e = lane & 7;
  float lbv = lb[lane];
  const float* xb = x + ((size_t)b << 14) * 64;
  for (int it = 0; it < 8; it++) {
    size_t t = t0 + (size_t)wv*8 + it;
    int l = (int)(t & (L_-1));
    int ipos = l >> 7, jpos = l & 127;
    float q = qk[t*128 + lane];
    float p = q * km[lane];
    p += __shfl_xor(p, 1); p += __shfl_xor(p, 2); p += __shfl_xor(p, 4);
    float z = 1.f/(p + 1e-6f);
    float pos = use_i ? (float)ipos : (float)jpos;
    float sn, cs; sincosf(pos*theta, &sn, &cs);
    float qp = __shfl_xor(q, 1);
    float qr = (lane & 1) ? (sn*qp + cs*q) : (cs*q - sn*qp);
    float acc = 0.f;
    #pragma unroll
    for (int d = 0; d < 8; d++) {
      float qrd = __shfl(qr, hbase + d);
      acc += qrd * kv[hbase*8 + d*8 + e];
    }
    acc *= z;
    float lp = lbv;
    #pragma unroll
    for (int dh = -1; dh <= 1; dh++) {
      int h2 = ipos + dh; if ((unsigned)h2 >= 128u) continue;
      #pragma unroll
      for (int dw = -1; dw <= 1; dw++) {
        int w2 = jpos + dw; if ((unsigned)w2 >= 128u) continue;
        lp += lwl[lane*9 + (dh+1)*3 + (dw+1)] * xb[((size_t)(h2 << 7) + w2)*64 + lane];
      }
    }
    out[t*128 + coff + lane] = acc + lp;
  }
}

// ---------------------------------------------------------------- launcher
extern "C" void kernel_launch(void* const* d_in, const int* in_sizes, int n_in,
                              void* d_out, int out_size, void* d_ws, size_t ws_size,
                              hipStream_t stream) {
  (void)in_sizes; (void)n_in; (void)out_size;

  float* base;
  if (ws_size >= WSF * sizeof(float)) {
    base = (float*)d_ws;
  } else {
    void* p = nullptr;
    hipGetSymbolAddress(&p, HIP_SYMBOL(g_ws));
    base = (float*)p;
  }
  float* P0 = base;          // x0 (planar, persists)
  float* PA = base + 1*NS;   // xseq / x_s / ACT
  float* PB = base + 2*NS;   // XT shortcut / XT2 / fmt2 planar
  float* PC = base + 3*NS;   // fmt1 planar / XT3 / XT4
  float* PD = base + 4*NS;   // gemm scratch / QK / xo seq
  float* PF = base + 5*NS;   // fft im / CAT / XSS / FFN / xo planar
  float* H0 = base + 6*NS;
  float* H1 = H0 + NH;
  float* H2 = H1 + NH;
  float* WG = H2 + NH;                 // B*8*L
  float* ACC = WG + WGSZ;              // 2304
  float* CW  = ACC + ACCSZ;            // converted weights
  int*   FLG = (int*)(CW + CWSZ);

  static const int wsz[47] = {
    16384,128,128,128,1152,128,1024,8,8,8,1024,128,128,128,128,128,
    16384,128,1152,16384,128,3200,16384,128,4096,64,576,64,8192,128,
    576,64,16384,128,1152,128,128,128,512,4,512,128,16384,32768,128,128,128};
  int woff[47]; { int a = 0; for (int i = 0; i < 47; i++){ woff[i] = a; a += wsz[i]; } }
  const float* Wf[47]; for (int i = 0; i < 47; i++) Wf[i] = CW + woff[i];
  const float *c1_w=Wf[0], *c1_b=Wf[1], *c1_g=Wf[2], *c1_be=Wf[3], *cpe1_w=Wf[4],
    *cpe1_b=Wf[5], *fw1=Wf[6], *fb1=Wf[7], *f_g=Wf[8], *f_be=Wf[9], *fw2=Wf[10],
    *fb2=Wf[11], *nbn_g=Wf[12], *nbn_be=Wf[13], *ln1_g=Wf[14], *ln1_b=Wf[15],
    *d3w1=Wf[16], *d3b1=Wf[17], *d3w2=Wf[18], *d5w1=Wf[19], *d5b1=Wf[20],
    *d5w2=Wf[21], *ap_w=Wf[22], *ap_b=Wf[23], *ip2_w=Wf[24], *ip2_b=Wf[25],
    *dwc2_w=Wf[26], *dwc2_b=Wf[27], *qk_w=Wf[28], *qk_b=Wf[29], *lepe_w=Wf[30],
    *lepe_b=Wf[31], *op_w=Wf[32], *op_b=Wf[33], *cpe2_w=Wf[34], *cpe2_b=Wf[35],
    *ln2_g=Wf[36], *ln2_b=Wf[37], *ffn_w1=Wf[38], *ffn_b1=Wf[39], *ffn_w2=Wf[40],
    *ffn_b2=Wf[41], *po_w=Wf[42], *red_w=Wf[43], *red_b=Wf[44], *red_g=Wf[45],
    *red_be=Wf[46];

  const void* x = d_in[0];

  // 0. dtype probe + weight conversion
  k_probe<<<1, 256, 0, stream>>>((const bf16_t*)x, FLG);
  P47 ps; for (int i = 0; i < 47; i++) ps.p[i] = d_in[i+1];
  k_cvt<<<(TOTW+255)/256, 256, 0, stream>>>(ps, FLG, CW);

  dim3 tgrid(512, 4, 4), tblk(32, 8);

  auto fmt = [&](float* tp, float* im) {
    k_fft_row_fwd<<<16384, 256, 0, stream>>>(tp, tp, im);        // in-place re
    k_fft_col<true><<<2048, 256, 0, stream>>>(tp, im);
    k_freq1<<<256, 256, 0, stream>>>(tp, fw1, fb1, f_g, f_be, WG);
    k_freq2<<<32768, 256, 0, stream>>>(WG, fw2, fb2, tp, im);
    k_fft_col<false><<<2048, 256, 0, stream>>>(tp, im);
    k_fft_row_inv_abs<<<16384, 256, 0, stream>>>(tp, im, nbn_g, nbn_be);
  };

  // attention branch: BR (NHWC 64ch) in brin; writes CAT column coff of PF
  auto attn = [&](const float* brin, float* qkbuf, int coff) {
    k_zero<<<9, 256, 0, stream>>>(ACC, 2304);
    k_mfma_tok<64,128,3,false><<<1024, 256, 0, stream>>>(brin, nullptr, qk_w, qk_b, qkbuf);
    k_kv<<<1024, 256, 0, stream>>>(qkbuf, brin, ACC, ACC + B_*512);
    k_attn2<<<2048, 256, 0, stream>>>(qkbuf, brin, ACC, ACC + B_*512, lepe_w, lepe_b, PF, coff);
  };

  // 1. x_0 = relu(bn(conv1x1(x)))                         -> P0 (planar)
  k_gemm_planar<128,true,false,false><<<dim3(256,4), 256, 0, stream>>>(
      x, nullptr, c1_w, c1_b, c1_g, c1_be, nullptr, P0, FLG);
  // 2. x -> seq                                           -> PA
  k_p2s<true><<<tgrid, tblk, 0, stream>>>(x, PA, nullptr, nullptr, FLG);
  // 3. xt = x + dw3(x,cpe1)+b                             -> PB (shortcut)
  k_dw3<128,0><<<32768, 256, 0, stream>>>(PA, cpe1_w, cpe1_b, PB);
  // 4. fmt1 -> PC (planar)
  k_s2p<<<tgrid, tblk, 0, stream>>>(PB, PC);
  fmt(PC, PF);
  // 5. x_s = ln(xt)                                       -> PA
  k_ln<<<16384, 256, 0, stream>>>(PB, ln1_g, ln1_b, PA);
  // 6. multi-scale convs
  k_mfma_tok<128,128,1,false><<<1024, 256, 0, stream>>>(PA, nullptr, d3w1, d3b1, PD);
  k_gconv<3><<<16384, 256, 0, stream>>>(PD, d3w2, H0);
  k_mfma_tok<128,128,1,false><<<1024, 256, 0, stream>>>(PA, nullptr, d5w1, d5b1, PD);
  k_gconv<5><<<16384, 256, 0, stream>>>(PD, d5w2, H1);
  k_mfma_tok<128,128,2,false><<<1024, 256, 0, stream>>>(PA, nullptr, ap_w, ap_b, PA); // in-place: ACT
  // 7. branch3 -> attention -> CAT[:, :, 0:64] in PF
  k_mfma_tok<64,64,1,false><<<1024, 256, 0, stream>>>(H0, nullptr, ip2_w, ip2_b, H2);
  k_dw3<64,1><<<16384, 256, 0, stream>>>(H2, dwc2_w, dwc2_b, H0);
  attn(H0, PD, 0);
  //    branch5 -> attention -> CAT[:, :, 64:128]
  k_mfma_tok<64,64,1,false><<<1024, 256, 0, stream>>>(H1, nullptr, ip2_w, ip2_b, H2);
  k_dw3<64,1><<<16384, 256, 0, stream>>>(H2, dwc2_w, dwc2_b, H1);
  attn(H1, PD, 64);
  // 8. xss = conv1x1(CAT * ACT, op_w)+op_b                -> PF (in-place)
  k_mfma_tok<128,128,1,true><<<1024, 256, 0, stream>>>(PF, PA, op_w, op_b, PF);
  // 9. xt2 = shortcut + xss + fmt1                        -> PB (in-place add1)
  k_p2s<false><<<tgrid, tblk, 0, stream>>>(PC, PB, PB, PF, nullptr);
  // 10. xt3 = xt2 + dw3(xt2,cpe2)+b                       -> PC
  k_dw3<128,0><<<32768, 256, 0, stream>>>(PB, cpe2_w, cpe2_b, PC);
  // 11. fmt2 -> PB (planar)
  k_s2p<<<tgrid, tblk, 0, stream>>>(PC, PB);
  fmt(PB, PD);
  // 12. ffn(ln2(xt3))                                     -> PF
  k_ln_ffn<<<16384, 256, 0, stream>>>(PC, ln2_g, ln2_b, ffn_w1, ffn_b1, ffn_w2, ffn_b2, PF);
  // 13. xt4 = xt3 + ffn + fmt2                            -> PC (in-place add1)
  k_p2s<false><<<tgrid, tblk, 0, stream>>>(PB, PC, PC, PF, nullptr);
  // 14. xo = conv1x1(xt4, po_w)                           -> PD (seq)
  k_mfma_tok<128,128,0,false><<<1024, 256, 0, stream>>>(PC, nullptr, po_w, nullptr, PD);
  // 15. xo -> planar                                      -> PF
  k_s2p<<<tgrid, tblk, 0, stream>>>(PD, PF);
  // 16. out = relu(bn(conv1x1([x0;xo], red))) + x0        -> d_out (dtype per flag)
  k_gemm_planar<256,false,true,true><<<dim3(256,4), 256, 0, stream>>>(
      P0, PF, red_w, red_b, red_g, red_be, P0, d_out, FLG);
}

// Round 6
// 1353.978 us; speedup vs baseline: 1.2241x; 1.0135x over previous
//
#include <hip/hip_runtime.h>
#include <math.h>

typedef unsigned short bf16_t;
typedef __attribute__((ext_vector_type(8))) short short8;
typedef __attribute__((ext_vector_type(4))) float f32x4;

#define B_ 4
#define C_ 128
#define H_ 128
#define W_ 128
#define L_ (H_*W_)               // 16384
#define NS  ((size_t)B_*L_*C_)   // 8388608 elems
#define NH  ((size_t)B_*L_*64)
#define NSP ((size_t)L_*C_)
#define PI_F 3.14159265358979323846f
#define BN_INV 0.9999950000374997f   // (1+1e-5)^-0.5
#define THETA_SC 0.8304820237218406f // log2(10000)/16
#define TOTW 157148
#define W16SHIFT 107548              // offsets >= this get +4 in bf16 mirror (8-align po_w/red_w)

__device__ __forceinline__ float ldf(bf16_t v){ return __uint_as_float(((unsigned)v)<<16); }
__device__ __forceinline__ bf16_t f2b(float f){
  unsigned u = __float_as_uint(f);
  u += 0x7fffu + ((u>>16)&1u);     // RNE
  return (bf16_t)(u>>16);
}

// workspace layout
#define WGSZ ((size_t)B_*8*L_)       // 524288
#define ACCSZ 2304
#define CWSZ 157184                  // fp32 weights
#define CW16SZF 78592                // bf16 mirror (157152 shorts) in floats
#define WSF (6*NS + 3*NH + WGSZ + ACCSZ + CWSZ + CW16SZF + 16)
__device__ float g_ws[WSF];

// ---------------------------------------------------------------- dtype probe + weight convert
__global__ void k_probe(const bf16_t* __restrict__ xb, int* __restrict__ flag){
  __shared__ int vote;
  if (threadIdx.x == 0) vote = 0;
  __syncthreads();
  int bad = 0;
  for (int i = threadIdx.x; i < 2048; i += 256) {
    float v = ldf(xb[2*i]);
    if (!(fabsf(v) < 1e6f)) bad = 1;
  }
  if (bad) atomicOr(&vote, 1);
  __syncthreads();
  if (threadIdx.x == 0) *flag = vote;  // 1 = fp32 storage, 0 = bf16 storage
}

struct P47 { const void* p[47]; };
__device__ __constant__ int c_wsz[47] = {
  16384,128,128,128,1152,128,1024,8,8,8,1024,128,128,128,128,128,
  16384,128,1152,16384,128,3200,16384,128,4096,64,576,64,8192,128,
  576,64,16384,128,1152,128,128,128,512,4,512,128,16384,32768,128,128,128};

__global__ __launch_bounds__(256) void k_cvt(P47 ps, const int* __restrict__ flagp,
                                             float* __restrict__ dst){
  int g = blockIdx.x*256 + threadIdx.x;
  if (g >= TOTW) return;
  int fl = *flagp;
  int idx = 0, off = g;
  while (off >= c_wsz[idx]) { off -= c_wsz[idx]; idx++; }
  const void* s = ps.p[idx];
  dst[g] = fl ? ((const float*)s)[off] : ldf(((const bf16_t*)s)[off]);
}

__global__ __launch_bounds__(256) void k_cvt16(const float* __restrict__ src, bf16_t* __restrict__ dst){
  int g = blockIdx.x*256 + threadIdx.x;
  if (g >= TOTW) return;
  dst[g + (g >= W16SHIFT ? 4 : 0)] = f2b(src[g]);
}

__global__ void k_zero(float* p, int n){
  int i = blockIdx.x*256 + threadIdx.x;
  if (i < n) p[i] = 0.f;
}

// ---------------------------------------------------------------- FFT core
__device__ __forceinline__ void fft128_fwd(float& lor, float& loi, float& hir, float& hii, int lane) {
  {
    float s, c; sincosf(-PI_F * (float)lane * (1.f/64.f), &s, &c);
    float ar = lor, ai = loi;
    float dr = ar - hir, di = ai - hii;
    lor = ar + hir; loi = ai + hii;
    hir = dr*c - di*s; hii = dr*s + di*c;
  }
  #pragma unroll
  for (int m = 32; m >= 1; m >>= 1) {
    int k = lane & (m-1);
    float s, c; sincosf(-PI_F * (float)k / (float)m, &s, &c);
    bool up = (lane & m) != 0;
    {
      float orr = __shfl_xor(lor, m), oii = __shfl_xor(loi, m);
      float sr = lor + orr, si = loi + oii;
      float dr = orr - lor, di = oii - loi;
      float tr = dr*c - di*s, ti = dr*s + di*c;
      lor = up ? tr : sr; loi = up ? ti : si;
    }
    {
      float orr = __shfl_xor(hir, m), oii = __shfl_xor(hii, m);
      float sr = hir + orr, si = hii + oii;
      float dr = orr - hir, di = oii - hii;
      float tr = dr*c - di*s, ti = dr*s + di*c;
      hir = up ? tr : sr; hii = up ? ti : si;
    }
  }
}

__device__ __forceinline__ void fft128_inv(float& lor, float& loi, float& hir, float& hii, int lane) {
  #pragma unroll
  for (int m = 1; m <= 32; m <<= 1) {
    int k = lane & (m-1);
    float s, c; sincosf(PI_F * (float)k / (float)m, &s, &c);
    bool up = (lane & m) != 0;
    {
      float orr = __shfl_xor(lor, m), oii = __shfl_xor(loi, m);
      float qr = orr*c - oii*s, qi = orr*s + oii*c;
      float lo_r = lor + qr, lo_i = loi + qi;
      float mr = lor*c - loi*s, mi = lor*s + loi*c;
      float up_r = orr - mr, up_i = oii - mi;
      lor = up ? up_r : lo_r; loi = up ? up_i : lo_i;
    }
    {
      float orr = __shfl_xor(hir, m), oii = __shfl_xor(hii, m);
      float qr = orr*c - oii*s, qi = orr*s + oii*c;
      float lo_r = hir + qr, lo_i = hii + qi;
      float mr = hir*c - hii*s, mi = hir*s + hii*c;
      float up_r = orr - mr, up_i = oii - mi;
      hir = up ? up_r : lo_r; hii = up ? up_i : lo_i;
    }
  }
  {
    float s, c; sincosf(PI_F * (float)lane * (1.f/64.f), &s, &c);
    float qr = hir*c - hii*s, qi = hir*s + hii*c;
    float pr = lor, pi = loi;
    lor = pr + qr; loi = pi + qi;
    hir = pr - qr; hii = pi - qi;
  }
}

__global__ __launch_bounds__(256) void k_fft_row_fwd(const float* __restrict__ in,
    float* __restrict__ re, float* __restrict__ im) {
  int lane = threadIdx.x & 63;
  size_t row = (size_t)blockIdx.x*4 + (threadIdx.x >> 6);
  size_t base = row * 128;
  float lor = in[base + lane], loi = 0.f;
  float hir = in[base + lane + 64], hii = 0.f;
  fft128_fwd(lor, loi, hir, hii, lane);
  re[base+lane] = lor; im[base+lane] = loi;
  re[base+lane+64] = hir; im[base+lane+64] = hii;
}

__global__ __launch_bounds__(256) void k_fft_row_inv_abs(
    float* __restrict__ re, float* __restrict__ im,
    const float* __restrict__ ng, const float* __restrict__ nbe) {
  int lane = threadIdx.x & 63;
  size_t row = (size_t)blockIdx.x*4 + (threadIdx.x >> 6);
  size_t base = row * 128;
  float lor = re[base+lane], loi = im[base+lane];
  float hir = re[base+lane+64], hii = im[base+lane+64];
  fft128_inv(lor, loi, hir, hii, lane);
  int c = (int)((row >> 7) & 127);
  float sg = ng[c] * BN_INV, sb = nbe[c];
  float v0 = sqrtf(lor*lor + loi*loi) * (1.f/128.f);
  float v1 = sqrtf(hir*hir + hii*hii) * (1.f/128.f);
  re[base+lane]    = fmaxf(v0*sg + sb, 0.f);
  re[base+lane+64] = fmaxf(v1*sg + sb, 0.f);
}

template<bool FWD>
__global__ __launch_bounds__(256) void k_fft_col(float* __restrict__ re, float* __restrict__ im) {
  __shared__ float Lre[128][33];
  __shared__ float Lim[128][33];
  int tid = threadIdx.x;
  size_t img = blockIdx.x >> 2;
  int w0 = (blockIdx.x & 3) * 32;
  float* rp = re + img * (size_t)L_ + w0;
  float* ip = im + img * (size_t)L_ + w0;
  for (int i = tid; i < 4096; i += 256) {
    int h = i >> 5, wl = i & 31;
    Lre[h][wl] = rp[(size_t)h*W_ + wl];
    Lim[h][wl] = ip[(size_t)h*W_ + wl];
  }
  __syncthreads();
  int lane = tid & 63, wv = tid >> 6;
  for (int i = 0; i < 8; i++) {
    int col = wv*8 + i;
    float lor = Lre[lane][col], loi = Lim[lane][col];
    float hir = Lre[lane+64][col], hii = Lim[lane+64][col];
    if (FWD) {
      fft128_fwd(lor, loi, hir, hii, lane);
    } else {
      fft128_inv(lor, loi, hir, hii, lane);
      lor *= (1.f/128.f); loi *= (1.f/128.f); hir *= (1.f/128.f); hii *= (1.f/128.f);
    }
    Lre[lane][col]=lor; Lim[lane][col]=loi;
    Lre[lane+64][col]=hir; Lim[lane+64][col]=hii;
  }
  __syncthreads();
  for (int i = tid; i < 4096; i += 256) {
    int h = i >> 5, wl = i & 31;
    rp[(size_t)h*W_ + wl] = Lre[h][wl];
    ip[(size_t)h*W_ + wl] = Lim[h][wl];
  }
}

// ---------------------------------------------------------------- freq-domain convs
__global__ __launch_bounds__(256) void k_freq1(const float* __restrict__ tre,
    const float* __restrict__ fw1, const float* __restrict__ fb1,
    const float* __restrict__ fg, const float* __restrict__ fbe,
    float* __restrict__ wg1) {
  __shared__ float w1s[1024];
  int tid = threadIdx.x;
  for (int i = tid; i < 1024; i += 256) w1s[i] = fw1[i];
  __syncthreads();
  size_t g = (size_t)blockIdx.x*256 + tid;   // (b,p)
  int p = (int)(g & (L_-1));
  int b = (int)(g >> 14);
  const float* tp = tre + (size_t)b*128*L_ + p;
  float acc[8];
  #pragma unroll
  for (int o = 0; o < 8; o++) acc[o] = 0.f;
  for (int c = 0; c < 128; c++) {
    float v = tp[(size_t)c*L_];
    #pragma unroll
    for (int o = 0; o < 8; o++) acc[o] += w1s[o*128+c]*v;
  }
  size_t ob = (size_t)b*8*L_ + p;
  #pragma unroll
  for (int o = 0; o < 8; o++) {
    float v = (acc[o] + fb1[o]) * (fg[o]*BN_INV) + fbe[o];
    wg1[ob + (size_t)o*L_] = fmaxf(v, 0.f);
  }
}

__global__ __launch_bounds__(256) void k_freq2(const float* __restrict__ wg1,
    const float* __restrict__ fw2, const float* __restrict__ fb2,
    float* __restrict__ re, float* __restrict__ im) {
  __shared__ float w2s[1024];
  __shared__ float b2s[128];
  int tid = threadIdx.x;
  for (int i = tid; i < 1024; i += 256) w2s[i] = fw2[i];
  if (tid < 128) b2s[tid] = fb2[tid];
  __syncthreads();
  size_t g = (size_t)blockIdx.x*256 + tid;   // (b,c,p)
  int p = (int)(g & (L_-1));
  int c = (int)((g >> 14) & 127);
  int b = (int)(g >> 21);
  const float* wp = wg1 + (size_t)b*8*L_ + p;
  float acc = b2s[c];
  #pragma unroll
  for (int o = 0; o < 8; o++) acc += w2s[c*8+o] * wp[(size_t)o*L_];
  float wgt = 1.f/(1.f+expf(-acc));
  re[g] *= wgt; im[g] *= wgt;
}

// ---------------------------------------------------------------- transposes
template<bool DUAL>
__global__ void k_p2s(const void* __restrict__ src, float* __restrict__ dst,
                      const float* __restrict__ add1, const float* __restrict__ add2,
                      const int* __restrict__ flagp) {
  __shared__ float tile[32][33];
  int fl = DUAL ? *flagp : 1;
  int b = blockIdx.z;
  int p0 = blockIdx.x*32, c0 = blockIdx.y*32;
  int tx = threadIdx.x, ty = threadIdx.y;
  size_t base_in = (size_t)b*NSP;
  #pragma unroll
  for (int k = 0; k < 4; k++) {
    size_t off = base_in + (size_t)(c0+ty+8*k)*L_ + p0 + tx;
    float v;
    if (DUAL && !fl) v = ldf(((const bf16_t*)src)[off]);
    else             v = ((const float*)src)[off];
    tile[ty+8*k][tx] = v;
  }
  __syncthreads();
  size_t base = (size_t)b*NSP;
  #pragma unroll
  for (int k = 0; k < 4; k++) {
    size_t idx = base + (size_t)(p0+ty+8*k)*C_ + c0 + tx;
    float v = tile[tx][ty+8*k];
    if (add1) v += add1[idx];
    if (add2) v += add2[idx];
    dst[idx] = v;
  }
}

__global__ void k_s2p(const float* __restrict__ src, float* __restrict__ dst) {
  __shared__ float tile[32][33];
  int b = blockIdx.z;
  int p0 = blockIdx.x*32, c0 = blockIdx.y*32;
  int tx = threadIdx.x, ty = threadIdx.y;
  const float* sp = src + (size_t)b*NSP;
  #pragma unroll
  for (int k = 0; k < 4; k++)
    tile[ty+8*k][tx] = sp[(size_t)(p0+ty+8*k)*C_ + c0 + tx];
  __syncthreads();
  float* dp = dst + (size_t)b*NSP;
  #pragma unroll
  for (int k = 0; k < 4; k++)
    dp[(size_t)(c0+ty+8*k)*L_ + p0 + tx] = tile[tx][ty+8*k];
}

// ---------------------------------------------------------------- depthwise convs (NHWC)
template<int CC, int MODE>  // MODE 0: out = in + dw + b ; MODE 1: out = silu(dw + b)
__global__ __launch_bounds__(256) void k_dw3(const float* __restrict__ in,
    const float* __restrict__ w, const float* __restrict__ bias,
    float* __restrict__ out) {
  __shared__ float wl[CC*9];
  int tid = threadIdx.x;
  for (int i = tid; i < CC*9; i += 256) wl[i] = w[i];
  __syncthreads();
  size_t g = (size_t)blockIdx.x*256 + tid;
  int c = (int)(g % CC);
  size_t t = g / CC;
  int wp_ = (int)(t % W_);
  int hp = (int)((t / W_) % H_);
  int b = (int)(t / (size_t)L_);
  const float* ip = in + (size_t)b * L_ * CC + c;
  float acc = bias[c];
  #pragma unroll
  for (int dh = -1; dh <= 1; dh++) {
    int h2 = hp + dh;
    if ((unsigned)h2 >= (unsigned)H_) continue;
    #pragma unroll
    for (int dw = -1; dw <= 1; dw++) {
      int w2 = wp_ + dw;
      if ((unsigned)w2 >= (unsigned)W_) continue;
      acc += wl[c*9 + (dh+1)*3 + (dw+1)] * ip[((size_t)h2*W_ + w2)*CC];
    }
  }
  if (MODE == 0) out[g] = in[g] + acc;
  else           out[g] = acc / (1.f + expf(-acc));
}

// grouped conv, 2 in-ch per out-ch. Weights preloaded into REGISTERS
// (each lane's oc is fixed) — zero LDS traffic in the tap loop.
template<int K>
__global__ __launch_bounds__(256) void k_gconv(const float* __restrict__ in,
    const float* __restrict__ w, float* __restrict__ out) {
  __shared__ float wl[K*K*128];
  int tid = threadIdx.x;
  for (int i = tid; i < 128*K*K; i += 256) {
    int tap = i >> 7, ch = i & 127;
    wl[i] = w[ch*(K*K) + tap];          // wl[tap*128 + ch]
  }
  __syncthreads();
  size_t g = (size_t)blockIdx.x*256 + tid;
  int oc = (int)(g & 63);
  float wx[K*K], wy[K*K];
  #pragma unroll
  for (int t = 0; t < K*K; t++) {
    wx[t] = wl[t*128 + 2*oc];
    wy[t] = wl[t*128 + 2*oc + 1];
  }
  size_t t = g >> 6;
  int wp_ = (int)(t & (W_-1));
  int hp = (int)((t >> 7) & (H_-1));
  int b = (int)(t >> 14);
  const float* ip = in + (size_t)b*L_*128 + 2*oc;
  const int P = K/2;
  float acc = 0.f;
  #pragma unroll
  for (int kh = 0; kh < K; kh++) {
    int h2 = hp + kh - P;
    if ((unsigned)h2 >= (unsigned)H_) continue;
    #pragma unroll
    for (int kw = 0; kw < K; kw++) {
      int w2 = wp_ + kw - P;
      if ((unsigned)w2 >= (unsigned)W_) continue;
      float2 px = *(const float2*)(ip + ((size_t)h2*W_ + w2)*128);
      acc += wx[kh*K + kw]*px.x + wy[kh*K + kw]*px.y;
    }
  }
  out[g] = acc;
}

// ---------------------------------------------------------------- MFMA token GEMM (seq, bf16 W from global)
// Wave = 16 tokens x COUT; block = 4 waves = 64 tokens. No LDS, no barrier.
// EPI 0:none 1:bias 2:bias+silu 3:bias+elu+1
template<int CIN, int COUT, int EPI, bool MUL>
__global__ __launch_bounds__(256) void k_mfma_tok(
    const float* __restrict__ in, const float* __restrict__ mulp,
    const bf16_t* __restrict__ W16, const float* __restrict__ bias,
    float* __restrict__ out) {
  constexpr int NO = COUT/16;
  int tid = threadIdx.x;
  int lane = tid & 63, wv = tid >> 6;
  int m = lane & 15, q = lane >> 4;
  size_t t0 = (size_t)blockIdx.x*64 + (size_t)wv*16;
  f32x4 acc[NO];
  #pragma unroll
  for (int i = 0; i < NO; i++) acc[i] = (f32x4){0.f,0.f,0.f,0.f};
  for (int k0 = 0; k0 < CIN; k0 += 32) {
    const float* ap = in + (t0 + m)*CIN + k0 + q*8;
    float4 a0 = *(const float4*)ap;
    float4 a1 = *(const float4*)(ap + 4);
    if (MUL) {
      const float* mp = mulp + (t0 + m)*CIN + k0 + q*8;
      float4 m0 = *(const float4*)mp;
      float4 m1 = *(const float4*)(mp + 4);
      a0.x*=m0.x; a0.y*=m0.y; a0.z*=m0.z; a0.w*=m0.w;
      a1.x*=m1.x; a1.y*=m1.y; a1.z*=m1.z; a1.w*=m1.w;
    }
    union { short s[8]; short8 v; } af;
    af.s[0]=(short)f2b(a0.x); af.s[1]=(short)f2b(a0.y);
    af.s[2]=(short)f2b(a0.z); af.s[3]=(short)f2b(a0.w);
    af.s[4]=(short)f2b(a1.x); af.s[5]=(short)f2b(a1.y);
    af.s[6]=(short)f2b(a1.z); af.s[7]=(short)f2b(a1.w);
    #pragma unroll
    for (int o = 0; o < NO; o++) {
      short8 bf = *(const short8*)(W16 + (size_t)(o*16 + m)*CIN + k0 + q*8);
      acc[o] = __builtin_amdgcn_mfma_f32_16x16x32_bf16(af.v, bf, acc[o], 0, 0, 0);
    }
  }
  #pragma unroll
  for (int o = 0; o < NO; o++) {
    float bv = (EPI >= 1) ? bias[o*16 + m] : 0.f;
    #pragma unroll
    for (int r = 0; r < 4; r++) {
      int row = q*4 + r;
      float v = acc[o][r] + bv;
      if (EPI == 2) v = v / (1.f + expf(-v));
      if (EPI == 3) v = v > 0.f ? v + 1.f : expf(v);
      out[(t0 + row)*COUT + o*16 + m] = v;
    }
  }
}

// ---------------------------------------------------------------- MFMA GEMM, seq input(s) -> planar output (c1 / red)
// COUT=128. CIN=128: in1 only. CIN=256: concat[in1;in2] (each 128-wide seq).
// Epilogue: bn+relu (+addp planar) -> planar out (fp32 or bf16 by flag).
template<int CIN, bool DUALOUT, bool ADDX>
__global__ __launch_bounds__(256) void k_mfma_pout(
    const float* __restrict__ in1, const float* __restrict__ in2,
    const bf16_t* __restrict__ W16, const float* __restrict__ bias,
    const float* __restrict__ gam, const float* __restrict__ bet,
    const float* __restrict__ addp, void* __restrict__ out,
    const int* __restrict__ flagp) {
  constexpr int NO = 8;
  int fl = DUALOUT ? *flagp : 1;
  int tid = threadIdx.x;
  int lane = tid & 63, wv = tid >> 6;
  int m = lane & 15, q = lane >> 4;
  size_t t0 = (size_t)blockIdx.x*64 + (size_t)wv*16;
  f32x4 acc[NO];
  #pragma unroll
  for (int i = 0; i < NO; i++) acc[i] = (f32x4){0.f,0.f,0.f,0.f};
  for (int k0 = 0; k0 < CIN; k0 += 32) {
    const float* src = (CIN == 128 || k0 < 128)
        ? (in1 + (t0 + m)*128 + k0)
        : (in2 + (t0 + m)*128 + (k0 - 128));
    float4 a0 = *(const float4*)(src + q*8);
    float4 a1 = *(const float4*)(src + q*8 + 4);
    union { short s[8]; short8 v; } af;
    af.s[0]=(short)f2b(a0.x); af.s[1]=(short)f2b(a0.y);
    af.s[2]=(short)f2b(a0.z); af.s[3]=(short)f2b(a0.w);
    af.s[4]=(short)f2b(a1.x); af.s[5]=(short)f2b(a1.y);
    af.s[6]=(short)f2b(a1.z); af.s[7]=(short)f2b(a1.w);
    #pragma unroll
    for (int o = 0; o < NO; o++) {
      short8 bf = *(const short8*)(W16 + (size_t)(o*16 + m)*CIN + k0 + q*8);
      acc[o] = __builtin_amdgcn_mfma_f32_16x16x32_bf16(af.v, bf, acc[o], 0, 0, 0);
    }
  }
  int b = (int)(t0 >> 14);
  int p0 = (int)(t0 & (L_-1)) + q*4;
  #pragma unroll
  for (int ot = 0; ot < NO; ot++) {
    int o = ot*16 + m;
    float bi = bias[o], gm = gam[o]*BN_INV, be = bet[o];
    size_t idx = ((size_t)b*128 + o)*L_ + p0;
    float4 r4;
    float* rr = (float*)&r4;
    #pragma unroll
    for (int r = 0; r < 4; r++) {
      float v = acc[ot][r] + bi;
      v = fmaxf(v*gm + be, 0.f);
      rr[r] = v;
    }
    if (ADDX) {
      float4 av = *(const float4*)(addp + idx);
      r4.x += av.x; r4.y += av.y; r4.z += av.z; r4.w += av.w;
    }
    if (DUALOUT && !fl) {
      ushort4 s4;
      s4.x = f2b(r4.x); s4.y = f2b(r4.y); s4.z = f2b(r4.z); s4.w = f2b(r4.w);
      *(ushort4*)((bf16_t*)out + idx) = s4;
    } else {
      *(float4*)((float*)out + idx) = r4;
    }
  }
}

// ---------------------------------------------------------------- LN / LN+FFN
__global__ __launch_bounds__(256) void k_ln(const float* __restrict__ in,
    const float* __restrict__ g, const float* __restrict__ be, float* __restrict__ out) {
  int tid = threadIdx.x, lane = tid & 63;
  size_t t = (size_t)blockIdx.x*4 + (tid >> 6);
  const float* row = in + t*128;
  float2 v = *(const float2*)(row + lane*2);
  float s = v.x + v.y, ss = v.x*v.x + v.y*v.y;
  #pragma unroll
  for (int m = 1; m < 64; m <<= 1) { s += __shfl_xor(s, m); ss += __shfl_xor(ss, m); }
  float mean = s*(1.f/128.f);
  float inv = rsqrtf(ss*(1.f/128.f) - mean*mean + 1e-5f);
  float2 o;
  o.x = (v.x-mean)*inv*g[lane*2]   + be[lane*2];
  o.y = (v.y-mean)*inv*g[lane*2+1] + be[lane*2+1];
  *(float2*)(out + t*128 + lane*2) = o;
}

__global__ __launch_bounds__(256) void k_ln_ffn(const float* __restrict__ in,
    const float* __restrict__ g, const float* __restrict__ be,
    const float* __restrict__ w1, const float* __restrict__ b1,
    const float* __restrict__ w2, const float* __restrict__ b2,
    float* __restrict__ out) {
  int tid = threadIdx.x, lane = tid & 63;
  size_t t = (size_t)blockIdx.x*4 + (tid >> 6);
  const float* row = in + t*128;
  float2 v = *(const float2*)(row + lane*2);
  float s = v.x + v.y, ss = v.x*v.x + v.y*v.y;
  #pragma unroll
  for (int m = 1; m < 64; m <<= 1) { s += __shfl_xor(s, m); ss += __shfl_xor(ss, m); }
  float mean = s*(1.f/128.f);
  float inv = rsqrtf(ss*(1.f/128.f) - mean*mean + 1e-5f);
  float hx = (v.x-mean)*inv*g[lane*2]   + be[lane*2];
  float hy = (v.y-mean)*inv*g[lane*2+1] + be[lane*2+1];
  float hp0 = hx*w1[0*128+lane*2] + hy*w1[0*128+lane*2+1];
  float hp1 = hx*w1[1*128+lane*2] + hy*w1[1*128+lane*2+1];
  float hp2 = hx*w1[2*128+lane*2] + hy*w1[2*128+lane*2+1];
  float hp3 = hx*w1[3*128+lane*2] + hy*w1[3*128+lane*2+1];
  #pragma unroll
  for (int m = 1; m < 64; m <<= 1) {
    hp0 += __shfl_xor(hp0, m); hp1 += __shfl_xor(hp1, m);
    hp2 += __shfl_xor(hp2, m); hp3 += __shfl_xor(hp3, m);
  }
  float hv0, hv1, hv2, hv3;
  { float a = hp0 + b1[0]; hv0 = 0.5f*a*(1.f+erff(a*0.7071067811865476f)); }
  { float a = hp1 + b1[1]; hv1 = 0.5f*a*(1.f+erff(a*0.7071067811865476f)); }
  { float a = hp2 + b1[2]; hv2 = 0.5f*a*(1.f+erff(a*0.7071067811865476f)); }
  { float a = hp3 + b1[3]; hv3 = 0.5f*a*(1.f+erff(a*0.7071067811865476f)); }
  int cx = lane*2, cy = lane*2+1;
  float2 o;
  o.x = hv0*w2[cx*4+0] + hv1*w2[cx*4+1] + hv2*w2[cx*4+2] + hv3*w2[cx*4+3] + b2[cx];
  o.y = hv0*w2[cy*4+0] + hv1*w2[cy*4+1] + hv2*w2[cy*4+2] + hv3*w2[cy*4+3] + b2[cy];
  *(float2*)(out + t*128 + lane*2) = o;
}

// ---------------------------------------------------------------- linear attention
__global__ __launch_bounds__(256) void k_kv(
    const float* __restrict__ qk, const float* __restrict__ v,
    float* __restrict__ akv_g, float* __restrict__ aks_g) {
  __shared__ float kvred[512];
  __shared__ float ksred[64];
  int tid = threadIdx.x;
  for (int i = tid; i < 512; i += 256) kvred[i] = 0.f;
  if (tid < 64) ksred[tid] = 0.f;
  __syncthreads();
  int lane = tid & 63, wv = tid >> 6;
  size_t t0 = (size_t)blockIdx.x * 64;
  int b = (int)(t0 >> 14);
  int pr = lane >> 1;
  float theta = exp2f(-(float)(pr & 15) * THETA_SC);
  bool use_i = pr < 16;
  int hbase = lane & 56;
  float akv[8];
  #pragma unroll
  for (int d = 0; d < 8; d++) akv[d] = 0.f;
  float aks = 0.f;
  for (int it = 0; it < 16; it++) {
    size_t t = t0 + (size_t)wv*16 + it;
    float k = qk[t*128 + 64 + lane];
    float xv = v[t*64 + lane];
    int l = (int)(t & (L_-1));
    float pos = use_i ? (float)(l >> 7) : (float)(l & 127);
    float sn, cs; sincosf(pos*theta, &sn, &cs);
    float kp = __shfl_xor(k, 1);
    float kr = (lane & 1) ? (sn*kp + cs*k) : (cs*k - sn*kp);
    #pragma unroll
    for (int d = 0; d < 8; d++) {
      float krd = __shfl(kr, hbase + d);
      akv[d] += krd * xv;
    }
    aks += k;
  }
  int h8 = lane >> 3, e = lane & 7;
  #pragma unroll
  for (int d = 0; d < 8; d++)
    atomicAdd(&kvred[h8*64 + d*8 + e], akv[d]);
  atomicAdd(&ksred[lane], aks);
  __syncthreads();
  for (int i = tid; i < 512; i += 256) atomicAdd(&akv_g[b*512 + i], kvred[i]);
  if (tid < 64) atomicAdd(&aks_g[b*64 + tid], ksred[tid]);
}

__global__ __launch_bounds__(256) void k_attn2(
    const float* __restrict__ qk, const float* __restrict__ x,
    const float* __restrict__ akv_g, const float* __restrict__ aks_g,
    const float* __restrict__ lw, const float* __restrict__ lb,
    float* __restrict__ out, int coff) {
  __shared__ float kv[512];
  __shared__ float km[64];
  __shared__ float lwl[576];
  int tid = threadIdx.x;
  size_t t0 = (size_t)blockIdx.x * 32;
  int b = (int)(t0 >> 14);
  const float invn = 1.f/16384.f;
  for (int i = tid; i < 512; i += 256) kv[i] = akv_g[b*512 + i]*invn;
  if (tid < 64) km[tid] = aks_g[b*64 + tid]*invn;
  for (int i = tid; i < 576; i += 256) lwl[i] = lw[i];
  __syncthreads();
  int lane = tid & 63, wv = tid >> 6;
  int pr = lane >> 1;
  float theta = exp2f(-(float)(pr & 15) * THETA_SC);
  bool use_i = pr < 16;
  int hbase = lane & 56, e = lane & 7;
  float lbv = lb[lane];
  const float* xb = x + ((size_t)b << 14) * 64;
  for (int it = 0; it < 8; it++) {
    size_t t = t0 + (size_t)wv*8 + it;
    int l = (int)(t & (L_-1));
    int ipos = l >> 7, jpos = l & 127;
    float q = qk[t*128 + lane];
    float p = q * km[lane];
    p += __shfl_xor(p, 1); p += __shfl_xor(p, 2); p += __shfl_xor(p, 4);
    float z = 1.f/(p + 1e-6f);
    float pos = use_i ? (float)ipos : (float)jpos;
    float sn, cs; sincosf(pos*theta, &sn, &cs);
    float qp = __shfl_xor(q, 1);
    float qr = (lane & 1) ? (sn*qp + cs*q) : (cs*q - sn*qp);
    float acc = 0.f;
    #pragma unroll
    for (int d = 0; d < 8; d++) {
      float qrd = __shfl(qr, hbase + d);
      acc += qrd * kv[hbase*8 + d*8 + e];
    }
    acc *= z;
    float lp = lbv;
    #pragma unroll
    for (int dh = -1; dh <= 1; dh++) {
      int h2 = ipos + dh; if ((unsigned)h2 >= 128u) continue;
      #pragma unroll
      for (int dw = -1; dw <= 1; dw++) {
        int w2 = jpos + dw; if ((unsigned)w2 >= 128u) continue;
        lp += lwl[lane*9 + (dh+1)*3 + (dw+1)] * xb[((size_t)(h2 << 7) + w2)*64 + lane];
      }
    }
    out[t*128 + coff + lane] = acc + lp;
  }
}

// ---------------------------------------------------------------- launcher
extern "C" void kernel_launch(void* const* d_in, const int* in_sizes, int n_in,
                              void* d_out, int out_size, void* d_ws, size_t ws_size,
                              hipStream_t stream) {
  (void)in_sizes; (void)n_in; (void)out_size;

  float* base;
  if (ws_size >= WSF * sizeof(float)) {
    base = (float*)d_ws;
  } else {
    void* p = nullptr;
    hipGetSymbolAddress(&p, HIP_SYMBOL(g_ws));
    base = (float*)p;
  }
  float* P0 = base;          // x0 (planar, persists)
  float* PA = base + 1*NS;   // xseq / x_s / ACT
  float* PB = base + 2*NS;   // XT shortcut / XT2 / fmt2 planar / x0 seq
  float* PC = base + 3*NS;   // fmt1 planar / XT3 / XT4
  float* PD = base + 4*NS;   // QK / xo seq
  float* PF = base + 5*NS;   // fft im / CAT / XSS / FFN
  float* H0 = base + 6*NS;
  float* H1 = H0 + NH;
  float* H2 = H1 + NH;
  float* WG = H2 + NH;                  // B*8*L
  float* ACC = WG + WGSZ;               // 2304
  float* CW  = ACC + ACCSZ;             // fp32 weights
  bf16_t* CW16 = (bf16_t*)(CW + CWSZ);  // bf16 weight mirror
  int*   FLG = (int*)(CW + CWSZ + CW16SZF);

  static const int wsz[47] = {
    16384,128,128,128,1152,128,1024,8,8,8,1024,128,128,128,128,128,
    16384,128,1152,16384,128,3200,16384,128,4096,64,576,64,8192,128,
    576,64,16384,128,1152,128,128,128,512,4,512,128,16384,32768,128,128,128};
  int woff[47]; { int a = 0; for (int i = 0; i < 47; i++){ woff[i] = a; a += wsz[i]; } }
  const float* Wf[47]; for (int i = 0; i < 47; i++) Wf[i] = CW + woff[i];
  auto W16 = [&](int i){ return (const bf16_t*)(CW16 + woff[i] + (woff[i] >= W16SHIFT ? 4 : 0)); };
  const float *c1_b=Wf[2-1], *c1_g=Wf[2], *c1_be=Wf[3], *cpe1_w=Wf[4],
    *cpe1_b=Wf[5], *fw1=Wf[6], *fb1=Wf[7], *f_g=Wf[8], *f_be=Wf[9], *fw2=Wf[10],
    *fb2=Wf[11], *nbn_g=Wf[12], *nbn_be=Wf[13], *ln1_g=Wf[14], *ln1_b=Wf[15],
    *d3b1=Wf[17], *d3w2=Wf[18], *d5b1=Wf[20],
    *d5w2=Wf[21], *ap_b=Wf[23], *ip2_b=Wf[25],
    *dwc2_w=Wf[26], *dwc2_b=Wf[27], *qk_b=Wf[29], *lepe_w=Wf[30],
    *lepe_b=Wf[31], *op_b=Wf[33], *cpe2_w=Wf[34], *cpe2_b=Wf[35],
    *ln2_g=Wf[36], *ln2_b=Wf[37], *ffn_w1=Wf[38], *ffn_b1=Wf[39], *ffn_w2=Wf[40],
    *ffn_b2=Wf[41], *red_b=Wf[44], *red_g=Wf[45], *red_be=Wf[46];
  const bf16_t *c1_w16=W16(0), *d3w1_16=W16(16), *d5w1_16=W16(19), *ap_w16=W16(22),
    *ip2_w16=W16(24), *qk_w16=W16(28), *op_w16=W16(32), *po_w16=W16(42), *red_w16=W16(43);

  const void* x = d_in[0];

  // 0. dtype probe + weight conversion (fp32 + bf16 mirror)
  k_probe<<<1, 256, 0, stream>>>((const bf16_t*)x, FLG);
  P47 ps; for (int i = 0; i < 47; i++) ps.p[i] = d_in[i+1];
  k_cvt<<<(TOTW+255)/256, 256, 0, stream>>>(ps, FLG, CW);
  k_cvt16<<<(TOTW+255)/256, 256, 0, stream>>>(CW, CW16);

  dim3 tgrid(512, 4, 4), tblk(32, 8);

  auto fmt = [&](float* tp, float* im) {
    k_fft_row_fwd<<<16384, 256, 0, stream>>>(tp, tp, im);
    k_fft_col<true><<<2048, 256, 0, stream>>>(tp, im);
    k_freq1<<<256, 256, 0, stream>>>(tp, fw1, fb1, f_g, f_be, WG);
    k_freq2<<<32768, 256, 0, stream>>>(WG, fw2, fb2, tp, im);
    k_fft_col<false><<<2048, 256, 0, stream>>>(tp, im);
    k_fft_row_inv_abs<<<16384, 256, 0, stream>>>(tp, im, nbn_g, nbn_be);
  };

  auto attn = [&](const float* brin, float* qkbuf, int coff) {
    k_zero<<<9, 256, 0, stream>>>(ACC, 2304);
    k_mfma_tok<64,128,3,false><<<1024, 256, 0, stream>>>(brin, nullptr, qk_w16, qk_b, qkbuf);
    k_kv<<<1024, 256, 0, stream>>>(qkbuf, brin, ACC, ACC + B_*512);
    k_attn2<<<2048, 256, 0, stream>>>(qkbuf, brin, ACC, ACC + B_*512, lepe_w, lepe_b, PF, coff);
  };

  // 2. x -> seq                                           -> PA
  k_p2s<true><<<tgrid, tblk, 0, stream>>>(x, PA, nullptr, nullptr, FLG);
  // 1. x_0 = relu(bn(conv1x1(x)))                         -> P0 (planar)
  k_mfma_pout<128,false,false><<<1024, 256, 0, stream>>>(
      PA, nullptr, c1_w16, c1_b, c1_g, c1_be, nullptr, P0, FLG);
  // 3. xt = x + dw3(x,cpe1)+b                             -> PB (shortcut)
  k_dw3<128,0><<<32768, 256, 0, stream>>>(PA, cpe1_w, cpe1_b, PB);
  // 4. fmt1 -> PC (planar)
  k_s2p<<<tgrid, tblk, 0, stream>>>(PB, PC);
  fmt(PC, PF);
  // 5. x_s = ln(xt)                                       -> PA
  k_ln<<<16384, 256, 0, stream>>>(PB, ln1_g, ln1_b, PA);
  // 6. multi-scale convs
  k_mfma_tok<128,128,1,false><<<1024, 256, 0, stream>>>(PA, nullptr, d3w1_16, d3b1, PD);
  k_gconv<3><<<16384, 256, 0, stream>>>(PD, d3w2, H0);
  k_mfma_tok<128,128,1,false><<<1024, 256, 0, stream>>>(PA, nullptr, d5w1_16, d5b1, PD);
  k_gconv<5><<<16384, 256, 0, stream>>>(PD, d5w2, H1);
  k_mfma_tok<128,128,2,false><<<1024, 256, 0, stream>>>(PA, nullptr, ap_w16, ap_b, PA); // in-place: ACT
  // 7. branch3 -> attention -> CAT[:, :, 0:64] in PF
  k_mfma_tok<64,64,1,false><<<1024, 256, 0, stream>>>(H0, nullptr, ip2_w16, ip2_b, H2);
  k_dw3<64,1><<<16384, 256, 0, stream>>>(H2, dwc2_w, dwc2_b, H0);
  attn(H0, PD, 0);
  //    branch5 -> attention -> CAT[:, :, 64:128]
  k_mfma_tok<64,64,1,false><<<1024, 256, 0, stream>>>(H1, nullptr, ip2_w16, ip2_b, H2);
  k_dw3<64,1><<<16384, 256, 0, stream>>>(H2, dwc2_w, dwc2_b, H1);
  attn(H1, PD, 64);
  // 8. xss = conv1x1(CAT * ACT, op_w)+op_b                -> PF (in-place)
  k_mfma_tok<128,128,1,true><<<1024, 256, 0, stream>>>(PF, PA, op_w16, op_b, PF);
  // 9. xt2 = shortcut + xss + fmt1                        -> PB (in-place add1)
  k_p2s<false><<<tgrid, tblk, 0, stream>>>(PC, PB, PB, PF, nullptr);
  // 10. xt3 = xt2 + dw3(xt2,cpe2)+b                       -> PC
  k_dw3<128,0><<<32768, 256, 0, stream>>>(PB, cpe2_w, cpe2_b, PC);
  // 11. fmt2 -> PB (planar)
  k_s2p<<<tgrid, tblk, 0, stream>>>(PC, PB);
  fmt(PB, PD);
  // 12. ffn(ln2(xt3))                                     -> PF
  k_ln_ffn<<<16384, 256, 0, stream>>>(PC, ln2_g, ln2_b, ffn_w1, ffn_b1, ffn_w2, ffn_b2, PF);
  // 13. xt4 = xt3 + ffn + fmt2                            -> PC (in-place add1)
  k_p2s<false><<<tgrid, tblk, 0, stream>>>(PB, PC, PC, PF, nullptr);
  // 14. xo = conv1x1(xt4, po_w)                           -> PD (seq)
  k_mfma_tok<128,128,0,false><<<1024, 256, 0, stream>>>(PC, nullptr, po_w16, nullptr, PD);
  // 15. x0 planar -> seq                                  -> PB
  k_p2s<false><<<tgrid, tblk, 0, stream>>>(P0, PB, nullptr, nullptr, nullptr);
  // 16. out = relu(bn(conv1x1([x0;xo], red))) + x0        -> d_out (planar, dtype per flag)
  k_mfma_pout<256,true,true><<<1024, 256, 0, stream>>>(
      PB, PD, red_w16, red_b, red_g, red_be, P0, d_out, FLG);
}

// Round 7
// 1150.624 us; speedup vs baseline: 1.4404x; 1.1767x over previous
//
#include <hip/hip_runtime.h>
#include <math.h>

typedef unsigned short bf16_t;
typedef __attribute__((ext_vector_type(8))) short short8;
typedef __attribute__((ext_vector_type(4))) float f32x4;

#define B_ 4
#define C_ 128
#define H_ 128
#define W_ 128
#define L_ (H_*W_)               // 16384
#define NS  ((size_t)B_*L_*C_)   // 8388608 elems
#define NH  ((size_t)B_*L_*64)
#define NSP ((size_t)L_*C_)
#define PI_F 3.14159265358979323846f
#define BN_INV 0.9999950000374997f   // (1+1e-5)^-0.5
#define THETA_SC 0.8304820237218406f // log2(10000)/16
#define TOTW 157148
#define W16SHIFT 107548              // offsets >= this get +4 in bf16 mirror (8-align po_w/red_w)

__device__ __forceinline__ float ldf(bf16_t v){ return __uint_as_float(((unsigned)v)<<16); }
__device__ __forceinline__ bf16_t f2b(float f){
  unsigned u = __float_as_uint(f);
  u += 0x7fffu + ((u>>16)&1u);     // RNE
  return (bf16_t)(u>>16);
}

// workspace layout
#define WGSZ ((size_t)B_*8*L_)       // 524288
#define ACCSZ 2304
#define CWSZ 157184                  // fp32 weights
#define CW16SZF 78592                // bf16 mirror (157152 shorts) in floats
#define WSF (6*NS + 3*NH + WGSZ + ACCSZ + CWSZ + CW16SZF + 16)
__device__ float g_ws[WSF];

// ---------------------------------------------------------------- dtype probe + weight convert
__global__ void k_probe(const bf16_t* __restrict__ xb, int* __restrict__ flag){
  __shared__ int vote;
  if (threadIdx.x == 0) vote = 0;
  __syncthreads();
  int bad = 0;
  for (int i = threadIdx.x; i < 2048; i += 256) {
    float v = ldf(xb[2*i]);
    if (!(fabsf(v) < 1e6f)) bad = 1;
  }
  if (bad) atomicOr(&vote, 1);
  __syncthreads();
  if (threadIdx.x == 0) *flag = vote;  // 1 = fp32 storage, 0 = bf16 storage
}

struct P47 { const void* p[47]; };
__device__ __constant__ int c_wsz[47] = {
  16384,128,128,128,1152,128,1024,8,8,8,1024,128,128,128,128,128,
  16384,128,1152,16384,128,3200,16384,128,4096,64,576,64,8192,128,
  576,64,16384,128,1152,128,128,128,512,4,512,128,16384,32768,128,128,128};

__global__ __launch_bounds__(256) void k_cvt(P47 ps, const int* __restrict__ flagp,
                                             float* __restrict__ dst){
  int g = blockIdx.x*256 + threadIdx.x;
  if (g >= TOTW) return;
  int fl = *flagp;
  int idx = 0, off = g;
  while (off >= c_wsz[idx]) { off -= c_wsz[idx]; idx++; }
  const void* s = ps.p[idx];
  dst[g] = fl ? ((const float*)s)[off] : ldf(((const bf16_t*)s)[off]);
}

__global__ __launch_bounds__(256) void k_cvt16(const float* __restrict__ src, bf16_t* __restrict__ dst){
  int g = blockIdx.x*256 + threadIdx.x;
  if (g >= TOTW) return;
  dst[g + (g >= W16SHIFT ? 4 : 0)] = f2b(src[g]);
}

__global__ void k_zero(float* p, int n){
  int i = blockIdx.x*256 + threadIdx.x;
  if (i < n) p[i] = 0.f;
}

// ---------------------------------------------------------------- FFT core
__device__ __forceinline__ void fft128_fwd(float& lor, float& loi, float& hir, float& hii, int lane) {
  {
    float s, c; sincosf(-PI_F * (float)lane * (1.f/64.f), &s, &c);
    float ar = lor, ai = loi;
    float dr = ar - hir, di = ai - hii;
    lor = ar + hir; loi = ai + hii;
    hir = dr*c - di*s; hii = dr*s + di*c;
  }
  #pragma unroll
  for (int m = 32; m >= 1; m >>= 1) {
    int k = lane & (m-1);
    float s, c; sincosf(-PI_F * (float)k / (float)m, &s, &c);
    bool up = (lane & m) != 0;
    {
      float orr = __shfl_xor(lor, m), oii = __shfl_xor(loi, m);
      float sr = lor + orr, si = loi + oii;
      float dr = orr - lor, di = oii - loi;
      float tr = dr*c - di*s, ti = dr*s + di*c;
      lor = up ? tr : sr; loi = up ? ti : si;
    }
    {
      float orr = __shfl_xor(hir, m), oii = __shfl_xor(hii, m);
      float sr = hir + orr, si = hii + oii;
      float dr = orr - hir, di = oii - hii;
      float tr = dr*c - di*s, ti = dr*s + di*c;
      hir = up ? tr : sr; hii = up ? ti : si;
    }
  }
}

__device__ __forceinline__ void fft128_inv(float& lor, float& loi, float& hir, float& hii, int lane) {
  #pragma unroll
  for (int m = 1; m <= 32; m <<= 1) {
    int k = lane & (m-1);
    float s, c; sincosf(PI_F * (float)k / (float)m, &s, &c);
    bool up = (lane & m) != 0;
    {
      float orr = __shfl_xor(lor, m), oii = __shfl_xor(loi, m);
      float qr = orr*c - oii*s, qi = orr*s + oii*c;
      float lo_r = lor + qr, lo_i = loi + qi;
      float mr = lor*c - loi*s, mi = lor*s + loi*c;
      float up_r = orr - mr, up_i = oii - mi;
      lor = up ? up_r : lo_r; loi = up ? up_i : lo_i;
    }
    {
      float orr = __shfl_xor(hir, m), oii = __shfl_xor(hii, m);
      float qr = orr*c - oii*s, qi = orr*s + oii*c;
      float lo_r = hir + qr, lo_i = hii + qi;
      float mr = hir*c - hii*s, mi = hir*s + hii*c;
      float up_r = orr - mr, up_i = oii - mi;
      hir = up ? up_r : lo_r; hii = up ? up_i : lo_i;
    }
  }
  {
    float s, c; sincosf(PI_F * (float)lane * (1.f/64.f), &s, &c);
    float qr = hir*c - hii*s, qi = hir*s + hii*c;
    float pr = lor, pi = loi;
    lor = pr + qr; loi = pi + qi;
    hir = pr - qr; hii = pi - qi;
  }
}

__global__ __launch_bounds__(256) void k_fft_row_fwd(const float* __restrict__ in,
    float* __restrict__ re, float* __restrict__ im) {
  int lane = threadIdx.x & 63;
  size_t row = (size_t)blockIdx.x*4 + (threadIdx.x >> 6);
  size_t base = row * 128;
  float lor = in[base + lane], loi = 0.f;
  float hir = in[base + lane + 64], hii = 0.f;
  fft128_fwd(lor, loi, hir, hii, lane);
  re[base+lane] = lor; im[base+lane] = loi;
  re[base+lane+64] = hir; im[base+lane+64] = hii;
}

__global__ __launch_bounds__(256) void k_fft_row_inv_abs(
    float* __restrict__ re, float* __restrict__ im,
    const float* __restrict__ ng, const float* __restrict__ nbe) {
  int lane = threadIdx.x & 63;
  size_t row = (size_t)blockIdx.x*4 + (threadIdx.x >> 6);
  size_t base = row * 128;
  float lor = re[base+lane], loi = im[base+lane];
  float hir = re[base+lane+64], hii = im[base+lane+64];
  fft128_inv(lor, loi, hir, hii, lane);
  int c = (int)((row >> 7) & 127);
  float sg = ng[c] * BN_INV, sb = nbe[c];
  float v0 = sqrtf(lor*lor + loi*loi) * (1.f/128.f);
  float v1 = sqrtf(hir*hir + hii*hii) * (1.f/128.f);
  re[base+lane]    = fmaxf(v0*sg + sb, 0.f);
  re[base+lane+64] = fmaxf(v1*sg + sb, 0.f);
}

template<bool FWD>
__global__ __launch_bounds__(256) void k_fft_col(float* __restrict__ re, float* __restrict__ im) {
  __shared__ float Lre[128][33];
  __shared__ float Lim[128][33];
  int tid = threadIdx.x;
  size_t img = blockIdx.x >> 2;
  int w0 = (blockIdx.x & 3) * 32;
  float* rp = re + img * (size_t)L_ + w0;
  float* ip = im + img * (size_t)L_ + w0;
  for (int i = tid; i < 4096; i += 256) {
    int h = i >> 5, wl = i & 31;
    Lre[h][wl] = rp[(size_t)h*W_ + wl];
    Lim[h][wl] = ip[(size_t)h*W_ + wl];
  }
  __syncthreads();
  int lane = tid & 63, wv = tid >> 6;
  for (int i = 0; i < 8; i++) {
    int col = wv*8 + i;
    float lor = Lre[lane][col], loi = Lim[lane][col];
    float hir = Lre[lane+64][col], hii = Lim[lane+64][col];
    if (FWD) {
      fft128_fwd(lor, loi, hir, hii, lane);
    } else {
      fft128_inv(lor, loi, hir, hii, lane);
      lor *= (1.f/128.f); loi *= (1.f/128.f); hir *= (1.f/128.f); hii *= (1.f/128.f);
    }
    Lre[lane][col]=lor; Lim[lane][col]=loi;
    Lre[lane+64][col]=hir; Lim[lane+64][col]=hii;
  }
  __syncthreads();
  for (int i = tid; i < 4096; i += 256) {
    int h = i >> 5, wl = i & 31;
    rp[(size_t)h*W_ + wl] = Lre[h][wl];
    ip[(size_t)h*W_ + wl] = Lim[h][wl];
  }
}

// ---------------------------------------------------------------- freq-domain convs
__global__ __launch_bounds__(256) void k_freq1(const float* __restrict__ tre,
    const float* __restrict__ fw1, const float* __restrict__ fb1,
    const float* __restrict__ fg, const float* __restrict__ fbe,
    float* __restrict__ wg1) {
  __shared__ float w1s[1024];
  int tid = threadIdx.x;
  for (int i = tid; i < 1024; i += 256) w1s[i] = fw1[i];
  __syncthreads();
  size_t g = (size_t)blockIdx.x*256 + tid;   // (b,p)
  int p = (int)(g & (L_-1));
  int b = (int)(g >> 14);
  const float* tp = tre + (size_t)b*128*L_ + p;
  float acc[8];
  #pragma unroll
  for (int o = 0; o < 8; o++) acc[o] = 0.f;
  for (int c = 0; c < 128; c++) {
    float v = tp[(size_t)c*L_];
    #pragma unroll
    for (int o = 0; o < 8; o++) acc[o] += w1s[o*128+c]*v;
  }
  size_t ob = (size_t)b*8*L_ + p;
  #pragma unroll
  for (int o = 0; o < 8; o++) {
    float v = (acc[o] + fb1[o]) * (fg[o]*BN_INV) + fbe[o];
    wg1[ob + (size_t)o*L_] = fmaxf(v, 0.f);
  }
}

__global__ __launch_bounds__(256) void k_freq2(const float* __restrict__ wg1,
    const float* __restrict__ fw2, const float* __restrict__ fb2,
    float* __restrict__ re, float* __restrict__ im) {
  __shared__ float w2s[1024];
  __shared__ float b2s[128];
  int tid = threadIdx.x;
  for (int i = tid; i < 1024; i += 256) w2s[i] = fw2[i];
  if (tid < 128) b2s[tid] = fb2[tid];
  __syncthreads();
  size_t g = (size_t)blockIdx.x*256 + tid;   // (b,c,p)
  int p = (int)(g & (L_-1));
  int c = (int)((g >> 14) & 127);
  int b = (int)(g >> 21);
  const float* wp = wg1 + (size_t)b*8*L_ + p;
  float acc = b2s[c];
  #pragma unroll
  for (int o = 0; o < 8; o++) acc += w2s[c*8+o] * wp[(size_t)o*L_];
  float wgt = 1.f/(1.f+expf(-acc));
  re[g] *= wgt; im[g] *= wgt;
}

// ---------------------------------------------------------------- transposes
template<bool DUAL>
__global__ void k_p2s(const void* __restrict__ src, float* __restrict__ dst,
                      const float* __restrict__ add1, const float* __restrict__ add2,
                      const int* __restrict__ flagp) {
  __shared__ float tile[32][33];
  int fl = DUAL ? *flagp : 1;
  int b = blockIdx.z;
  int p0 = blockIdx.x*32, c0 = blockIdx.y*32;
  int tx = threadIdx.x, ty = threadIdx.y;
  size_t base_in = (size_t)b*NSP;
  #pragma unroll
  for (int k = 0; k < 4; k++) {
    size_t off = base_in + (size_t)(c0+ty+8*k)*L_ + p0 + tx;
    float v;
    if (DUAL && !fl) v = ldf(((const bf16_t*)src)[off]);
    else             v = ((const float*)src)[off];
    tile[ty+8*k][tx] = v;
  }
  __syncthreads();
  size_t base = (size_t)b*NSP;
  #pragma unroll
  for (int k = 0; k < 4; k++) {
    size_t idx = base + (size_t)(p0+ty+8*k)*C_ + c0 + tx;
    float v = tile[tx][ty+8*k];
    if (add1) v += add1[idx];
    if (add2) v += add2[idx];
    dst[idx] = v;
  }
}

__global__ void k_s2p(const float* __restrict__ src, float* __restrict__ dst) {
  __shared__ float tile[32][33];
  int b = blockIdx.z;
  int p0 = blockIdx.x*32, c0 = blockIdx.y*32;
  int tx = threadIdx.x, ty = threadIdx.y;
  const float* sp = src + (size_t)b*NSP;
  #pragma unroll
  for (int k = 0; k < 4; k++)
    tile[ty+8*k][tx] = sp[(size_t)(p0+ty+8*k)*C_ + c0 + tx];
  __syncthreads();
  float* dp = dst + (size_t)b*NSP;
  #pragma unroll
  for (int k = 0; k < 4; k++)
    dp[(size_t)(c0+ty+8*k)*L_ + p0 + tx] = tile[tx][ty+8*k];
}

// ---------------------------------------------------------------- depthwise 3x3 (NHWC), 4 pixels/thread
// MODE 0: out = in + dw + b ; MODE 1: out = silu(dw + b)
template<int CC, int MODE>
__global__ __launch_bounds__(256) void k_dw3(const float* __restrict__ in,
    const float* __restrict__ w, const float* __restrict__ bias,
    float* __restrict__ out) {
  __shared__ float wl[9*CC];
  int tid = threadIdx.x;
  for (int i = tid; i < 9*CC; i += 256) {
    int tap = i / CC, ch = i % CC;
    wl[i] = w[ch*9 + tap];               // wl[tap*CC + ch]
  }
  __syncthreads();
  size_t g = (size_t)blockIdx.x*256 + tid;
  int c = (int)(g & (CC-1));
  float wr[9];
  #pragma unroll
  for (int t = 0; t < 9; t++) wr[t] = wl[t*CC + c];
  size_t s = g / CC;                      // strip index: B*H*(W/4)
  int w0 = (int)(s & 31) * 4;
  int hp = (int)((s >> 5) & 127);
  int b  = (int)(s >> 12);
  const float* ip = in + (size_t)b*L_*CC + c;
  float bi = bias[c];
  float a0 = bi, a1 = bi, a2 = bi, a3 = bi;
  #pragma unroll
  for (int dh = -1; dh <= 1; dh++) {
    int h2 = hp + dh;
    if ((unsigned)h2 >= 128u) continue;
    const float* rp = ip + (size_t)h2*W_*CC;
    float px[6];
    #pragma unroll
    for (int x = 0; x < 6; x++) {
      int w2 = w0 - 1 + x;
      px[x] = ((unsigned)w2 < 128u) ? rp[(size_t)w2*CC] : 0.f;
    }
    #pragma unroll
    for (int dw = 0; dw < 3; dw++) {
      float f = wr[(dh+1)*3 + dw];
      a0 += f*px[dw];   a1 += f*px[dw+1];
      a2 += f*px[dw+2]; a3 += f*px[dw+3];
    }
  }
  size_t tb = (size_t)b*L_ + (size_t)hp*W_ + w0;
  if (MODE == 0) {
    out[(tb+0)*CC + c] = in[(tb+0)*CC + c] + a0;
    out[(tb+1)*CC + c] = in[(tb+1)*CC + c] + a1;
    out[(tb+2)*CC + c] = in[(tb+2)*CC + c] + a2;
    out[(tb+3)*CC + c] = in[(tb+3)*CC + c] + a3;
  } else {
    out[(tb+0)*CC + c] = a0 / (1.f + expf(-a0));
    out[(tb+1)*CC + c] = a1 / (1.f + expf(-a1));
    out[(tb+2)*CC + c] = a2 / (1.f + expf(-a2));
    out[(tb+3)*CC + c] = a3 / (1.f + expf(-a3));
  }
}

// ---------------------------------------------------------------- grouped conv KxK (2 in-ch/out-ch), 4 pixels/thread
template<int K>
__global__ __launch_bounds__(256) void k_gconv(const float* __restrict__ in,
    const float* __restrict__ w, float* __restrict__ out) {
  __shared__ float wl[K*K*128];
  int tid = threadIdx.x;
  for (int i = tid; i < 128*K*K; i += 256) {
    int tap = i >> 7, ch = i & 127;
    wl[i] = w[ch*(K*K) + tap];           // wl[tap*128 + ch]
  }
  __syncthreads();
  size_t g = (size_t)blockIdx.x*256 + tid;
  int oc = (int)(g & 63);
  float wx[K*K], wy[K*K];
  #pragma unroll
  for (int t = 0; t < K*K; t++) {
    wx[t] = wl[t*128 + 2*oc];
    wy[t] = wl[t*128 + 2*oc + 1];
  }
  size_t s = g >> 6;                     // strip index: B*H*(W/4)
  int w0 = (int)(s & 31) * 4;
  int hp = (int)((s >> 5) & 127);
  int b  = (int)(s >> 12);
  const float* ip = in + (size_t)b*L_*128 + 2*oc;
  constexpr int P = K/2;
  float a0 = 0.f, a1 = 0.f, a2 = 0.f, a3 = 0.f;
  #pragma unroll
  for (int kh = 0; kh < K; kh++) {
    int h2 = hp + kh - P;
    if ((unsigned)h2 >= 128u) continue;
    const float* rp = ip + (size_t)h2*W_*128;
    float2 px[K+3];
    #pragma unroll
    for (int x = 0; x < K+3; x++) {
      int w2 = w0 - P + x;
      px[x] = ((unsigned)w2 < 128u) ? *(const float2*)(rp + (size_t)w2*128)
                                    : make_float2(0.f, 0.f);
    }
    #pragma unroll
    for (int kw = 0; kw < K; kw++) {
      float fx = wx[kh*K + kw], fy = wy[kh*K + kw];
      a0 += fx*px[kw+0].x + fy*px[kw+0].y;
      a1 += fx*px[kw+1].x + fy*px[kw+1].y;
      a2 += fx*px[kw+2].x + fy*px[kw+2].y;
      a3 += fx*px[kw+3].x + fy*px[kw+3].y;
    }
  }
  size_t tb = (size_t)b*L_ + (size_t)hp*W_ + w0;
  out[(tb+0)*64 + oc] = a0;
  out[(tb+1)*64 + oc] = a1;
  out[(tb+2)*64 + oc] = a2;
  out[(tb+3)*64 + oc] = a3;
}

// ---------------------------------------------------------------- MFMA token GEMM (seq, bf16 W from global)
template<int CIN, int COUT, int EPI, bool MUL>   // EPI 0:none 1:bias 2:bias+silu 3:bias+elu+1
__global__ __launch_bounds__(256) void k_mfma_tok(
    const float* __restrict__ in, const float* __restrict__ mulp,
    const bf16_t* __restrict__ W16, const float* __restrict__ bias,
    float* __restrict__ out) {
  constexpr int NO = COUT/16;
  int tid = threadIdx.x;
  int lane = tid & 63, wv = tid >> 6;
  int m = lane & 15, q = lane >> 4;
  size_t t0 = (size_t)blockIdx.x*64 + (size_t)wv*16;
  f32x4 acc[NO];
  #pragma unroll
  for (int i = 0; i < NO; i++) acc[i] = (f32x4){0.f,0.f,0.f,0.f};
  for (int k0 = 0; k0 < CIN; k0 += 32) {
    const float* ap = in + (t0 + m)*CIN + k0 + q*8;
    float4 a0 = *(const float4*)ap;
    float4 a1 = *(const float4*)(ap + 4);
    if (MUL) {
      const float* mp = mulp + (t0 + m)*CIN + k0 + q*8;
      float4 m0 = *(const float4*)mp;
      float4 m1 = *(const float4*)(mp + 4);
      a0.x*=m0.x; a0.y*=m0.y; a0.z*=m0.z; a0.w*=m0.w;
      a1.x*=m1.x; a1.y*=m1.y; a1.z*=m1.z; a1.w*=m1.w;
    }
    union { short s[8]; short8 v; } af;
    af.s[0]=(short)f2b(a0.x); af.s[1]=(short)f2b(a0.y);
    af.s[2]=(short)f2b(a0.z); af.s[3]=(short)f2b(a0.w);
    af.s[4]=(short)f2b(a1.x); af.s[5]=(short)f2b(a1.y);
    af.s[6]=(short)f2b(a1.z); af.s[7]=(short)f2b(a1.w);
    #pragma unroll
    for (int o = 0; o < NO; o++) {
      short8 bf = *(const short8*)(W16 + (size_t)(o*16 + m)*CIN + k0 + q*8);
      acc[o] = __builtin_amdgcn_mfma_f32_16x16x32_bf16(af.v, bf, acc[o], 0, 0, 0);
    }
  }
  #pragma unroll
  for (int o = 0; o < NO; o++) {
    float bv = (EPI >= 1) ? bias[o*16 + m] : 0.f;
    #pragma unroll
    for (int r = 0; r < 4; r++) {
      int row = q*4 + r;
      float v = acc[o][r] + bv;
      if (EPI == 2) v = v / (1.f + expf(-v));
      if (EPI == 3) v = v > 0.f ? v + 1.f : expf(v);
      out[(t0 + row)*COUT + o*16 + m] = v;
    }
  }
}

// ---------------------------------------------------------------- MFMA GEMM, seq input(s) -> planar output (c1 / red)
template<int CIN, bool DUALOUT, bool ADDX>
__global__ __launch_bounds__(256) void k_mfma_pout(
    const float* __restrict__ in1, const float* __restrict__ in2,
    const bf16_t* __restrict__ W16, const float* __restrict__ bias,
    const float* __restrict__ gam, const float* __restrict__ bet,
    const float* __restrict__ addp, void* __restrict__ out,
    const int* __restrict__ flagp) {
  constexpr int NO = 8;
  int fl = DUALOUT ? *flagp : 1;
  int tid = threadIdx.x;
  int lane = tid & 63, wv = tid >> 6;
  int m = lane & 15, q = lane >> 4;
  size_t t0 = (size_t)blockIdx.x*64 + (size_t)wv*16;
  f32x4 acc[NO];
  #pragma unroll
  for (int i = 0; i < NO; i++) acc[i] = (f32x4){0.f,0.f,0.f,0.f};
  for (int k0 = 0; k0 < CIN; k0 += 32) {
    const float* src = (CIN == 128 || k0 < 128)
        ? (in1 + (t0 + m)*128 + k0)
        : (in2 + (t0 + m)*128 + (k0 - 128));
    float4 a0 = *(const float4*)(src + q*8);
    float4 a1 = *(const float4*)(src + q*8 + 4);
    union { short s[8]; short8 v; } af;
    af.s[0]=(short)f2b(a0.x); af.s[1]=(short)f2b(a0.y);
    af.s[2]=(short)f2b(a0.z); af.s[3]=(short)f2b(a0.w);
    af.s[4]=(short)f2b(a1.x); af.s[5]=(short)f2b(a1.y);
    af.s[6]=(short)f2b(a1.z); af.s[7]=(short)f2b(a1.w);
    #pragma unroll
    for (int o = 0; o < NO; o++) {
      short8 bf = *(const short8*)(W16 + (size_t)(o*16 + m)*CIN + k0 + q*8);
      acc[o] = __builtin_amdgcn_mfma_f32_16x16x32_bf16(af.v, bf, acc[o], 0, 0, 0);
    }
  }
  int b = (int)(t0 >> 14);
  int p0 = (int)(t0 & (L_-1)) + q*4;
  #pragma unroll
  for (int ot = 0; ot < NO; ot++) {
    int o = ot*16 + m;
    float bi = bias[o], gm = gam[o]*BN_INV, be = bet[o];
    size_t idx = ((size_t)b*128 + o)*L_ + p0;
    float4 r4;
    float* rr = (float*)&r4;
    #pragma unroll
    for (int r = 0; r < 4; r++) {
      float v = acc[ot][r] + bi;
      v = fmaxf(v*gm + be, 0.f);
      rr[r] = v;
    }
    if (ADDX) {
      float4 av = *(const float4*)(addp + idx);
      r4.x += av.x; r4.y += av.y; r4.z += av.z; r4.w += av.w;
    }
    if (DUALOUT && !fl) {
      ushort4 s4;
      s4.x = f2b(r4.x); s4.y = f2b(r4.y); s4.z = f2b(r4.z); s4.w = f2b(r4.w);
      *(ushort4*)((bf16_t*)out + idx) = s4;
    } else {
      *(float4*)((float*)out + idx) = r4;
    }
  }
}

// ---------------------------------------------------------------- LN / LN+FFN
__global__ __launch_bounds__(256) void k_ln(const float* __restrict__ in,
    const float* __restrict__ g, const float* __restrict__ be, float* __restrict__ out) {
  int tid = threadIdx.x, lane = tid & 63;
  size_t t = (size_t)blockIdx.x*4 + (tid >> 6);
  const float* row = in + t*128;
  float2 v = *(const float2*)(row + lane*2);
  float s = v.x + v.y, ss = v.x*v.x + v.y*v.y;
  #pragma unroll
  for (int m = 1; m < 64; m <<= 1) { s += __shfl_xor(s, m); ss += __shfl_xor(ss, m); }
  float mean = s*(1.f/128.f);
  float inv = rsqrtf(ss*(1.f/128.f) - mean*mean + 1e-5f);
  float2 o;
  o.x = (v.x-mean)*inv*g[lane*2]   + be[lane*2];
  o.y = (v.y-mean)*inv*g[lane*2+1] + be[lane*2+1];
  *(float2*)(out + t*128 + lane*2) = o;
}

__global__ __launch_bounds__(256) void k_ln_ffn(const float* __restrict__ in,
    const float* __restrict__ g, const float* __restrict__ be,
    const float* __restrict__ w1, const float* __restrict__ b1,
    const float* __restrict__ w2, const float* __restrict__ b2,
    float* __restrict__ out) {
  int tid = threadIdx.x, lane = tid & 63;
  size_t t = (size_t)blockIdx.x*4 + (tid >> 6);
  const float* row = in + t*128;
  float2 v = *(const float2*)(row + lane*2);
  float s = v.x + v.y, ss = v.x*v.x + v.y*v.y;
  #pragma unroll
  for (int m = 1; m < 64; m <<= 1) { s += __shfl_xor(s, m); ss += __shfl_xor(ss, m); }
  float mean = s*(1.f/128.f);
  float inv = rsqrtf(ss*(1.f/128.f) - mean*mean + 1e-5f);
  float hx = (v.x-mean)*inv*g[lane*2]   + be[lane*2];
  float hy = (v.y-mean)*inv*g[lane*2+1] + be[lane*2+1];
  float hp0 = hx*w1[0*128+lane*2] + hy*w1[0*128+lane*2+1];
  float hp1 = hx*w1[1*128+lane*2] + hy*w1[1*128+lane*2+1];
  float hp2 = hx*w1[2*128+lane*2] + hy*w1[2*128+lane*2+1];
  float hp3 = hx*w1[3*128+lane*2] + hy*w1[3*128+lane*2+1];
  #pragma unroll
  for (int m = 1; m < 64; m <<= 1) {
    hp0 += __shfl_xor(hp0, m); hp1 += __shfl_xor(hp1, m);
    hp2 += __shfl_xor(hp2, m); hp3 += __shfl_xor(hp3, m);
  }
  float hv0, hv1, hv2, hv3;
  { float a = hp0 + b1[0]; hv0 = 0.5f*a*(1.f+erff(a*0.7071067811865476f)); }
  { float a = hp1 + b1[1]; hv1 = 0.5f*a*(1.f+erff(a*0.7071067811865476f)); }
  { float a = hp2 + b1[2]; hv2 = 0.5f*a*(1.f+erff(a*0.7071067811865476f)); }
  { float a = hp3 + b1[3]; hv3 = 0.5f*a*(1.f+erff(a*0.7071067811865476f)); }
  int cx = lane*2, cy = lane*2+1;
  float2 o;
  o.x = hv0*w2[cx*4+0] + hv1*w2[cx*4+1] + hv2*w2[cx*4+2] + hv3*w2[cx*4+3] + b2[cx];
  o.y = hv0*w2[cy*4+0] + hv1*w2[cy*4+1] + hv2*w2[cy*4+2] + hv3*w2[cy*4+3] + b2[cy];
  *(float2*)(out + t*128 + lane*2) = o;
}

// ---------------------------------------------------------------- linear attention
__global__ __launch_bounds__(256) void k_kv(
    const float* __restrict__ qk, const float* __restrict__ v,
    float* __restrict__ akv_g, float* __restrict__ aks_g) {
  __shared__ float kvred[512];
  __shared__ float ksred[64];
  int tid = threadIdx.x;
  for (int i = tid; i < 512; i += 256) kvred[i] = 0.f;
  if (tid < 64) ksred[tid] = 0.f;
  __syncthreads();
  int lane = tid & 63, wv = tid >> 6;
  size_t t0 = (size_t)blockIdx.x * 64;
  int b = (int)(t0 >> 14);
  int pr = lane >> 1;
  float theta = exp2f(-(float)(pr & 15) * THETA_SC);
  bool use_i = pr < 16;
  int hbase = lane & 56;
  float akv[8];
  #pragma unroll
  for (int d = 0; d < 8; d++) akv[d] = 0.f;
  float aks = 0.f;
  for (int it = 0; it < 16; it++) {
    size_t t = t0 + (size_t)wv*16 + it;
    float k = qk[t*128 + 64 + lane];
    float xv = v[t*64 + lane];
    int l = (int)(t & (L_-1));
    float pos = use_i ? (float)(l >> 7) : (float)(l & 127);
    float sn, cs; sincosf(pos*theta, &sn, &cs);
    float kp = __shfl_xor(k, 1);
    float kr = (lane & 1) ? (sn*kp + cs*k) : (cs*k - sn*kp);
    #pragma unroll
    for (int d = 0; d < 8; d++) {
      float krd = __shfl(kr, hbase + d);
      akv[d] += krd * xv;
    }
    aks += k;
  }
  int h8 = lane >> 3, e = lane & 7;
  #pragma unroll
  for (int d = 0; d < 8; d++)
    atomicAdd(&kvred[h8*64 + d*8 + e], akv[d]);
  atomicAdd(&ksred[lane], aks);
  __syncthreads();
  for (int i = tid; i < 512; i += 256) atomicAdd(&akv_g[b*512 + i], kvred[i]);
  if (tid < 64) atomicAdd(&aks_g[b*64 + tid], ksred[tid]);
}

__global__ __launch_bounds__(256) void k_attn2(
    const float* __restrict__ qk, const float* __restrict__ x,
    const float* __restrict__ akv_g, const float* __restrict__ aks_g,
    const float* __restrict__ lw, const float* __restrict__ lb,
    float* __restrict__ out, int coff) {
  __shared__ float kv[512];
  __shared__ float km[64];
  __shared__ float lwl[576];
  int tid = threadIdx.x;
  size_t t0 = (size_t)blockIdx.x * 32;
  int b = (int)(t0 >> 14);
  const float invn = 1.f/16384.f;
  for (int i = tid; i < 512; i += 256) kv[i] = akv_g[b*512 + i]*invn;
  if (tid < 64) km[tid] = aks_g[b*64 + tid]*invn;
  for (int i = tid; i < 576; i += 256) lwl[i] = lw[i];
  __syncthreads();
  int lane = tid & 63, wv = tid >> 6;
  int pr = lane >> 1;
  float theta = exp2f(-(float)(pr & 15) * THETA_SC);
  bool use_i = pr < 16;
  int hbase = lane & 56, e = lane & 7;
  float lbv = lb[lane];
  const float* xb = x + ((size_t)b << 14) * 64;
  for (int it = 0; it < 8; it++) {
    size_t t = t0 + (size_t)wv*8 + it;
    int l = (int)(t & (L_-1));
    int ipos = l >> 7, jpos = l & 127;
    float q = qk[t*128 + lane];
    float p = q * km[lane];
    p += __shfl_xor(p, 1); p += __shfl_xor(p, 2); p += __shfl_xor(p, 4);
    float z = 1.f/(p + 1e-6f);
    float pos = use_i ? (float)ipos : (float)jpos;
    float sn, cs; sincosf(pos*theta, &sn, &cs);
    float qp = __shfl_xor(q, 1);
    float qr = (lane & 1) ? (sn*qp + cs*q) : (cs*q - sn*qp);
    float acc = 0.f;
    #pragma unroll
    for (int d = 0; d < 8; d++) {
      float qrd = __shfl(qr, hbase + d);
      acc += qrd * kv[hbase*8 + d*8 + e];
    }
    acc *= z;
    float lp = lbv;
    #pragma unroll
    for (int dh = -1; dh <= 1; dh++) {
      int h2 = ipos + dh; if ((unsigned)h2 >= 128u) continue;
      #pragma unroll
      for (int dw = -1; dw <= 1; dw++) {
        int w2 = jpos + dw; if ((unsigned)w2 >= 128u) continue;
        lp += lwl[lane*9 + (dh+1)*3 + (dw+1)] * xb[((size_t)(h2 << 7) + w2)*64 + lane];
      }
    }
    out[t*128 + coff + lane] = acc + lp;
  }
}

// ---------------------------------------------------------------- launcher
extern "C" void kernel_launch(void* const* d_in, const int* in_sizes, int n_in,
                              void* d_out, int out_size, void* d_ws, size_t ws_size,
                              hipStream_t stream) {
  (void)in_sizes; (void)n_in; (void)out_size;

  float* base;
  if (ws_size >= WSF * sizeof(float)) {
    base = (float*)d_ws;
  } else {
    void* p = nullptr;
    hipGetSymbolAddress(&p, HIP_SYMBOL(g_ws));
    base = (float*)p;
  }
  float* P0 = base;          // x0 (planar, persists)
  float* PA = base + 1*NS;   // xseq / x_s / ACT
  float* PB = base + 2*NS;   // XT shortcut / XT2 / fmt2 planar / x0 seq
  float* PC = base + 3*NS;   // fmt1 planar / XT3 / XT4
  float* PD = base + 4*NS;   // QK / xo seq
  float* PF = base + 5*NS;   // fft im / CAT / XSS / FFN
  float* H0 = base + 6*NS;
  float* H1 = H0 + NH;
  float* H2 = H1 + NH;
  float* WG = H2 + NH;                  // B*8*L
  float* ACC = WG + WGSZ;               // 2304
  float* CW  = ACC + ACCSZ;             // fp32 weights
  bf16_t* CW16 = (bf16_t*)(CW + CWSZ);  // bf16 weight mirror
  int*   FLG = (int*)(CW + CWSZ + CW16SZF);

  static const int wsz[47] = {
    16384,128,128,128,1152,128,1024,8,8,8,1024,128,128,128,128,128,
    16384,128,1152,16384,128,3200,16384,128,4096,64,576,64,8192,128,
    576,64,16384,128,1152,128,128,128,512,4,512,128,16384,32768,128,128,128};
  int woff[47]; { int a = 0; for (int i = 0; i < 47; i++){ woff[i] = a; a += wsz[i]; } }
  const float* Wf[47]; for (int i = 0; i < 47; i++) Wf[i] = CW + woff[i];
  auto W16 = [&](int i){ return (const bf16_t*)(CW16 + woff[i] + (woff[i] >= W16SHIFT ? 4 : 0)); };
  const float *c1_b=Wf[1], *c1_g=Wf[2], *c1_be=Wf[3], *cpe1_w=Wf[4],
    *cpe1_b=Wf[5], *fw1=Wf[6], *fb1=Wf[7], *f_g=Wf[8], *f_be=Wf[9], *fw2=Wf[10],
    *fb2=Wf[11], *nbn_g=Wf[12], *nbn_be=Wf[13], *ln1_g=Wf[14], *ln1_b=Wf[15],
    *d3b1=Wf[17], *d3w2=Wf[18], *d5b1=Wf[20],
    *d5w2=Wf[21], *ap_b=Wf[23], *ip2_b=Wf[25],
    *dwc2_w=Wf[26], *dwc2_b=Wf[27], *qk_b=Wf[29], *lepe_w=Wf[30],
    *lepe_b=Wf[31], *op_b=Wf[33], *cpe2_w=Wf[34], *cpe2_b=Wf[35],
    *ln2_g=Wf[36], *ln2_b=Wf[37], *ffn_w1=Wf[38], *ffn_b1=Wf[39], *ffn_w2=Wf[40],
    *ffn_b2=Wf[41], *red_b=Wf[44], *red_g=Wf[45], *red_be=Wf[46];
  const bf16_t *c1_w16=W16(0), *d3w1_16=W16(16), *d5w1_16=W16(19), *ap_w16=W16(22),
    *ip2_w16=W16(24), *qk_w16=W16(28), *op_w16=W16(32), *po_w16=W16(42), *red_w16=W16(43);

  const void* x = d_in[0];

  // 0. dtype probe + weight conversion (fp32 + bf16 mirror)
  k_probe<<<1, 256, 0, stream>>>((const bf16_t*)x, FLG);
  P47 ps; for (int i = 0; i < 47; i++) ps.p[i] = d_in[i+1];
  k_cvt<<<(TOTW+255)/256, 256, 0, stream>>>(ps, FLG, CW);
  k_cvt16<<<(TOTW+255)/256, 256, 0, stream>>>(CW, CW16);

  dim3 tgrid(512, 4, 4), tblk(32, 8);

  auto fmt = [&](float* tp, float* im) {
    k_fft_row_fwd<<<16384, 256, 0, stream>>>(tp, tp, im);
    k_fft_col<true><<<2048, 256, 0, stream>>>(tp, im);
    k_freq1<<<256, 256, 0, stream>>>(tp, fw1, fb1, f_g, f_be, WG);
    k_freq2<<<32768, 256, 0, stream>>>(WG, fw2, fb2, tp, im);
    k_fft_col<false><<<2048, 256, 0, stream>>>(tp, im);
    k_fft_row_inv_abs<<<16384, 256, 0, stream>>>(tp, im, nbn_g, nbn_be);
  };

  auto attn = [&](const float* brin, float* qkbuf, int coff) {
    k_zero<<<9, 256, 0, stream>>>(ACC, 2304);
    k_mfma_tok<64,128,3,false><<<1024, 256, 0, stream>>>(brin, nullptr, qk_w16, qk_b, qkbuf);
    k_kv<<<1024, 256, 0, stream>>>(qkbuf, brin, ACC, ACC + B_*512);
    k_attn2<<<2048, 256, 0, stream>>>(qkbuf, brin, ACC, ACC + B_*512, lepe_w, lepe_b, PF, coff);
  };

  // 2. x -> seq                                           -> PA
  k_p2s<true><<<tgrid, tblk, 0, stream>>>(x, PA, nullptr, nullptr, FLG);
  // 1. x_0 = relu(bn(conv1x1(x)))                         -> P0 (planar)
  k_mfma_pout<128,false,false><<<1024, 256, 0, stream>>>(
      PA, nullptr, c1_w16, c1_b, c1_g, c1_be, nullptr, P0, FLG);
  // 3. xt = x + dw3(x,cpe1)+b                             -> PB (shortcut)
  k_dw3<128,0><<<8192, 256, 0, stream>>>(PA, cpe1_w, cpe1_b, PB);
  // 4. fmt1 -> PC (planar)
  k_s2p<<<tgrid, tblk, 0, stream>>>(PB, PC);
  fmt(PC, PF);
  // 5. x_s = ln(xt)                                       -> PA
  k_ln<<<16384, 256, 0, stream>>>(PB, ln1_g, ln1_b, PA);
  // 6. multi-scale convs
  k_mfma_tok<128,128,1,false><<<1024, 256, 0, stream>>>(PA, nullptr, d3w1_16, d3b1, PD);
  k_gconv<3><<<4096, 256, 0, stream>>>(PD, d3w2, H0);
  k_mfma_tok<128,128,1,false><<<1024, 256, 0, stream>>>(PA, nullptr, d5w1_16, d5b1, PD);
  k_gconv<5><<<4096, 256, 0, stream>>>(PD, d5w2, H1);
  k_mfma_tok<128,128,2,false><<<1024, 256, 0, stream>>>(PA, nullptr, ap_w16, ap_b, PA); // in-place: ACT
  // 7. branch3 -> attention -> CAT[:, :, 0:64] in PF
  k_mfma_tok<64,64,1,false><<<1024, 256, 0, stream>>>(H0, nullptr, ip2_w16, ip2_b, H2);
  k_dw3<64,1><<<4096, 256, 0, stream>>>(H2, dwc2_w, dwc2_b, H0);
  attn(H0, PD, 0);
  //    branch5 -> attention -> CAT[:, :, 64:128]
  k_mfma_tok<64,64,1,false><<<1024, 256, 0, stream>>>(H1, nullptr, ip2_w16, ip2_b, H2);
  k_dw3<64,1><<<4096, 256, 0, stream>>>(H2, dwc2_w, dwc2_b, H1);
  attn(H1, PD, 64);
  // 8. xss = conv1x1(CAT * ACT, op_w)+op_b                -> PF (in-place)
  k_mfma_tok<128,128,1,true><<<1024, 256, 0, stream>>>(PF, PA, op_w16, op_b, PF);
  // 9. xt2 = shortcut + xss + fmt1                        -> PB (in-place add1)
  k_p2s<false><<<tgrid, tblk, 0, stream>>>(PC, PB, PB, PF, nullptr);
  // 10. xt3 = xt2 + dw3(xt2,cpe2)+b                       -> PC
  k_dw3<128,0><<<8192, 256, 0, stream>>>(PB, cpe2_w, cpe2_b, PC);
  // 11. fmt2 -> PB (planar)
  k_s2p<<<tgrid, tblk, 0, stream>>>(PC, PB);
  fmt(PB, PD);
  // 12. ffn(ln2(xt3))                                     -> PF
  k_ln_ffn<<<16384, 256, 0, stream>>>(PC, ln2_g, ln2_b, ffn_w1, ffn_b1, ffn_w2, ffn_b2, PF);
  // 13. xt4 = xt3 + ffn + fmt2                            -> PC (in-place add1)
  k_p2s<false><<<tgrid, tblk, 0, stream>>>(PB, PC, PC, PF, nullptr);
  // 14. xo = conv1x1(xt4, po_w)                           -> PD (seq)
  k_mfma_tok<128,128,0,false><<<1024, 256, 0, stream>>>(PC, nullptr, po_w16, nullptr, PD);
  // 15. x0 planar -> seq                                  -> PB
  k_p2s<false><<<tgrid, tblk, 0, stream>>>(P0, PB, nullptr, nullptr, nullptr);
  // 16. out = relu(bn(conv1x1([x0;xo], red))) + x0        -> d_out (planar, dtype per flag)
  k_mfma_pout<256,true,true><<<1024, 256, 0, stream>>>(
      PB, PD, red_w16, red_b, red_g, red_be, P0, d_out, FLG);
}

// Round 8
// 1036.358 us; speedup vs baseline: 1.5992x; 1.1103x over previous
//
#include <hip/hip_runtime.h>
#include <math.h>

typedef unsigned short bf16_t;
typedef __attribute__((ext_vector_type(8))) short short8;
typedef __attribute__((ext_vector_type(4))) float f32x4;

#define B_ 4
#define C_ 128
#define H_ 128
#define W_ 128
#define L_ (H_*W_)               // 16384
#define NS  ((size_t)B_*L_*C_)   // 8388608 elems
#define NH  ((size_t)B_*L_*64)
#define NSP ((size_t)L_*C_)
#define PI_F 3.14159265358979323846f
#define BN_INV 0.9999950000374997f   // (1+1e-5)^-0.5
#define THETA_SC 0.8304820237218406f // log2(10000)/16
#define TOTW 157148
#define W16SHIFT 107548              // offsets >= this get +4 in bf16 mirror (8-align po_w/red_w)

__device__ __forceinline__ float ldf(bf16_t v){ return __uint_as_float(((unsigned)v)<<16); }
__device__ __forceinline__ bf16_t f2b(float f){
  unsigned u = __float_as_uint(f);
  u += 0x7fffu + ((u>>16)&1u);     // RNE
  return (bf16_t)(u>>16);
}

// workspace layout
#define WGSZ ((size_t)B_*8*L_)       // 524288
#define ACCSZ 2304
#define CWSZ 157184                  // fp32 weights
#define CW16SZF 78592                // bf16 mirror in floats
#define WSF (6*NS + 3*NH + WGSZ + ACCSZ + CWSZ + CW16SZF + 16)
__device__ float g_ws[WSF];

// ---------------------------------------------------------------- dtype probe + weight convert
__global__ void k_probe(const bf16_t* __restrict__ xb, int* __restrict__ flag){
  __shared__ int vote;
  if (threadIdx.x == 0) vote = 0;
  __syncthreads();
  int bad = 0;
  for (int i = threadIdx.x; i < 2048; i += 256) {
    float v = ldf(xb[2*i]);
    if (!(fabsf(v) < 1e6f)) bad = 1;
  }
  if (bad) atomicOr(&vote, 1);
  __syncthreads();
  if (threadIdx.x == 0) *flag = vote;  // 1 = fp32 storage, 0 = bf16 storage
}

struct P47 { const void* p[47]; };
__device__ __constant__ int c_wsz[47] = {
  16384,128,128,128,1152,128,1024,8,8,8,1024,128,128,128,128,128,
  16384,128,1152,16384,128,3200,16384,128,4096,64,576,64,8192,128,
  576,64,16384,128,1152,128,128,128,512,4,512,128,16384,32768,128,128,128};

__global__ __launch_bounds__(256) void k_cvt(P47 ps, const int* __restrict__ flagp,
                                             float* __restrict__ dst){
  int g = blockIdx.x*256 + threadIdx.x;
  if (g >= TOTW) return;
  int fl = *flagp;
  int idx = 0, off = g;
  while (off >= c_wsz[idx]) { off -= c_wsz[idx]; idx++; }
  const void* s = ps.p[idx];
  dst[g] = fl ? ((const float*)s)[off] : ldf(((const bf16_t*)s)[off]);
}

__global__ __launch_bounds__(256) void k_cvt16(const float* __restrict__ src, bf16_t* __restrict__ dst){
  int g = blockIdx.x*256 + threadIdx.x;
  if (g >= TOTW) return;
  dst[g + (g >= W16SHIFT ? 4 : 0)] = f2b(src[g]);
}

__global__ void k_zero(float* p, int n){
  int i = blockIdx.x*256 + threadIdx.x;
  if (i < n) p[i] = 0.f;
}

// ---------------------------------------------------------------- FFT core
__device__ __forceinline__ void fft128_fwd(float& lor, float& loi, float& hir, float& hii, int lane) {
  {
    float s, c; sincosf(-PI_F * (float)lane * (1.f/64.f), &s, &c);
    float ar = lor, ai = loi;
    float dr = ar - hir, di = ai - hii;
    lor = ar + hir; loi = ai + hii;
    hir = dr*c - di*s; hii = dr*s + di*c;
  }
  #pragma unroll
  for (int m = 32; m >= 1; m >>= 1) {
    int k = lane & (m-1);
    float s, c; sincosf(-PI_F * (float)k / (float)m, &s, &c);
    bool up = (lane & m) != 0;
    {
      float orr = __shfl_xor(lor, m), oii = __shfl_xor(loi, m);
      float sr = lor + orr, si = loi + oii;
      float dr = orr - lor, di = oii - loi;
      float tr = dr*c - di*s, ti = dr*s + di*c;
      lor = up ? tr : sr; loi = up ? ti : si;
    }
    {
      float orr = __shfl_xor(hir, m), oii = __shfl_xor(hii, m);
      float sr = hir + orr, si = hii + oii;
      float dr = orr - hir, di = oii - hii;
      float tr = dr*c - di*s, ti = dr*s + di*c;
      hir = up ? tr : sr; hii = up ? ti : si;
    }
  }
}

__device__ __forceinline__ void fft128_inv(float& lor, float& loi, float& hir, float& hii, int lane) {
  #pragma unroll
  for (int m = 1; m <= 32; m <<= 1) {
    int k = lane & (m-1);
    float s, c; sincosf(PI_F * (float)k / (float)m, &s, &c);
    bool up = (lane & m) != 0;
    {
      float orr = __shfl_xor(lor, m), oii = __shfl_xor(loi, m);
      float qr = orr*c - oii*s, qi = orr*s + oii*c;
      float lo_r = lor + qr, lo_i = loi + qi;
      float mr = lor*c - loi*s, mi = lor*s + loi*c;
      float up_r = orr - mr, up_i = oii - mi;
      lor = up ? up_r : lo_r; loi = up ? up_i : lo_i;
    }
    {
      float orr = __shfl_xor(hir, m), oii = __shfl_xor(hii, m);
      float qr = orr*c - oii*s, qi = orr*s + oii*c;
      float lo_r = hir + qr, lo_i = hii + qi;
      float mr = hir*c - hii*s, mi = hir*s + hii*c;
      float up_r = orr - mr, up_i = oii - mi;
      hir = up ? up_r : lo_r; hii = up ? up_i : lo_i;
    }
  }
  {
    float s, c; sincosf(PI_F * (float)lane * (1.f/64.f), &s, &c);
    float qr = hir*c - hii*s, qi = hir*s + hii*c;
    float pr = lor, pi = loi;
    lor = pr + qr; loi = pi + qi;
    hir = pr - qr; hii = pi - qi;
  }
}

// fused seq-read + transpose + forward row FFT. Block = (b, h, c-half): 64ch x 128w.
__global__ __launch_bounds__(256) void k_fft_row_fwd_seq(
    const float* __restrict__ in, float* __restrict__ re, float* __restrict__ im) {
  __shared__ float T[64*130];
  int tid = threadIdx.x;
  int bid = blockIdx.x;
  int ch = (bid & 1) * 64;
  int h  = (bid >> 1) & 127;
  int b  = bid >> 8;
  const float* ip = in + ((size_t)b*L_ + (size_t)h*128)*128 + ch;
  #pragma unroll
  for (int it = 0; it < 8; it++) {
    int idx = it*256 + tid;            // 2048 float4 loads
    int c4 = (idx & 15)*4, w = idx >> 4;
    float4 v = *(const float4*)(ip + (size_t)w*128 + c4);
    T[(c4+0)*130 + w] = v.x;
    T[(c4+1)*130 + w] = v.y;
    T[(c4+2)*130 + w] = v.z;
    T[(c4+3)*130 + w] = v.w;
  }
  __syncthreads();
  int lane = tid & 63, wv = tid >> 6;
  size_t obase = (size_t)(b*128 + ch)*L_ + (size_t)h*128;
  for (int i = 0; i < 16; i++) {
    int cc = wv*16 + i;
    float lor = T[cc*130 + lane], loi = 0.f;
    float hir = T[cc*130 + 64 + lane], hii = 0.f;
    fft128_fwd(lor, loi, hir, hii, lane);
    size_t o = obase + (size_t)cc*L_;
    re[o + lane] = lor;      im[o + lane] = loi;
    re[o + lane + 64] = hir; im[o + lane + 64] = hii;
  }
}

__global__ __launch_bounds__(256) void k_fft_col_fwd(float* __restrict__ re, float* __restrict__ im) {
  __shared__ float Lre[128][33];
  __shared__ float Lim[128][33];
  int tid = threadIdx.x;
  size_t img = blockIdx.x >> 2;
  int w0 = (blockIdx.x & 3) * 32;
  float* rp = re + img * (size_t)L_ + w0;
  float* ip = im + img * (size_t)L_ + w0;
  for (int i = tid; i < 4096; i += 256) {
    int h = i >> 5, wl = i & 31;
    Lre[h][wl] = rp[(size_t)h*W_ + wl];
    Lim[h][wl] = ip[(size_t)h*W_ + wl];
  }
  __syncthreads();
  int lane = tid & 63, wv = tid >> 6;
  for (int i = 0; i < 8; i++) {
    int col = wv*8 + i;
    float lor = Lre[lane][col], loi = Lim[lane][col];
    float hir = Lre[lane+64][col], hii = Lim[lane+64][col];
    fft128_fwd(lor, loi, hir, hii, lane);
    Lre[lane][col]=lor; Lim[lane][col]=loi;
    Lre[lane+64][col]=hir; Lim[lane+64][col]=hii;
  }
  __syncthreads();
  for (int i = tid; i < 4096; i += 256) {
    int h = i >> 5, wl = i & 31;
    rp[(size_t)h*W_ + wl] = Lre[h][wl];
    ip[(size_t)h*W_ + wl] = Lim[h][wl];
  }
}

// inverse col FFT with freq2's sigmoid gating fused into the load phase.
__global__ __launch_bounds__(256) void k_fft_col_inv_scaled(
    float* __restrict__ re, float* __restrict__ im,
    const float* __restrict__ wg1, const float* __restrict__ fw2,
    const float* __restrict__ fb2) {
  __shared__ float Lre[128][33];
  __shared__ float Lim[128][33];
  __shared__ float w2r[8];
  int tid = threadIdx.x;
  size_t img = blockIdx.x >> 2;
  int c = (int)(img & 127);
  int b = (int)(img >> 7);
  int w0 = (blockIdx.x & 3) * 32;
  if (tid < 8) w2r[tid] = fw2[c*8 + tid];
  float b2 = fb2[c];
  float* rp = re + img * (size_t)L_ + w0;
  float* ip = im + img * (size_t)L_ + w0;
  const float* wgp = wg1 + (size_t)b*8*L_ + w0;
  __syncthreads();
  for (int i = tid; i < 4096; i += 256) {
    int h = i >> 5, wl = i & 31;
    size_t p = (size_t)h*W_ + wl;
    float a = b2;
    #pragma unroll
    for (int o = 0; o < 8; o++) a += w2r[o] * wgp[(size_t)o*L_ + p];
    float wgt = 1.f/(1.f+expf(-a));
    Lre[h][wl] = rp[p] * wgt;
    Lim[h][wl] = ip[p] * wgt;
  }
  __syncthreads();
  int lane = tid & 63, wv = tid >> 6;
  for (int i = 0; i < 8; i++) {
    int col = wv*8 + i;
    float lor = Lre[lane][col], loi = Lim[lane][col];
    float hir = Lre[lane+64][col], hii = Lim[lane+64][col];
    fft128_inv(lor, loi, hir, hii, lane);
    Lre[lane][col]=lor*(1.f/128.f); Lim[lane][col]=loi*(1.f/128.f);
    Lre[lane+64][col]=hir*(1.f/128.f); Lim[lane+64][col]=hii*(1.f/128.f);
  }
  __syncthreads();
  for (int i = tid; i < 4096; i += 256) {
    int h = i >> 5, wl = i & 31;
    rp[(size_t)h*W_ + wl] = Lre[h][wl];
    ip[(size_t)h*W_ + wl] = Lim[h][wl];
  }
}

// inverse row FFT + abs + bn + relu + transpose to seq with two fused residual adds.
// out may alias add1 (same-thread read-then-write).
__global__ __launch_bounds__(256) void k_fft_row_inv_abs_seq(
    const float* __restrict__ re, const float* __restrict__ im,
    const float* __restrict__ ng, const float* __restrict__ nbe,
    const float* __restrict__ add1, const float* __restrict__ add2,
    float* __restrict__ out) {
  __shared__ float T[64*130];
  int tid = threadIdx.x;
  int bid = blockIdx.x;
  int ch = (bid & 1) * 64;
  int h  = (bid >> 1) & 127;
  int b  = bid >> 8;
  int lane = tid & 63, wv = tid >> 6;
  size_t ibase = (size_t)(b*128 + ch)*L_ + (size_t)h*128;
  for (int i = 0; i < 16; i++) {
    int cc = wv*16 + i;
    size_t o = ibase + (size_t)cc*L_;
    float lor = re[o + lane], loi = im[o + lane];
    float hir = re[o + lane + 64], hii = im[o + lane + 64];
    fft128_inv(lor, loi, hir, hii, lane);
    float sg = ng[ch+cc]*BN_INV, sb = nbe[ch+cc];
    T[cc*130 + lane]      = fmaxf(sqrtf(lor*lor+loi*loi)*(1.f/128.f)*sg + sb, 0.f);
    T[cc*130 + 64 + lane] = fmaxf(sqrtf(hir*hir+hii*hii)*(1.f/128.f)*sg + sb, 0.f);
  }
  __syncthreads();
  size_t sb0 = ((size_t)b*L_ + (size_t)h*128)*128 + ch;
  #pragma unroll
  for (int it = 0; it < 8; it++) {
    int idx = it*256 + tid;
    int c4 = (idx & 15)*4, w = idx >> 4;
    size_t off = sb0 + (size_t)w*128 + c4;
    float4 v;
    v.x = T[(c4+0)*130 + w];
    v.y = T[(c4+1)*130 + w];
    v.z = T[(c4+2)*130 + w];
    v.w = T[(c4+3)*130 + w];
    float4 x1 = *(const float4*)(add1 + off);
    float4 x2 = *(const float4*)(add2 + off);
    v.x += x1.x + x2.x; v.y += x1.y + x2.y;
    v.z += x1.z + x2.z; v.w += x1.w + x2.w;
    *(float4*)(out + off) = v;
  }
}

// ---------------------------------------------------------------- freq hidden (8ch) conv
__global__ __launch_bounds__(256) void k_freq1(const float* __restrict__ tre,
    const float* __restrict__ fw1, const float* __restrict__ fb1,
    const float* __restrict__ fg, const float* __restrict__ fbe,
    float* __restrict__ wg1) {
  __shared__ float w1s[1024];
  int tid = threadIdx.x;
  for (int i = tid; i < 1024; i += 256) w1s[i] = fw1[i];
  __syncthreads();
  size_t g = (size_t)blockIdx.x*256 + tid;   // (b,p)
  int p = (int)(g & (L_-1));
  int b = (int)(g >> 14);
  const float* tp = tre + (size_t)b*128*L_ + p;
  float acc[8];
  #pragma unroll
  for (int o = 0; o < 8; o++) acc[o] = 0.f;
  for (int c = 0; c < 128; c++) {
    float v = tp[(size_t)c*L_];
    #pragma unroll
    for (int o = 0; o < 8; o++) acc[o] += w1s[o*128+c]*v;
  }
  size_t ob = (size_t)b*8*L_ + p;
  #pragma unroll
  for (int o = 0; o < 8; o++) {
    float v = (acc[o] + fb1[o]) * (fg[o]*BN_INV) + fbe[o];
    wg1[ob + (size_t)o*L_] = fmaxf(v, 0.f);
  }
}

// ---------------------------------------------------------------- planar->seq transpose
template<bool DUAL>
__global__ void k_p2s(const void* __restrict__ src, float* __restrict__ dst,
                      const float* __restrict__ add1, const float* __restrict__ add2,
                      const int* __restrict__ flagp) {
  __shared__ float tile[32][33];
  int fl = DUAL ? *flagp : 1;
  int b = blockIdx.z;
  int p0 = blockIdx.x*32, c0 = blockIdx.y*32;
  int tx = threadIdx.x, ty = threadIdx.y;
  size_t base_in = (size_t)b*NSP;
  #pragma unroll
  for (int k = 0; k < 4; k++) {
    size_t off = base_in + (size_t)(c0+ty+8*k)*L_ + p0 + tx;
    float v;
    if (DUAL && !fl) v = ldf(((const bf16_t*)src)[off]);
    else             v = ((const float*)src)[off];
    tile[ty+8*k][tx] = v;
  }
  __syncthreads();
  size_t base = (size_t)b*NSP;
  #pragma unroll
  for (int k = 0; k < 4; k++) {
    size_t idx = base + (size_t)(p0+ty+8*k)*C_ + c0 + tx;
    float v = tile[tx][ty+8*k];
    if (add1) v += add1[idx];
    if (add2) v += add2[idx];
    dst[idx] = v;
  }
}

// ---------------------------------------------------------------- depthwise 3x3 (NHWC), 4 pixels/thread
template<int CC, int MODE>  // MODE 0: out = in + dw + b ; MODE 1: out = silu(dw + b)
__global__ __launch_bounds__(256) void k_dw3(const float* __restrict__ in,
    const float* __restrict__ w, const float* __restrict__ bias,
    float* __restrict__ out) {
  __shared__ float wl[9*CC];
  int tid = threadIdx.x;
  for (int i = tid; i < 9*CC; i += 256) {
    int tap = i / CC, ch = i % CC;
    wl[i] = w[ch*9 + tap];
  }
  __syncthreads();
  size_t g = (size_t)blockIdx.x*256 + tid;
  int c = (int)(g & (CC-1));
  float wr[9];
  #pragma unroll
  for (int t = 0; t < 9; t++) wr[t] = wl[t*CC + c];
  size_t s = g / CC;
  int w0 = (int)(s & 31) * 4;
  int hp = (int)((s >> 5) & 127);
  int b  = (int)(s >> 12);
  const float* ip = in + (size_t)b*L_*CC + c;
  float bi = bias[c];
  float a0 = bi, a1 = bi, a2 = bi, a3 = bi;
  #pragma unroll
  for (int dh = -1; dh <= 1; dh++) {
    int h2 = hp + dh;
    if ((unsigned)h2 >= 128u) continue;
    const float* rp = ip + (size_t)h2*W_*CC;
    float px[6];
    #pragma unroll
    for (int x = 0; x < 6; x++) {
      int w2 = w0 - 1 + x;
      px[x] = ((unsigned)w2 < 128u) ? rp[(size_t)w2*CC] : 0.f;
    }
    #pragma unroll
    for (int dw = 0; dw < 3; dw++) {
      float f = wr[(dh+1)*3 + dw];
      a0 += f*px[dw];   a1 += f*px[dw+1];
      a2 += f*px[dw+2]; a3 += f*px[dw+3];
    }
  }
  size_t tb = (size_t)b*L_ + (size_t)hp*W_ + w0;
  if (MODE == 0) {
    out[(tb+0)*CC + c] = in[(tb+0)*CC + c] + a0;
    out[(tb+1)*CC + c] = in[(tb+1)*CC + c] + a1;
    out[(tb+2)*CC + c] = in[(tb+2)*CC + c] + a2;
    out[(tb+3)*CC + c] = in[(tb+3)*CC + c] + a3;
  } else {
    out[(tb+0)*CC + c] = a0 / (1.f + expf(-a0));
    out[(tb+1)*CC + c] = a1 / (1.f + expf(-a1));
    out[(tb+2)*CC + c] = a2 / (1.f + expf(-a2));
    out[(tb+3)*CC + c] = a3 / (1.f + expf(-a3));
  }
}

// ---------------------------------------------------------------- grouped conv KxK, 4 pixels/thread
template<int K>
__global__ __launch_bounds__(256) void k_gconv(const float* __restrict__ in,
    const float* __restrict__ w, float* __restrict__ out) {
  __shared__ float wl[K*K*128];
  int tid = threadIdx.x;
  for (int i = tid; i < 128*K*K; i += 256) {
    int tap = i >> 7, ch = i & 127;
    wl[i] = w[ch*(K*K) + tap];
  }
  __syncthreads();
  size_t g = (size_t)blockIdx.x*256 + tid;
  int oc = (int)(g & 63);
  float wx[K*K], wy[K*K];
  #pragma unroll
  for (int t = 0; t < K*K; t++) {
    wx[t] = wl[t*128 + 2*oc];
    wy[t] = wl[t*128 + 2*oc + 1];
  }
  size_t s = g >> 6;
  int w0 = (int)(s & 31) * 4;
  int hp = (int)((s >> 5) & 127);
  int b  = (int)(s >> 12);
  const float* ip = in + (size_t)b*L_*128 + 2*oc;
  constexpr int P = K/2;
  float a0 = 0.f, a1 = 0.f, a2 = 0.f, a3 = 0.f;
  #pragma unroll
  for (int kh = 0; kh < K; kh++) {
    int h2 = hp + kh - P;
    if ((unsigned)h2 >= 128u) continue;
    const float* rp = ip + (size_t)h2*W_*128;
    float2 px[K+3];
    #pragma unroll
    for (int x = 0; x < K+3; x++) {
      int w2 = w0 - P + x;
      px[x] = ((unsigned)w2 < 128u) ? *(const float2*)(rp + (size_t)w2*128)
                                    : make_float2(0.f, 0.f);
    }
    #pragma unroll
    for (int kw = 0; kw < K; kw++) {
      float fx = wx[kh*K + kw], fy = wy[kh*K + kw];
      a0 += fx*px[kw+0].x + fy*px[kw+0].y;
      a1 += fx*px[kw+1].x + fy*px[kw+1].y;
      a2 += fx*px[kw+2].x + fy*px[kw+2].y;
      a3 += fx*px[kw+3].x + fy*px[kw+3].y;
    }
  }
  size_t tb = (size_t)b*L_ + (size_t)hp*W_ + w0;
  out[(tb+0)*64 + oc] = a0;
  out[(tb+1)*64 + oc] = a1;
  out[(tb+2)*64 + oc] = a2;
  out[(tb+3)*64 + oc] = a3;
}

// ---------------------------------------------------------------- MFMA token GEMM (seq, bf16 W from global)
template<int CIN, int COUT, int EPI, bool MUL>   // EPI 0:none 1:bias 2:bias+silu 3:bias+elu+1
__global__ __launch_bounds__(256) void k_mfma_tok(
    const float* __restrict__ in, const float* __restrict__ mulp,
    const bf16_t* __restrict__ W16, const float* __restrict__ bias,
    float* __restrict__ out) {
  constexpr int NO = COUT/16;
  int tid = threadIdx.x;
  int lane = tid & 63, wv = tid >> 6;
  int m = lane & 15, q = lane >> 4;
  size_t t0 = (size_t)blockIdx.x*64 + (size_t)wv*16;
  f32x4 acc[NO];
  #pragma unroll
  for (int i = 0; i < NO; i++) acc[i] = (f32x4){0.f,0.f,0.f,0.f};
  for (int k0 = 0; k0 < CIN; k0 += 32) {
    const float* ap = in + (t0 + m)*CIN + k0 + q*8;
    float4 a0 = *(const float4*)ap;
    float4 a1 = *(const float4*)(ap + 4);
    if (MUL) {
      const float* mp = mulp + (t0 + m)*CIN + k0 + q*8;
      float4 m0 = *(const float4*)mp;
      float4 m1 = *(const float4*)(mp + 4);
      a0.x*=m0.x; a0.y*=m0.y; a0.z*=m0.z; a0.w*=m0.w;
      a1.x*=m1.x; a1.y*=m1.y; a1.z*=m1.z; a1.w*=m1.w;
    }
    union { short s[8]; short8 v; } af;
    af.s[0]=(short)f2b(a0.x); af.s[1]=(short)f2b(a0.y);
    af.s[2]=(short)f2b(a0.z); af.s[3]=(short)f2b(a0.w);
    af.s[4]=(short)f2b(a1.x); af.s[5]=(short)f2b(a1.y);
    af.s[6]=(short)f2b(a1.z); af.s[7]=(short)f2b(a1.w);
    #pragma unroll
    for (int o = 0; o < NO; o++) {
      short8 bf = *(const short8*)(W16 + (size_t)(o*16 + m)*CIN + k0 + q*8);
      acc[o] = __builtin_amdgcn_mfma_f32_16x16x32_bf16(af.v, bf, acc[o], 0, 0, 0);
    }
  }
  #pragma unroll
  for (int o = 0; o < NO; o++) {
    float bv = (EPI >= 1) ? bias[o*16 + m] : 0.f;
    #pragma unroll
    for (int r = 0; r < 4; r++) {
      int row = q*4 + r;
      float v = acc[o][r] + bv;
      if (EPI == 2) v = v / (1.f + expf(-v));
      if (EPI == 3) v = v > 0.f ? v + 1.f : expf(v);
      out[(t0 + row)*COUT + o*16 + m] = v;
    }
  }
}

// ---------------------------------------------------------------- MFMA GEMM, seq input(s) -> planar output
template<int CIN, bool DUALOUT, bool ADDX>
__global__ __launch_bounds__(256) void k_mfma_pout(
    const float* __restrict__ in1, const float* __restrict__ in2,
    const bf16_t* __restrict__ W16, const float* __restrict__ bias,
    const float* __restrict__ gam, const float* __restrict__ bet,
    const float* __restrict__ addp, void* __restrict__ out,
    const int* __restrict__ flagp) {
  constexpr int NO = 8;
  int fl = DUALOUT ? *flagp : 1;
  int tid = threadIdx.x;
  int lane = tid & 63, wv = tid >> 6;
  int m = lane & 15, q = lane >> 4;
  size_t t0 = (size_t)blockIdx.x*64 + (size_t)wv*16;
  f32x4 acc[NO];
  #pragma unroll
  for (int i = 0; i < NO; i++) acc[i] = (f32x4){0.f,0.f,0.f,0.f};
  for (int k0 = 0; k0 < CIN; k0 += 32) {
    const float* src = (CIN == 128 || k0 < 128)
        ? (in1 + (t0 + m)*128 + k0)
        : (in2 + (t0 + m)*128 + (k0 - 128));
    float4 a0 = *(const float4*)(src + q*8);
    float4 a1 = *(const float4*)(src + q*8 + 4);
    union { short s[8]; short8 v; } af;
    af.s[0]=(short)f2b(a0.x); af.s[1]=(short)f2b(a0.y);
    af.s[2]=(short)f2b(a0.z); af.s[3]=(short)f2b(a0.w);
    af.s[4]=(short)f2b(a1.x); af.s[5]=(short)f2b(a1.y);
    af.s[6]=(short)f2b(a1.z); af.s[7]=(short)f2b(a1.w);
    #pragma unroll
    for (int o = 0; o < NO; o++) {
      short8 bf = *(const short8*)(W16 + (size_t)(o*16 + m)*CIN + k0 + q*8);
      acc[o] = __builtin_amdgcn_mfma_f32_16x16x32_bf16(af.v, bf, acc[o], 0, 0, 0);
    }
  }
  int b = (int)(t0 >> 14);
  int p0 = (int)(t0 & (L_-1)) + q*4;
  #pragma unroll
  for (int ot = 0; ot < NO; ot++) {
    int o = ot*16 + m;
    float bi = bias[o], gm = gam[o]*BN_INV, be = bet[o];
    size_t idx = ((size_t)b*128 + o)*L_ + p0;
    float4 r4;
    float* rr = (float*)&r4;
    #pragma unroll
    for (int r = 0; r < 4; r++) {
      float v = acc[ot][r] + bi;
      v = fmaxf(v*gm + be, 0.f);
      rr[r] = v;
    }
    if (ADDX) {
      float4 av = *(const float4*)(addp + idx);
      r4.x += av.x; r4.y += av.y; r4.z += av.z; r4.w += av.w;
    }
    if (DUALOUT && !fl) {
      ushort4 s4;
      s4.x = f2b(r4.x); s4.y = f2b(r4.y); s4.z = f2b(r4.z); s4.w = f2b(r4.w);
      *(ushort4*)((bf16_t*)out + idx) = s4;
    } else {
      *(float4*)((float*)out + idx) = r4;
    }
  }
}

// ---------------------------------------------------------------- LN / LN+FFN
__global__ __launch_bounds__(256) void k_ln(const float* __restrict__ in,
    const float* __restrict__ g, const float* __restrict__ be, float* __restrict__ out) {
  int tid = threadIdx.x, lane = tid & 63;
  size_t t = (size_t)blockIdx.x*4 + (tid >> 6);
  const float* row = in + t*128;
  float2 v = *(const float2*)(row + lane*2);
  float s = v.x + v.y, ss = v.x*v.x + v.y*v.y;
  #pragma unroll
  for (int m = 1; m < 64; m <<= 1) { s += __shfl_xor(s, m); ss += __shfl_xor(ss, m); }
  float mean = s*(1.f/128.f);
  float inv = rsqrtf(ss*(1.f/128.f) - mean*mean + 1e-5f);
  float2 o;
  o.x = (v.x-mean)*inv*g[lane*2]   + be[lane*2];
  o.y = (v.y-mean)*inv*g[lane*2+1] + be[lane*2+1];
  *(float2*)(out + t*128 + lane*2) = o;
}

__global__ __launch_bounds__(256) void k_ln_ffn(const float* __restrict__ in,
    const float* __restrict__ g, const float* __restrict__ be,
    const float* __restrict__ w1, const float* __restrict__ b1,
    const float* __restrict__ w2, const float* __restrict__ b2,
    float* __restrict__ out) {
  int tid = threadIdx.x, lane = tid & 63;
  size_t t = (size_t)blockIdx.x*4 + (tid >> 6);
  const float* row = in + t*128;
  float2 v = *(const float2*)(row + lane*2);
  float s = v.x + v.y, ss = v.x*v.x + v.y*v.y;
  #pragma unroll
  for (int m = 1; m < 64; m <<= 1) { s += __shfl_xor(s, m); ss += __shfl_xor(ss, m); }
  float mean = s*(1.f/128.f);
  float inv = rsqrtf(ss*(1.f/128.f) - mean*mean + 1e-5f);
  float hx = (v.x-mean)*inv*g[lane*2]   + be[lane*2];
  float hy = (v.y-mean)*inv*g[lane*2+1] + be[lane*2+1];
  float hp0 = hx*w1[0*128+lane*2] + hy*w1[0*128+lane*2+1];
  float hp1 = hx*w1[1*128+lane*2] + hy*w1[1*128+lane*2+1];
  float hp2 = hx*w1[2*128+lane*2] + hy*w1[2*128+lane*2+1];
  float hp3 = hx*w1[3*128+lane*2] + hy*w1[3*128+lane*2+1];
  #pragma unroll
  for (int m = 1; m < 64; m <<= 1) {
    hp0 += __shfl_xor(hp0, m); hp1 += __shfl_xor(hp1, m);
    hp2 += __shfl_xor(hp2, m); hp3 += __shfl_xor(hp3, m);
  }
  float hv0, hv1, hv2, hv3;
  { float a = hp0 + b1[0]; hv0 = 0.5f*a*(1.f+erff(a*0.7071067811865476f)); }
  { float a = hp1 + b1[1]; hv1 = 0.5f*a*(1.f+erff(a*0.7071067811865476f)); }
  { float a = hp2 + b1[2]; hv2 = 0.5f*a*(1.f+erff(a*0.7071067811865476f)); }
  { float a = hp3 + b1[3]; hv3 = 0.5f*a*(1.f+erff(a*0.7071067811865476f)); }
  int cx = lane*2, cy = lane*2+1;
  float2 o;
  o.x = hv0*w2[cx*4+0] + hv1*w2[cx*4+1] + hv2*w2[cx*4+2] + hv3*w2[cx*4+3] + b2[cx];
  o.y = hv0*w2[cy*4+0] + hv1*w2[cy*4+1] + hv2*w2[cy*4+2] + hv3*w2[cy*4+3] + b2[cy];
  *(float2*)(out + t*128 + lane*2) = o;
}

// ---------------------------------------------------------------- linear attention
__global__ __launch_bounds__(256) void k_kv(
    const float* __restrict__ qk, const float* __restrict__ v,
    float* __restrict__ akv_g, float* __restrict__ aks_g) {
  __shared__ float kvred[512];
  __shared__ float ksred[64];
  int tid = threadIdx.x;
  for (int i = tid; i < 512; i += 256) kvred[i] = 0.f;
  if (tid < 64) ksred[tid] = 0.f;
  __syncthreads();
  int lane = tid & 63, wv = tid >> 6;
  size_t t0 = (size_t)blockIdx.x * 64;
  int b = (int)(t0 >> 14);
  int pr = lane >> 1;
  float theta = exp2f(-(float)(pr & 15) * THETA_SC);
  bool use_i = pr < 16;
  int hbase = lane & 56;
  float akv[8];
  #pragma unroll
  for (int d = 0; d < 8; d++) akv[d] = 0.f;
  float aks = 0.f;
  for (int it = 0; it < 16; it++) {
    size_t t = t0 + (size_t)wv*16 + it;
    float k = qk[t*128 + 64 + lane];
    float xv = v[t*64 + lane];
    int l = (int)(t & (L_-1));
    float pos = use_i ? (float)(l >> 7) : (float)(l & 127);
    float sn, cs; sincosf(pos*theta, &sn, &cs);
    float kp = __shfl_xor(k, 1);
    float kr = (lane & 1) ? (sn*kp + cs*k) : (cs*k - sn*kp);
    #pragma unroll
    for (int d = 0; d < 8; d++) {
      float krd = __shfl(kr, hbase + d);
      akv[d] += krd * xv;
    }
    aks += k;
  }
  int h8 = lane >> 3, e = lane & 7;
  #pragma unroll
  for (int d = 0; d < 8; d++)
    atomicAdd(&kvred[h8*64 + d*8 + e], akv[d]);
  atomicAdd(&ksred[lane], aks);
  __syncthreads();
  for (int i = tid; i < 512; i += 256) atomicAdd(&akv_g[b*512 + i], kvred[i]);
  if (tid < 64) atomicAdd(&aks_g[b*64 + tid], ksred[tid]);
}

__global__ __launch_bounds__(256) void k_attn2(
    const float* __restrict__ qk, const float* __restrict__ x,
    const float* __restrict__ akv_g, const float* __restrict__ aks_g,
    const float* __restrict__ lw, const float* __restrict__ lb,
    float* __restrict__ out, int coff) {
  __shared__ float kv[512];
  __shared__ float km[64];
  __shared__ float lwl[576];
  int tid = threadIdx.x;
  size_t t0 = (size_t)blockIdx.x * 32;
  int b = (int)(t0 >> 14);
  const float invn = 1.f/16384.f;
  for (int i = tid; i < 512; i += 256) kv[i] = akv_g[b*512 + i]*invn;
  if (tid < 64) km[tid] = aks_g[b*64 + tid]*invn;
  for (int i = tid; i < 576; i += 256) lwl[i] = lw[i];
  __syncthreads();
  int lane = tid & 63, wv = tid >> 6;
  int pr = lane >> 1;
  float theta = exp2f(-(float)(pr & 15) * THETA_SC);
  bool use_i = pr < 16;
  int hbase = lane & 56, e = lane & 7;
  float lbv = lb[lane];
  const float* xb = x + ((size_t)b << 14) * 64;
  for (int it = 0; it < 8; it++) {
    size_t t = t0 + (size_t)wv*8 + it;
    int l = (int)(t & (L_-1));
    int ipos = l >> 7, jpos = l & 127;
    float q = qk[t*128 + lane];
    float p = q * km[lane];
    p += __shfl_xor(p, 1); p += __shfl_xor(p, 2); p += __shfl_xor(p, 4);
    float z = 1.f/(p + 1e-6f);
    float pos = use_i ? (float)ipos : (float)jpos;
    float sn, cs; sincosf(pos*theta, &sn, &cs);
    float qp = __shfl_xor(q, 1);
    float qr = (lane & 1) ? (sn*qp + cs*q) : (cs*q - sn*qp);
    float acc = 0.f;
    #pragma unroll
    for (int d = 0; d < 8; d++) {
      float qrd = __shfl(qr, hbase + d);
      acc += qrd * kv[hbase*8 + d*8 + e];
    }
    acc *= z;
    float lp = lbv;
    #pragma unroll
    for (int dh = -1; dh <= 1; dh++) {
      int h2 = ipos + dh; if ((unsigned)h2 >= 128u) continue;
      #pragma unroll
      for (int dw = -1; dw <= 1; dw++) {
        int w2 = jpos + dw; if ((unsigned)w2 >= 128u) continue;
        lp += lwl[lane*9 + (dh+1)*3 + (dw+1)] * xb[((size_t)(h2 << 7) + w2)*64 + lane];
      }
    }
    out[t*128 + coff + lane] = acc + lp;
  }
}

// ---------------------------------------------------------------- launcher
extern "C" void kernel_launch(void* const* d_in, const int* in_sizes, int n_in,
                              void* d_out, int out_size, void* d_ws, size_t ws_size,
                              hipStream_t stream) {
  (void)in_sizes; (void)n_in; (void)out_size;

  float* base;
  if (ws_size >= WSF * sizeof(float)) {
    base = (float*)d_ws;
  } else {
    void* p = nullptr;
    hipGetSymbolAddress(&p, HIP_SYMBOL(g_ws));
    base = (float*)p;
  }
  float* P0 = base;          // x0 (planar, persists)
  float* PA = base + 1*NS;   // xseq / x_s / ACT
  float* PB = base + 2*NS;   // xt shortcut / xt2 / fmt2 re / x0 seq
  float* PC = base + 3*NS;   // fmt1 re / xt3 / xt4
  float* PD = base + 4*NS;   // QK / fmt im / xo seq
  float* PF = base + 5*NS;   // CAT / xss / FFN
  float* H0 = base + 6*NS;
  float* H1 = H0 + NH;
  float* H2 = H1 + NH;
  float* WG = H2 + NH;                  // B*8*L
  float* ACC = WG + WGSZ;               // 2304
  float* CW  = ACC + ACCSZ;             // fp32 weights
  bf16_t* CW16 = (bf16_t*)(CW + CWSZ);  // bf16 weight mirror
  int*   FLG = (int*)(CW + CWSZ + CW16SZF);

  static const int wsz[47] = {
    16384,128,128,128,1152,128,1024,8,8,8,1024,128,128,128,128,128,
    16384,128,1152,16384,128,3200,16384,128,4096,64,576,64,8192,128,
    576,64,16384,128,1152,128,128,128,512,4,512,128,16384,32768,128,128,128};
  int woff[47]; { int a = 0; for (int i = 0; i < 47; i++){ woff[i] = a; a += wsz[i]; } }
  const float* Wf[47]; for (int i = 0; i < 47; i++) Wf[i] = CW + woff[i];
  auto W16 = [&](int i){ return (const bf16_t*)(CW16 + woff[i] + (woff[i] >= W16SHIFT ? 4 : 0)); };
  const float *c1_b=Wf[1], *c1_g=Wf[2], *c1_be=Wf[3], *cpe1_w=Wf[4],
    *cpe1_b=Wf[5], *fw1=Wf[6], *fb1=Wf[7], *f_g=Wf[8], *f_be=Wf[9], *fw2=Wf[10],
    *fb2=Wf[11], *nbn_g=Wf[12], *nbn_be=Wf[13], *ln1_g=Wf[14], *ln1_b=Wf[15],
    *d3b1=Wf[17], *d3w2=Wf[18], *d5b1=Wf[20],
    *d5w2=Wf[21], *ap_b=Wf[23], *ip2_b=Wf[25],
    *dwc2_w=Wf[26], *dwc2_b=Wf[27], *qk_b=Wf[29], *lepe_w=Wf[30],
    *lepe_b=Wf[31], *op_b=Wf[33], *cpe2_w=Wf[34], *cpe2_b=Wf[35],
    *ln2_g=Wf[36], *ln2_b=Wf[37], *ffn_w1=Wf[38], *ffn_b1=Wf[39], *ffn_w2=Wf[40],
    *ffn_b2=Wf[41], *red_b=Wf[44], *red_g=Wf[45], *red_be=Wf[46];
  const bf16_t *c1_w16=W16(0), *d3w1_16=W16(16), *d5w1_16=W16(19), *ap_w16=W16(22),
    *ip2_w16=W16(24), *qk_w16=W16(28), *op_w16=W16(32), *po_w16=W16(42), *red_w16=W16(43);

  const void* x = d_in[0];

  // 0. dtype probe + weight conversion (fp32 + bf16 mirror)
  k_probe<<<1, 256, 0, stream>>>((const bf16_t*)x, FLG);
  P47 ps; for (int i = 0; i < 47; i++) ps.p[i] = d_in[i+1];
  k_cvt<<<(TOTW+255)/256, 256, 0, stream>>>(ps, FLG, CW);
  k_cvt16<<<(TOTW+255)/256, 256, 0, stream>>>(CW, CW16);

  dim3 tgrid(512, 4, 4), tblk(32, 8);

  // fully fused fmt: seq in, residual adds fused into seq out (out may alias add1)
  auto fmt_fused = [&](const float* seq_in, float* re, float* im,
                       const float* add1, const float* add2, float* outp) {
    k_fft_row_fwd_seq<<<1024, 256, 0, stream>>>(seq_in, re, im);
    k_fft_col_fwd<<<2048, 256, 0, stream>>>(re, im);
    k_freq1<<<256, 256, 0, stream>>>(re, fw1, fb1, f_g, f_be, WG);
    k_fft_col_inv_scaled<<<2048, 256, 0, stream>>>(re, im, WG, fw2, fb2);
    k_fft_row_inv_abs_seq<<<1024, 256, 0, stream>>>(re, im, nbn_g, nbn_be, add1, add2, outp);
  };

  auto attn = [&](const float* brin, float* qkbuf, int coff) {
    k_zero<<<9, 256, 0, stream>>>(ACC, 2304);
    k_mfma_tok<64,128,3,false><<<1024, 256, 0, stream>>>(brin, nullptr, qk_w16, qk_b, qkbuf);
    k_kv<<<1024, 256, 0, stream>>>(qkbuf, brin, ACC, ACC + B_*512);
    k_attn2<<<2048, 256, 0, stream>>>(qkbuf, brin, ACC, ACC + B_*512, lepe_w, lepe_b, PF, coff);
  };

  // x -> seq                                               -> PA
  k_p2s<true><<<tgrid, tblk, 0, stream>>>(x, PA, nullptr, nullptr, FLG);
  // x_0 = relu(bn(conv1x1(x)))                             -> P0 (planar)
  k_mfma_pout<128,false,false><<<1024, 256, 0, stream>>>(
      PA, nullptr, c1_w16, c1_b, c1_g, c1_be, nullptr, P0, FLG);
  // xt = x + dw3(x,cpe1)+b                                 -> PB (shortcut)
  k_dw3<128,0><<<8192, 256, 0, stream>>>(PA, cpe1_w, cpe1_b, PB);
  // x_s = ln(xt)                                           -> PA
  k_ln<<<16384, 256, 0, stream>>>(PB, ln1_g, ln1_b, PA);
  // multi-scale convs
  k_mfma_tok<128,128,1,false><<<1024, 256, 0, stream>>>(PA, nullptr, d3w1_16, d3b1, PD);
  k_gconv<3><<<4096, 256, 0, stream>>>(PD, d3w2, H0);
  k_mfma_tok<128,128,1,false><<<1024, 256, 0, stream>>>(PA, nullptr, d5w1_16, d5b1, PD);
  k_gconv<5><<<4096, 256, 0, stream>>>(PD, d5w2, H1);
  k_mfma_tok<128,128,2,false><<<1024, 256, 0, stream>>>(PA, nullptr, ap_w16, ap_b, PA); // ACT
  // branch3 -> attention -> CAT[:, :, 0:64] in PF
  k_mfma_tok<64,64,1,false><<<1024, 256, 0, stream>>>(H0, nullptr, ip2_w16, ip2_b, H2);
  k_dw3<64,1><<<4096, 256, 0, stream>>>(H2, dwc2_w, dwc2_b, H0);
  attn(H0, PD, 0);
  // branch5 -> attention -> CAT[:, :, 64:128]
  k_mfma_tok<64,64,1,false><<<1024, 256, 0, stream>>>(H1, nullptr, ip2_w16, ip2_b, H2);
  k_dw3<64,1><<<4096, 256, 0, stream>>>(H2, dwc2_w, dwc2_b, H1);
  attn(H1, PD, 64);
  // xss = conv1x1(CAT * ACT, op_w)+op_b                    -> PF (in-place)
  k_mfma_tok<128,128,1,true><<<1024, 256, 0, stream>>>(PF, PA, op_w16, op_b, PF);
  // fmt1 (delayed) + xt2 = shortcut + xss + fmt1           -> PB
  fmt_fused(PB, PC, PD, PB, PF, PB);
  // xt3 = xt2 + dw3(xt2,cpe2)+b                            -> PC
  k_dw3<128,0><<<8192, 256, 0, stream>>>(PB, cpe2_w, cpe2_b, PC);
  // ffn(ln2(xt3))                                          -> PF
  k_ln_ffn<<<16384, 256, 0, stream>>>(PC, ln2_g, ln2_b, ffn_w1, ffn_b1, ffn_w2, ffn_b2, PF);
  // fmt2 + xt4 = xt3 + ffn + fmt2                          -> PC
  fmt_fused(PC, PB, PD, PC, PF, PC);
  // xo = conv1x1(xt4, po_w)                                -> PD (seq)
  k_mfma_tok<128,128,0,false><<<1024, 256, 0, stream>>>(PC, nullptr, po_w16, nullptr, PD);
  // x0 planar -> seq                                       -> PB
  k_p2s<false><<<tgrid, tblk, 0, stream>>>(P0, PB, nullptr, nullptr, nullptr);
  // out = relu(bn(conv1x1([x0;xo], red))) + x0             -> d_out (planar, dtype per flag)
  k_mfma_pout<256,true,true><<<1024, 256, 0, stream>>>(
      PB, PD, red_w16, red_b, red_g, red_be, P0, d_out, FLG);
}

// Round 9
// 1015.937 us; speedup vs baseline: 1.6314x; 1.0201x over previous
//
#include <hip/hip_runtime.h>
#include <math.h>

typedef unsigned short bf16_t;
typedef __attribute__((ext_vector_type(8))) short short8;
typedef __attribute__((ext_vector_type(4))) float f32x4;

#define B_ 4
#define C_ 128
#define H_ 128
#define W_ 128
#define L_ (H_*W_)               // 16384
#define NS  ((size_t)B_*L_*C_)   // 8388608 elems
#define NH  ((size_t)B_*L_*64)
#define NSP ((size_t)L_*C_)
#define PI_F 3.14159265358979323846f
#define BN_INV 0.9999950000374997f   // (1+1e-5)^-0.5
#define THETA_SC 0.8304820237218406f // log2(10000)/16
#define TOTW 157148
#define W16SHIFT 107548              // offsets >= this get +4 in bf16 mirror (8-align po_w/red_w)

__device__ __forceinline__ float ldf(bf16_t v){ return __uint_as_float(((unsigned)v)<<16); }
__device__ __forceinline__ bf16_t f2b(float f){
  unsigned u = __float_as_uint(f);
  u += 0x7fffu + ((u>>16)&1u);     // RNE
  return (bf16_t)(u>>16);
}

// workspace layout
#define WGSZ ((size_t)B_*8*L_)       // 524288
#define ACCSZ 2304
#define CWSZ 157184                  // fp32 weights
#define CW16SZF 78592                // bf16 mirror in floats
#define WSF (6*NS + 3*NH + WGSZ + ACCSZ + CWSZ + CW16SZF + 16)
__device__ float g_ws[WSF];

// ---------------------------------------------------------------- dtype probe + weight convert
__global__ void k_probe(const bf16_t* __restrict__ xb, int* __restrict__ flag){
  __shared__ int vote;
  if (threadIdx.x == 0) vote = 0;
  __syncthreads();
  int bad = 0;
  for (int i = threadIdx.x; i < 2048; i += 256) {
    float v = ldf(xb[2*i]);
    if (!(fabsf(v) < 1e6f)) bad = 1;
  }
  if (bad) atomicOr(&vote, 1);
  __syncthreads();
  if (threadIdx.x == 0) *flag = vote;  // 1 = fp32 storage, 0 = bf16 storage
}

struct P47 { const void* p[47]; };
__device__ __constant__ int c_wsz[47] = {
  16384,128,128,128,1152,128,1024,8,8,8,1024,128,128,128,128,128,
  16384,128,1152,16384,128,3200,16384,128,4096,64,576,64,8192,128,
  576,64,16384,128,1152,128,128,128,512,4,512,128,16384,32768,128,128,128};

__global__ __launch_bounds__(256) void k_cvt(P47 ps, const int* __restrict__ flagp,
                                             float* __restrict__ dst){
  int g = blockIdx.x*256 + threadIdx.x;
  if (g >= TOTW) return;
  int fl = *flagp;
  int idx = 0, off = g;
  while (off >= c_wsz[idx]) { off -= c_wsz[idx]; idx++; }
  const void* s = ps.p[idx];
  dst[g] = fl ? ((const float*)s)[off] : ldf(((const bf16_t*)s)[off]);
}

__global__ __launch_bounds__(256) void k_cvt16(const float* __restrict__ src, bf16_t* __restrict__ dst){
  int g = blockIdx.x*256 + threadIdx.x;
  if (g >= TOTW) return;
  dst[g + (g >= W16SHIFT ? 4 : 0)] = f2b(src[g]);
}

__global__ void k_zero(float* p, int n){
  int i = blockIdx.x*256 + threadIdx.x;
  if (i < n) p[i] = 0.f;
}

// ---------------------------------------------------------------- FFT core (hoisted twiddles)
// Twiddles depend only on (lane, stage): compute the 7 (c,s) pairs ONCE per
// thread, reuse across all columns handled by the thread.
__device__ __forceinline__ void tw_fwd(int lane, float* tc, float* ts) {
  sincosf(-PI_F * (float)lane * (1.f/64.f), &ts[0], &tc[0]);
  int i = 1;
  #pragma unroll
  for (int m = 32; m >= 1; m >>= 1, i++) {
    int k = lane & (m-1);
    sincosf(-PI_F * (float)k / (float)m, &ts[i], &tc[i]);
  }
}
__device__ __forceinline__ void tw_inv(int lane, float* tc, float* ts) {
  int i = 0;
  #pragma unroll
  for (int m = 1; m <= 32; m <<= 1, i++) {
    int k = lane & (m-1);
    sincosf(PI_F * (float)k / (float)m, &ts[i], &tc[i]);
  }
  sincosf(PI_F * (float)lane * (1.f/64.f), &ts[6], &tc[6]);
}

__device__ __forceinline__ void fft128_fwd(float& lor, float& loi, float& hir, float& hii,
                                           int lane, const float* tc, const float* ts) {
  {
    float s = ts[0], c = tc[0];
    float ar = lor, ai = loi;
    float dr = ar - hir, di = ai - hii;
    lor = ar + hir; loi = ai + hii;
    hir = dr*c - di*s; hii = dr*s + di*c;
  }
  int i = 1;
  #pragma unroll
  for (int m = 32; m >= 1; m >>= 1, i++) {
    float s = ts[i], c = tc[i];
    bool up = (lane & m) != 0;
    {
      float orr = __shfl_xor(lor, m), oii = __shfl_xor(loi, m);
      float sr = lor + orr, si = loi + oii;
      float dr = orr - lor, di = oii - loi;
      float tr = dr*c - di*s, ti = dr*s + di*c;
      lor = up ? tr : sr; loi = up ? ti : si;
    }
    {
      float orr = __shfl_xor(hir, m), oii = __shfl_xor(hii, m);
      float sr = hir + orr, si = hii + oii;
      float dr = orr - hir, di = oii - hii;
      float tr = dr*c - di*s, ti = dr*s + di*c;
      hir = up ? tr : sr; hii = up ? ti : si;
    }
  }
}

__device__ __forceinline__ void fft128_inv(float& lor, float& loi, float& hir, float& hii,
                                           int lane, const float* tc, const float* ts) {
  int i = 0;
  #pragma unroll
  for (int m = 1; m <= 32; m <<= 1, i++) {
    float s = ts[i], c = tc[i];
    bool up = (lane & m) != 0;
    {
      float orr = __shfl_xor(lor, m), oii = __shfl_xor(loi, m);
      float qr = orr*c - oii*s, qi = orr*s + oii*c;
      float lo_r = lor + qr, lo_i = loi + qi;
      float mr = lor*c - loi*s, mi = lor*s + loi*c;
      float up_r = orr - mr, up_i = oii - mi;
      lor = up ? up_r : lo_r; loi = up ? up_i : lo_i;
    }
    {
      float orr = __shfl_xor(hir, m), oii = __shfl_xor(hii, m);
      float qr = orr*c - oii*s, qi = orr*s + oii*c;
      float lo_r = hir + qr, lo_i = hii + qi;
      float mr = hir*c - hii*s, mi = hir*s + hii*c;
      float up_r = orr - mr, up_i = oii - mi;
      hir = up ? up_r : lo_r; hii = up ? up_i : lo_i;
    }
  }
  {
    float s = ts[6], c = tc[6];
    float qr = hir*c - hii*s, qi = hir*s + hii*c;
    float pr = lor, pi = loi;
    lor = pr + qr; loi = pi + qi;
    hir = pr - qr; hii = pi - qi;
  }
}

// fused seq-read + transpose + forward row FFT. Block = (b, h, c-half): 64ch x 128w.
__global__ __launch_bounds__(256) void k_fft_row_fwd_seq(
    const float* __restrict__ in, float* __restrict__ re, float* __restrict__ im) {
  __shared__ float T[64*130];
  int tid = threadIdx.x;
  int bid = blockIdx.x;
  int ch = (bid & 1) * 64;
  int h  = (bid >> 1) & 127;
  int b  = bid >> 8;
  const float* ip = in + ((size_t)b*L_ + (size_t)h*128)*128 + ch;
  #pragma unroll
  for (int it = 0; it < 8; it++) {
    int idx = it*256 + tid;            // 2048 float4 loads
    int c4 = (idx & 15)*4, w = idx >> 4;
    float4 v = *(const float4*)(ip + (size_t)w*128 + c4);
    T[(c4+0)*130 + w] = v.x;
    T[(c4+1)*130 + w] = v.y;
    T[(c4+2)*130 + w] = v.z;
    T[(c4+3)*130 + w] = v.w;
  }
  __syncthreads();
  int lane = tid & 63, wv = tid >> 6;
  float tc[7], ts[7];
  tw_fwd(lane, tc, ts);
  size_t obase = (size_t)(b*128 + ch)*L_ + (size_t)h*128;
  for (int i = 0; i < 16; i++) {
    int cc = wv*16 + i;
    float lor = T[cc*130 + lane], loi = 0.f;
    float hir = T[cc*130 + 64 + lane], hii = 0.f;
    fft128_fwd(lor, loi, hir, hii, lane, tc, ts);
    size_t o = obase + (size_t)cc*L_;
    re[o + lane] = lor;      im[o + lane] = loi;
    re[o + lane + 64] = hir; im[o + lane + 64] = hii;
  }
}

__global__ __launch_bounds__(256) void k_fft_col_fwd(float* __restrict__ re, float* __restrict__ im) {
  __shared__ float Lre[128][33];
  __shared__ float Lim[128][33];
  int tid = threadIdx.x;
  size_t img = blockIdx.x >> 2;
  int w0 = (blockIdx.x & 3) * 32;
  float* rp = re + img * (size_t)L_ + w0;
  float* ip = im + img * (size_t)L_ + w0;
  for (int i = tid; i < 4096; i += 256) {
    int h = i >> 5, wl = i & 31;
    Lre[h][wl] = rp[(size_t)h*W_ + wl];
    Lim[h][wl] = ip[(size_t)h*W_ + wl];
  }
  __syncthreads();
  int lane = tid & 63, wv = tid >> 6;
  float tc[7], ts[7];
  tw_fwd(lane, tc, ts);
  for (int i = 0; i < 8; i++) {
    int col = wv*8 + i;
    float lor = Lre[lane][col], loi = Lim[lane][col];
    float hir = Lre[lane+64][col], hii = Lim[lane+64][col];
    fft128_fwd(lor, loi, hir, hii, lane, tc, ts);
    Lre[lane][col]=lor; Lim[lane][col]=loi;
    Lre[lane+64][col]=hir; Lim[lane+64][col]=hii;
  }
  __syncthreads();
  for (int i = tid; i < 4096; i += 256) {
    int h = i >> 5, wl = i & 31;
    rp[(size_t)h*W_ + wl] = Lre[h][wl];
    ip[(size_t)h*W_ + wl] = Lim[h][wl];
  }
}

// inverse col FFT with freq2's sigmoid gating fused into the load phase.
__global__ __launch_bounds__(256) void k_fft_col_inv_scaled(
    float* __restrict__ re, float* __restrict__ im,
    const float* __restrict__ wg1, const float* __restrict__ fw2,
    const float* __restrict__ fb2) {
  __shared__ float Lre[128][33];
  __shared__ float Lim[128][33];
  __shared__ float w2r[8];
  int tid = threadIdx.x;
  size_t img = blockIdx.x >> 2;
  int c = (int)(img & 127);
  int b = (int)(img >> 7);
  int w0 = (blockIdx.x & 3) * 32;
  if (tid < 8) w2r[tid] = fw2[c*8 + tid];
  float b2 = fb2[c];
  float* rp = re + img * (size_t)L_ + w0;
  float* ip = im + img * (size_t)L_ + w0;
  const float* wgp = wg1 + (size_t)b*8*L_ + w0;
  __syncthreads();
  for (int i = tid; i < 4096; i += 256) {
    int h = i >> 5, wl = i & 31;
    size_t p = (size_t)h*W_ + wl;
    float a = b2;
    #pragma unroll
    for (int o = 0; o < 8; o++) a += w2r[o] * wgp[(size_t)o*L_ + p];
    float wgt = 1.f/(1.f+expf(-a));
    Lre[h][wl] = rp[p] * wgt;
    Lim[h][wl] = ip[p] * wgt;
  }
  __syncthreads();
  int lane = tid & 63, wv = tid >> 6;
  float tc[7], ts[7];
  tw_inv(lane, tc, ts);
  for (int i = 0; i < 8; i++) {
    int col = wv*8 + i;
    float lor = Lre[lane][col], loi = Lim[lane][col];
    float hir = Lre[lane+64][col], hii = Lim[lane+64][col];
    fft128_inv(lor, loi, hir, hii, lane, tc, ts);
    Lre[lane][col]=lor*(1.f/128.f); Lim[lane][col]=loi*(1.f/128.f);
    Lre[lane+64][col]=hir*(1.f/128.f); Lim[lane+64][col]=hii*(1.f/128.f);
  }
  __syncthreads();
  for (int i = tid; i < 4096; i += 256) {
    int h = i >> 5, wl = i & 31;
    rp[(size_t)h*W_ + wl] = Lre[h][wl];
    ip[(size_t)h*W_ + wl] = Lim[h][wl];
  }
}

// inverse row FFT + abs + bn + relu + transpose to seq with two fused residual adds.
// out may alias add1 (same-thread read-then-write).
__global__ __launch_bounds__(256) void k_fft_row_inv_abs_seq(
    const float* __restrict__ re, const float* __restrict__ im,
    const float* __restrict__ ng, const float* __restrict__ nbe,
    const float* __restrict__ add1, const float* __restrict__ add2,
    float* __restrict__ out) {
  __shared__ float T[64*130];
  int tid = threadIdx.x;
  int bid = blockIdx.x;
  int ch = (bid & 1) * 64;
  int h  = (bid >> 1) & 127;
  int b  = bid >> 8;
  int lane = tid & 63, wv = tid >> 6;
  float tc[7], ts[7];
  tw_inv(lane, tc, ts);
  size_t ibase = (size_t)(b*128 + ch)*L_ + (size_t)h*128;
  for (int i = 0; i < 16; i++) {
    int cc = wv*16 + i;
    size_t o = ibase + (size_t)cc*L_;
    float lor = re[o + lane], loi = im[o + lane];
    float hir = re[o + lane + 64], hii = im[o + lane + 64];
    fft128_inv(lor, loi, hir, hii, lane, tc, ts);
    float sg = ng[ch+cc]*BN_INV, sb = nbe[ch+cc];
    T[cc*130 + lane]      = fmaxf(sqrtf(lor*lor+loi*loi)*(1.f/128.f)*sg + sb, 0.f);
    T[cc*130 + 64 + lane] = fmaxf(sqrtf(hir*hir+hii*hii)*(1.f/128.f)*sg + sb, 0.f);
  }
  __syncthreads();
  size_t sb0 = ((size_t)b*L_ + (size_t)h*128)*128 + ch;
  #pragma unroll
  for (int it = 0; it < 8; it++) {
    int idx = it*256 + tid;
    int c4 = (idx & 15)*4, w = idx >> 4;
    size_t off = sb0 + (size_t)w*128 + c4;
    float4 v;
    v.x = T[(c4+0)*130 + w];
    v.y = T[(c4+1)*130 + w];
    v.z = T[(c4+2)*130 + w];
    v.w = T[(c4+3)*130 + w];
    float4 x1 = *(const float4*)(add1 + off);
    float4 x2 = *(const float4*)(add2 + off);
    v.x += x1.x + x2.x; v.y += x1.y + x2.y;
    v.z += x1.z + x2.z; v.w += x1.w + x2.w;
    *(float4*)(out + off) = v;
  }
}

// ---------------------------------------------------------------- freq hidden (8ch) conv
__global__ __launch_bounds__(256) void k_freq1(const float* __restrict__ tre,
    const float* __restrict__ fw1, const float* __restrict__ fb1,
    const float* __restrict__ fg, const float* __restrict__ fbe,
    float* __restrict__ wg1) {
  __shared__ float w1s[1024];
  int tid = threadIdx.x;
  for (int i = tid; i < 1024; i += 256) w1s[i] = fw1[i];
  __syncthreads();
  size_t g = (size_t)blockIdx.x*256 + tid;   // (b,p)
  int p = (int)(g & (L_-1));
  int b = (int)(g >> 14);
  const float* tp = tre + (size_t)b*128*L_ + p;
  float acc[8];
  #pragma unroll
  for (int o = 0; o < 8; o++) acc[o] = 0.f;
  for (int c = 0; c < 128; c++) {
    float v = tp[(size_t)c*L_];
    #pragma unroll
    for (int o = 0; o < 8; o++) acc[o] += w1s[o*128+c]*v;
  }
  size_t ob = (size_t)b*8*L_ + p;
  #pragma unroll
  for (int o = 0; o < 8; o++) {
    float v = (acc[o] + fb1[o]) * (fg[o]*BN_INV) + fbe[o];
    wg1[ob + (size_t)o*L_] = fmaxf(v, 0.f);
  }
}

// ---------------------------------------------------------------- planar->seq transpose
template<bool DUAL>
__global__ void k_p2s(const void* __restrict__ src, float* __restrict__ dst,
                      const float* __restrict__ add1, const float* __restrict__ add2,
                      const int* __restrict__ flagp) {
  __shared__ float tile[32][33];
  int fl = DUAL ? *flagp : 1;
  int b = blockIdx.z;
  int p0 = blockIdx.x*32, c0 = blockIdx.y*32;
  int tx = threadIdx.x, ty = threadIdx.y;
  size_t base_in = (size_t)b*NSP;
  #pragma unroll
  for (int k = 0; k < 4; k++) {
    size_t off = base_in + (size_t)(c0+ty+8*k)*L_ + p0 + tx;
    float v;
    if (DUAL && !fl) v = ldf(((const bf16_t*)src)[off]);
    else             v = ((const float*)src)[off];
    tile[ty+8*k][tx] = v;
  }
  __syncthreads();
  size_t base = (size_t)b*NSP;
  #pragma unroll
  for (int k = 0; k < 4; k++) {
    size_t idx = base + (size_t)(p0+ty+8*k)*C_ + c0 + tx;
    float v = tile[tx][ty+8*k];
    if (add1) v += add1[idx];
    if (add2) v += add2[idx];
    dst[idx] = v;
  }
}

// ---------------------------------------------------------------- depthwise 3x3 (NHWC), 4 pixels/thread
template<int CC, int MODE>  // MODE 0: out = in + dw + b ; MODE 1: out = silu(dw + b)
__global__ __launch_bounds__(256) void k_dw3(const float* __restrict__ in,
    const float* __restrict__ w, const float* __restrict__ bias,
    float* __restrict__ out) {
  __shared__ float wl[9*CC];
  int tid = threadIdx.x;
  for (int i = tid; i < 9*CC; i += 256) {
    int tap = i / CC, ch = i % CC;
    wl[i] = w[ch*9 + tap];
  }
  __syncthreads();
  size_t g = (size_t)blockIdx.x*256 + tid;
  int c = (int)(g & (CC-1));
  float wr[9];
  #pragma unroll
  for (int t = 0; t < 9; t++) wr[t] = wl[t*CC + c];
  size_t s = g / CC;
  int w0 = (int)(s & 31) * 4;
  int hp = (int)((s >> 5) & 127);
  int b  = (int)(s >> 12);
  const float* ip = in + (size_t)b*L_*CC + c;
  float bi = bias[c];
  float a0 = bi, a1 = bi, a2 = bi, a3 = bi;
  #pragma unroll
  for (int dh = -1; dh <= 1; dh++) {
    int h2 = hp + dh;
    if ((unsigned)h2 >= 128u) continue;
    const float* rp = ip + (size_t)h2*W_*CC;
    float px[6];
    #pragma unroll
    for (int x = 0; x < 6; x++) {
      int w2 = w0 - 1 + x;
      px[x] = ((unsigned)w2 < 128u) ? rp[(size_t)w2*CC] : 0.f;
    }
    #pragma unroll
    for (int dw = 0; dw < 3; dw++) {
      float f = wr[(dh+1)*3 + dw];
      a0 += f*px[dw];   a1 += f*px[dw+1];
      a2 += f*px[dw+2]; a3 += f*px[dw+3];
    }
  }
  size_t tb = (size_t)b*L_ + (size_t)hp*W_ + w0;
  if (MODE == 0) {
    out[(tb+0)*CC + c] = in[(tb+0)*CC + c] + a0;
    out[(tb+1)*CC + c] = in[(tb+1)*CC + c] + a1;
    out[(tb+2)*CC + c] = in[(tb+2)*CC + c] + a2;
    out[(tb+3)*CC + c] = in[(tb+3)*CC + c] + a3;
  } else {
    out[(tb+0)*CC + c] = a0 / (1.f + expf(-a0));
    out[(tb+1)*CC + c] = a1 / (1.f + expf(-a1));
    out[(tb+2)*CC + c] = a2 / (1.f + expf(-a2));
    out[(tb+3)*CC + c] = a3 / (1.f + expf(-a3));
  }
}

// ---------------------------------------------------------------- grouped conv KxK, 4 pixels/thread
template<int K>
__global__ __launch_bounds__(256) void k_gconv(const float* __restrict__ in,
    const float* __restrict__ w, float* __restrict__ out) {
  __shared__ float wl[K*K*128];
  int tid = threadIdx.x;
  for (int i = tid; i < 128*K*K; i += 256) {
    int tap = i >> 7, ch = i & 127;
    wl[i] = w[ch*(K*K) + tap];
  }
  __syncthreads();
  size_t g = (size_t)blockIdx.x*256 + tid;
  int oc = (int)(g & 63);
  float wx[K*K], wy[K*K];
  #pragma unroll
  for (int t = 0; t < K*K; t++) {
    wx[t] = wl[t*128 + 2*oc];
    wy[t] = wl[t*128 + 2*oc + 1];
  }
  size_t s = g >> 6;
  int w0 = (int)(s & 31) * 4;
  int hp = (int)((s >> 5) & 127);
  int b  = (int)(s >> 12);
  const float* ip = in + (size_t)b*L_*128 + 2*oc;
  constexpr int P = K/2;
  float a0 = 0.f, a1 = 0.f, a2 = 0.f, a3 = 0.f;
  #pragma unroll
  for (int kh = 0; kh < K; kh++) {
    int h2 = hp + kh - P;
    if ((unsigned)h2 >= 128u) continue;
    const float* rp = ip + (size_t)h2*W_*128;
    float2 px[K+3];
    #pragma unroll
    for (int x = 0; x < K+3; x++) {
      int w2 = w0 - P + x;
      px[x] = ((unsigned)w2 < 128u) ? *(const float2*)(rp + (size_t)w2*128)
                                    : make_float2(0.f, 0.f);
    }
    #pragma unroll
    for (int kw = 0; kw < K; kw++) {
      float fx = wx[kh*K + kw], fy = wy[kh*K + kw];
      a0 += fx*px[kw+0].x + fy*px[kw+0].y;
      a1 += fx*px[kw+1].x + fy*px[kw+1].y;
      a2 += fx*px[kw+2].x + fy*px[kw+2].y;
      a3 += fx*px[kw+3].x + fy*px[kw+3].y;
    }
  }
  size_t tb = (size_t)b*L_ + (size_t)hp*W_ + w0;
  out[(tb+0)*64 + oc] = a0;
  out[(tb+1)*64 + oc] = a1;
  out[(tb+2)*64 + oc] = a2;
  out[(tb+3)*64 + oc] = a3;
}

// ---------------------------------------------------------------- MFMA token GEMM (seq, bf16 W from global)
template<int CIN, int COUT, int EPI, bool MUL>   // EPI 0:none 1:bias 2:bias+silu 3:bias+elu+1
__global__ __launch_bounds__(256) void k_mfma_tok(
    const float* __restrict__ in, const float* __restrict__ mulp,
    const bf16_t* __restrict__ W16, const float* __restrict__ bias,
    float* __restrict__ out) {
  constexpr int NO = COUT/16;
  int tid = threadIdx.x;
  int lane = tid & 63, wv = tid >> 6;
  int m = lane & 15, q = lane >> 4;
  size_t t0 = (size_t)blockIdx.x*64 + (size_t)wv*16;
  f32x4 acc[NO];
  #pragma unroll
  for (int i = 0; i < NO; i++) acc[i] = (f32x4){0.f,0.f,0.f,0.f};
  for (int k0 = 0; k0 < CIN; k0 += 32) {
    const float* ap = in + (t0 + m)*CIN + k0 + q*8;
    float4 a0 = *(const float4*)ap;
    float4 a1 = *(const float4*)(ap + 4);
    if (MUL) {
      const float* mp = mulp + (t0 + m)*CIN + k0 + q*8;
      float4 m0 = *(const float4*)mp;
      float4 m1 = *(const float4*)(mp + 4);
      a0.x*=m0.x; a0.y*=m0.y; a0.z*=m0.z; a0.w*=m0.w;
      a1.x*=m1.x; a1.y*=m1.y; a1.z*=m1.z; a1.w*=m1.w;
    }
    union { short s[8]; short8 v; } af;
    af.s[0]=(short)f2b(a0.x); af.s[1]=(short)f2b(a0.y);
    af.s[2]=(short)f2b(a0.z); af.s[3]=(short)f2b(a0.w);
    af.s[4]=(short)f2b(a1.x); af.s[5]=(short)f2b(a1.y);
    af.s[6]=(short)f2b(a1.z); af.s[7]=(short)f2b(a1.w);
    #pragma unroll
    for (int o = 0; o < NO; o++) {
      short8 bf = *(const short8*)(W16 + (size_t)(o*16 + m)*CIN + k0 + q*8);
      acc[o] = __builtin_amdgcn_mfma_f32_16x16x32_bf16(af.v, bf, acc[o], 0, 0, 0);
    }
  }
  #pragma unroll
  for (int o = 0; o < NO; o++) {
    float bv = (EPI >= 1) ? bias[o*16 + m] : 0.f;
    #pragma unroll
    for (int r = 0; r < 4; r++) {
      int row = q*4 + r;
      float v = acc[o][r] + bv;
      if (EPI == 2) v = v / (1.f + expf(-v));
      if (EPI == 3) v = v > 0.f ? v + 1.f : expf(v);
      out[(t0 + row)*COUT + o*16 + m] = v;
    }
  }
}

// ---------------------------------------------------------------- MFMA GEMM, seq input(s) -> planar output
template<int CIN, bool DUALOUT, bool ADDX>
__global__ __launch_bounds__(256) void k_mfma_pout(
    const float* __restrict__ in1, const float* __restrict__ in2,
    const bf16_t* __restrict__ W16, const float* __restrict__ bias,
    const float* __restrict__ gam, const float* __restrict__ bet,
    const float* __restrict__ addp, void* __restrict__ out,
    const int* __restrict__ flagp) {
  constexpr int NO = 8;
  int fl = DUALOUT ? *flagp : 1;
  int tid = threadIdx.x;
  int lane = tid & 63, wv = tid >> 6;
  int m = lane & 15, q = lane >> 4;
  size_t t0 = (size_t)blockIdx.x*64 + (size_t)wv*16;
  f32x4 acc[NO];
  #pragma unroll
  for (int i = 0; i < NO; i++) acc[i] = (f32x4){0.f,0.f,0.f,0.f};
  for (int k0 = 0; k0 < CIN; k0 += 32) {
    const float* src = (CIN == 128 || k0 < 128)
        ? (in1 + (t0 + m)*128 + k0)
        : (in2 + (t0 + m)*128 + (k0 - 128));
    float4 a0 = *(const float4*)(src + q*8);
    float4 a1 = *(const float4*)(src + q*8 + 4);
    union { short s[8]; short8 v; } af;
    af.s[0]=(short)f2b(a0.x); af.s[1]=(short)f2b(a0.y);
    af.s[2]=(short)f2b(a0.z); af.s[3]=(short)f2b(a0.w);
    af.s[4]=(short)f2b(a1.x); af.s[5]=(short)f2b(a1.y);
    af.s[6]=(short)f2b(a1.z); af.s[7]=(short)f2b(a1.w);
    #pragma unroll
    for (int o = 0; o < NO; o++) {
      short8 bf = *(const short8*)(W16 + (size_t)(o*16 + m)*CIN + k0 + q*8);
      acc[o] = __builtin_amdgcn_mfma_f32_16x16x32_bf16(af.v, bf, acc[o], 0, 0, 0);
    }
  }
  int b = (int)(t0 >> 14);
  int p0 = (int)(t0 & (L_-1)) + q*4;
  #pragma unroll
  for (int ot = 0; ot < NO; ot++) {
    int o = ot*16 + m;
    float bi = bias[o], gm = gam[o]*BN_INV, be = bet[o];
    size_t idx = ((size_t)b*128 + o)*L_ + p0;
    float4 r4;
    float* rr = (float*)&r4;
    #pragma unroll
    for (int r = 0; r < 4; r++) {
      float v = acc[ot][r] + bi;
      v = fmaxf(v*gm + be, 0.f);
      rr[r] = v;
    }
    if (ADDX) {
      float4 av = *(const float4*)(addp + idx);
      r4.x += av.x; r4.y += av.y; r4.z += av.z; r4.w += av.w;
    }
    if (DUALOUT && !fl) {
      ushort4 s4;
      s4.x = f2b(r4.x); s4.y = f2b(r4.y); s4.z = f2b(r4.z); s4.w = f2b(r4.w);
      *(ushort4*)((bf16_t*)out + idx) = s4;
    } else {
      *(float4*)((float*)out + idx) = r4;
    }
  }
}

// ---------------------------------------------------------------- LN / LN+FFN
__global__ __launch_bounds__(256) void k_ln(const float* __restrict__ in,
    const float* __restrict__ g, const float* __restrict__ be, float* __restrict__ out) {
  int tid = threadIdx.x, lane = tid & 63;
  size_t t = (size_t)blockIdx.x*4 + (tid >> 6);
  const float* row = in + t*128;
  float2 v = *(const float2*)(row + lane*2);
  float s = v.x + v.y, ss = v.x*v.x + v.y*v.y;
  #pragma unroll
  for (int m = 1; m < 64; m <<= 1) { s += __shfl_xor(s, m); ss += __shfl_xor(ss, m); }
  float mean = s*(1.f/128.f);
  float inv = rsqrtf(ss*(1.f/128.f) - mean*mean + 1e-5f);
  float2 o;
  o.x = (v.x-mean)*inv*g[lane*2]   + be[lane*2];
  o.y = (v.y-mean)*inv*g[lane*2+1] + be[lane*2+1];
  *(float2*)(out + t*128 + lane*2) = o;
}

__global__ __launch_bounds__(256) void k_ln_ffn(const float* __restrict__ in,
    const float* __restrict__ g, const float* __restrict__ be,
    const float* __restrict__ w1, const float* __restrict__ b1,
    const float* __restrict__ w2, const float* __restrict__ b2,
    float* __restrict__ out) {
  int tid = threadIdx.x, lane = tid & 63;
  size_t t = (size_t)blockIdx.x*4 + (tid >> 6);
  const float* row = in + t*128;
  float2 v = *(const float2*)(row + lane*2);
  float s = v.x + v.y, ss = v.x*v.x + v.y*v.y;
  #pragma unroll
  for (int m = 1; m < 64; m <<= 1) { s += __shfl_xor(s, m); ss += __shfl_xor(ss, m); }
  float mean = s*(1.f/128.f);
  float inv = rsqrtf(ss*(1.f/128.f) - mean*mean + 1e-5f);
  float hx = (v.x-mean)*inv*g[lane*2]   + be[lane*2];
  float hy = (v.y-mean)*inv*g[lane*2+1] + be[lane*2+1];
  float hp0 = hx*w1[0*128+lane*2] + hy*w1[0*128+lane*2+1];
  float hp1 = hx*w1[1*128+lane*2] + hy*w1[1*128+lane*2+1];
  float hp2 = hx*w1[2*128+lane*2] + hy*w1[2*128+lane*2+1];
  float hp3 = hx*w1[3*128+lane*2] + hy*w1[3*128+lane*2+1];
  #pragma unroll
  for (int m = 1; m < 64; m <<= 1) {
    hp0 += __shfl_xor(hp0, m); hp1 += __shfl_xor(hp1, m);
    hp2 += __shfl_xor(hp2, m); hp3 += __shfl_xor(hp3, m);
  }
  float hv0, hv1, hv2, hv3;
  { float a = hp0 + b1[0]; hv0 = 0.5f*a*(1.f+erff(a*0.7071067811865476f)); }
  { float a = hp1 + b1[1]; hv1 = 0.5f*a*(1.f+erff(a*0.7071067811865476f)); }
  { float a = hp2 + b1[2]; hv2 = 0.5f*a*(1.f+erff(a*0.7071067811865476f)); }
  { float a = hp3 + b1[3]; hv3 = 0.5f*a*(1.f+erff(a*0.7071067811865476f)); }
  int cx = lane*2, cy = lane*2+1;
  float2 o;
  o.x = hv0*w2[cx*4+0] + hv1*w2[cx*4+1] + hv2*w2[cx*4+2] + hv3*w2[cx*4+3] + b2[cx];
  o.y = hv0*w2[cy*4+0] + hv1*w2[cy*4+1] + hv2*w2[cy*4+2] + hv3*w2[cy*4+3] + b2[cy];
  *(float2*)(out + t*128 + lane*2) = o;
}

// ---------------------------------------------------------------- linear attention
__global__ __launch_bounds__(256) void k_kv(
    const float* __restrict__ qk, const float* __restrict__ v,
    float* __restrict__ akv_g, float* __restrict__ aks_g) {
  __shared__ float kvred[512];
  __shared__ float ksred[64];
  int tid = threadIdx.x;
  for (int i = tid; i < 512; i += 256) kvred[i] = 0.f;
  if (tid < 64) ksred[tid] = 0.f;
  __syncthreads();
  int lane = tid & 63, wv = tid >> 6;
  size_t t0 = (size_t)blockIdx.x * 64;
  int b = (int)(t0 >> 14);
  int pr = lane >> 1;
  float theta = exp2f(-(float)(pr & 15) * THETA_SC);
  bool use_i = pr < 16;
  int hbase = lane & 56;
  float akv[8];
  #pragma unroll
  for (int d = 0; d < 8; d++) akv[d] = 0.f;
  float aks = 0.f;
  for (int it = 0; it < 16; it++) {
    size_t t = t0 + (size_t)wv*16 + it;
    float k = qk[t*128 + 64 + lane];
    float xv = v[t*64 + lane];
    int l = (int)(t & (L_-1));
    float pos = use_i ? (float)(l >> 7) : (float)(l & 127);
    float sn, cs; sincosf(pos*theta, &sn, &cs);
    float kp = __shfl_xor(k, 1);
    float kr = (lane & 1) ? (sn*kp + cs*k) : (cs*k - sn*kp);
    #pragma unroll
    for (int d = 0; d < 8; d++) {
      float krd = __shfl(kr, hbase + d);
      akv[d] += krd * xv;
    }
    aks += k;
  }
  int h8 = lane >> 3, e = lane & 7;
  #pragma unroll
  for (int d = 0; d < 8; d++)
    atomicAdd(&kvred[h8*64 + d*8 + e], akv[d]);
  atomicAdd(&ksred[lane], aks);
  __syncthreads();
  for (int i = tid; i < 512; i += 256) atomicAdd(&akv_g[b*512 + i], kvred[i]);
  if (tid < 64) atomicAdd(&aks_g[b*64 + tid], ksred[tid]);
}

__global__ __launch_bounds__(256) void k_attn2(
    const float* __restrict__ qk, const float* __restrict__ x,
    const float* __restrict__ akv_g, const float* __restrict__ aks_g,
    const float* __restrict__ lw, const float* __restrict__ lb,
    float* __restrict__ out, int coff) {
  __shared__ float kv[512];
  __shared__ float km[64];
  __shared__ float lwl[576];
  int tid = threadIdx.x;
  size_t t0 = (size_t)blockIdx.x * 32;
  int b = (int)(t0 >> 14);
  const float invn = 1.f/16384.f;
  for (int i = tid; i < 512; i += 256) kv[i] = akv_g[b*512 + i]*invn;
  if (tid < 64) km[tid] = aks_g[b*64 + tid]*invn;
  for (int i = tid; i < 576; i += 256) lwl[i] = lw[i];
  __syncthreads();
  int lane = tid & 63, wv = tid >> 6;
  int pr = lane >> 1;
  float theta = exp2f(-(float)(pr & 15) * THETA_SC);
  bool use_i = pr < 16;
  int hbase = lane & 56, e = lane & 7;
  float lbv = lb[lane];
  const float* xb = x + ((size_t)b << 14) * 64;
  for (int it = 0; it < 8; it++) {
    size_t t = t0 + (size_t)wv*8 + it;
    int l = (int)(t & (L_-1));
    int ipos = l >> 7, jpos = l & 127;
    float q = qk[t*128 + lane];
    float p = q * km[lane];
    p += __shfl_xor(p, 1); p += __shfl_xor(p, 2); p += __shfl_xor(p, 4);
    float z = 1.f/(p + 1e-6f);
    float pos = use_i ? (float)ipos : (float)jpos;
    float sn, cs; sincosf(pos*theta, &sn, &cs);
    float qp = __shfl_xor(q, 1);
    float qr = (lane & 1) ? (sn*qp + cs*q) : (cs*q - sn*qp);
    float acc = 0.f;
    #pragma unroll
    for (int d = 0; d < 8; d++) {
      float qrd = __shfl(qr, hbase + d);
      acc += qrd * kv[hbase*8 + d*8 + e];
    }
    acc *= z;
    float lp = lbv;
    #pragma unroll
    for (int dh = -1; dh <= 1; dh++) {
      int h2 = ipos + dh; if ((unsigned)h2 >= 128u) continue;
      #pragma unroll
      for (int dw = -1; dw <= 1; dw++) {
        int w2 = jpos + dw; if ((unsigned)w2 >= 128u) continue;
        lp += lwl[lane*9 + (dh+1)*3 + (dw+1)] * xb[((size_t)(h2 << 7) + w2)*64 + lane];
      }
    }
    out[t*128 + coff + lane] = acc + lp;
  }
}

// ---------------------------------------------------------------- launcher
extern "C" void kernel_launch(void* const* d_in, const int* in_sizes, int n_in,
                              void* d_out, int out_size, void* d_ws, size_t ws_size,
                              hipStream_t stream) {
  (void)in_sizes; (void)n_in; (void)out_size;

  float* base;
  if (ws_size >= WSF * sizeof(float)) {
    base = (float*)d_ws;
  } else {
    void* p = nullptr;
    hipGetSymbolAddress(&p, HIP_SYMBOL(g_ws));
    base = (float*)p;
  }
  float* P0 = base;          // x0 (planar, persists)
  float* PA = base + 1*NS;   // xseq / x_s / ACT
  float* PB = base + 2*NS;   // xt shortcut / xt2 / fmt2 re / x0 seq
  float* PC = base + 3*NS;   // fmt1 re / xt3 / xt4
  float* PD = base + 4*NS;   // QK / fmt im / xo seq
  float* PF = base + 5*NS;   // CAT / xss / FFN
  float* H0 = base + 6*NS;
  float* H1 = H0 + NH;
  float* H2 = H1 + NH;
  float* WG = H2 + NH;                  // B*8*L
  float* ACC = WG + WGSZ;               // 2304
  float* CW  = ACC + ACCSZ;             // fp32 weights
  bf16_t* CW16 = (bf16_t*)(CW + CWSZ);  // bf16 weight mirror
  int*   FLG = (int*)(CW + CWSZ + CW16SZF);

  static const int wsz[47] = {
    16384,128,128,128,1152,128,1024,8,8,8,1024,128,128,128,128,128,
    16384,128,1152,16384,128,3200,16384,128,4096,64,576,64,8192,128,
    576,64,16384,128,1152,128,128,128,512,4,512,128,16384,32768,128,128,128};
  int woff[47]; { int a = 0; for (int i = 0; i < 47; i++){ woff[i] = a; a += wsz[i]; } }
  const float* Wf[47]; for (int i = 0; i < 47; i++) Wf[i] = CW + woff[i];
  auto W16 = [&](int i){ return (const bf16_t*)(CW16 + woff[i] + (woff[i] >= W16SHIFT ? 4 : 0)); };
  const float *c1_b=Wf[1], *c1_g=Wf[2], *c1_be=Wf[3], *cpe1_w=Wf[4],
    *cpe1_b=Wf[5], *fw1=Wf[6], *fb1=Wf[7], *f_g=Wf[8], *f_be=Wf[9], *fw2=Wf[10],
    *fb2=Wf[11], *nbn_g=Wf[12], *nbn_be=Wf[13], *ln1_g=Wf[14], *ln1_b=Wf[15],
    *d3b1=Wf[17], *d3w2=Wf[18], *d5b1=Wf[20],
    *d5w2=Wf[21], *ap_b=Wf[23], *ip2_b=Wf[25],
    *dwc2_w=Wf[26], *dwc2_b=Wf[27], *qk_b=Wf[29], *lepe_w=Wf[30],
    *lepe_b=Wf[31], *op_b=Wf[33], *cpe2_w=Wf[34], *cpe2_b=Wf[35],
    *ln2_g=Wf[36], *ln2_b=Wf[37], *ffn_w1=Wf[38], *ffn_b1=Wf[39], *ffn_w2=Wf[40],
    *ffn_b2=Wf[41], *red_b=Wf[44], *red_g=Wf[45], *red_be=Wf[46];
  const bf16_t *c1_w16=W16(0), *d3w1_16=W16(16), *d5w1_16=W16(19), *ap_w16=W16(22),
    *ip2_w16=W16(24), *qk_w16=W16(28), *op_w16=W16(32), *po_w16=W16(42), *red_w16=W16(43);

  const void* x = d_in[0];

  // 0. dtype probe + weight conversion (fp32 + bf16 mirror)
  k_probe<<<1, 256, 0, stream>>>((const bf16_t*)x, FLG);
  P47 ps; for (int i = 0; i < 47; i++) ps.p[i] = d_in[i+1];
  k_cvt<<<(TOTW+255)/256, 256, 0, stream>>>(ps, FLG, CW);
  k_cvt16<<<(TOTW+255)/256, 256, 0, stream>>>(CW, CW16);

  dim3 tgrid(512, 4, 4), tblk(32, 8);

  // fully fused fmt: seq in, residual adds fused into seq out (out may alias add1)
  auto fmt_fused = [&](const float* seq_in, float* re, float* im,
                       const float* add1, const float* add2, float* outp) {
    k_fft_row_fwd_seq<<<1024, 256, 0, stream>>>(seq_in, re, im);
    k_fft_col_fwd<<<2048, 256, 0, stream>>>(re, im);
    k_freq1<<<256, 256, 0, stream>>>(re, fw1, fb1, f_g, f_be, WG);
    k_fft_col_inv_scaled<<<2048, 256, 0, stream>>>(re, im, WG, fw2, fb2);
    k_fft_row_inv_abs_seq<<<1024, 256, 0, stream>>>(re, im, nbn_g, nbn_be, add1, add2, outp);
  };

  auto attn = [&](const float* brin, float* qkbuf, int coff) {
    k_zero<<<9, 256, 0, stream>>>(ACC, 2304);
    k_mfma_tok<64,128,3,false><<<1024, 256, 0, stream>>>(brin, nullptr, qk_w16, qk_b, qkbuf);
    k_kv<<<1024, 256, 0, stream>>>(qkbuf, brin, ACC, ACC + B_*512);
    k_attn2<<<2048, 256, 0, stream>>>(qkbuf, brin, ACC, ACC + B_*512, lepe_w, lepe_b, PF, coff);
  };

  // x -> seq                                               -> PA
  k_p2s<true><<<tgrid, tblk, 0, stream>>>(x, PA, nullptr, nullptr, FLG);
  // x_0 = relu(bn(conv1x1(x)))                             -> P0 (planar)
  k_mfma_pout<128,false,false><<<1024, 256, 0, stream>>>(
      PA, nullptr, c1_w16, c1_b, c1_g, c1_be, nullptr, P0, FLG);
  // xt = x + dw3(x,cpe1)+b                                 -> PB (shortcut)
  k_dw3<128,0><<<8192, 256, 0, stream>>>(PA, cpe1_w, cpe1_b, PB);
  // x_s = ln(xt)                                           -> PA
  k_ln<<<16384, 256, 0, stream>>>(PB, ln1_g, ln1_b, PA);
  // multi-scale convs
  k_mfma_tok<128,128,1,false><<<1024, 256, 0, stream>>>(PA, nullptr, d3w1_16, d3b1, PD);
  k_gconv<3><<<4096, 256, 0, stream>>>(PD, d3w2, H0);
  k_mfma_tok<128,128,1,false><<<1024, 256, 0, stream>>>(PA, nullptr, d5w1_16, d5b1, PD);
  k_gconv<5><<<4096, 256, 0, stream>>>(PD, d5w2, H1);
  k_mfma_tok<128,128,2,false><<<1024, 256, 0, stream>>>(PA, nullptr, ap_w16, ap_b, PA); // ACT
  // branch3 -> attention -> CAT[:, :, 0:64] in PF
  k_mfma_tok<64,64,1,false><<<1024, 256, 0, stream>>>(H0, nullptr, ip2_w16, ip2_b, H2);
  k_dw3<64,1><<<4096, 256, 0, stream>>>(H2, dwc2_w, dwc2_b, H0);
  attn(H0, PD, 0);
  // branch5 -> attention -> CAT[:, :, 64:128]
  k_mfma_tok<64,64,1,false><<<1024, 256, 0, stream>>>(H1, nullptr, ip2_w16, ip2_b, H2);
  k_dw3<64,1><<<4096, 256, 0, stream>>>(H2, dwc2_w, dwc2_b, H1);
  attn(H1, PD, 64);
  // xss = conv1x1(CAT * ACT, op_w)+op_b                    -> PF (in-place)
  k_mfma_tok<128,128,1,true><<<1024, 256, 0, stream>>>(PF, PA, op_w16, op_b, PF);
  // fmt1 (delayed) + xt2 = shortcut + xss + fmt1           -> PB
  fmt_fused(PB, PC, PD, PB, PF, PB);
  // xt3 = xt2 + dw3(xt2,cpe2)+b                            -> PC
  k_dw3<128,0><<<8192, 256, 0, stream>>>(PB, cpe2_w, cpe2_b, PC);
  // ffn(ln2(xt3))                                          -> PF
  k_ln_ffn<<<16384, 256, 0, stream>>>(PC, ln2_g, ln2_b, ffn_w1, ffn_b1, ffn_w2, ffn_b2, PF);
  // fmt2 + xt4 = xt3 + ffn + fmt2                          -> PC
  fmt_fused(PC, PB, PD, PC, PF, PC);
  // xo = conv1x1(xt4, po_w)                                -> PD (seq)
  k_mfma_tok<128,128,0,false><<<1024, 256, 0, stream>>>(PC, nullptr, po_w16, nullptr, PD);
  // x0 planar -> seq                                       -> PB
  k_p2s<false><<<tgrid, tblk, 0, stream>>>(P0, PB, nullptr, nullptr, nullptr);
  // out = relu(bn(conv1x1([x0;xo], red))) + x0             -> d_out (planar, dtype per flag)
  k_mfma_pout<256,true,true><<<1024, 256, 0, stream>>>(
      PB, PD, red_w16, red_b, red_g, red_be, P0, d_out, FLG);
}